// Round 2
// baseline (651.379 us; speedup 1.0000x reference)
//
#include <hip/hip_runtime.h>
#include <math.h>

#define NN 50000
#define NE 800000
#define FIN 128
#define HID 64
#define HEADS 4
#define C1 256   // HEADS*HID
#define CLS 40
#define EPSF 1e-16f

// ---------------- counting sort of edges by dst ----------------

__global__ void k_zero(int* a, int n) {
    int i = blockIdx.x * 256 + threadIdx.x;
    if (i < n) a[i] = 0;
}

__global__ void k_hist(const int* __restrict__ ei, int* __restrict__ counts) {
    int i = blockIdx.x * 256 + threadIdx.x;
    if (i < NE) atomicAdd(&counts[ei[NE + i]], 1);
}

__global__ __launch_bounds__(1024) void k_scan1(const int* __restrict__ counts,
                                                int* __restrict__ offs,
                                                int* __restrict__ partials) {
    __shared__ int s[1024];
    int t = threadIdx.x;
    int g = blockIdx.x * 1024 + t;
    int v = (g < NN) ? counts[g] : 0;
    s[t] = v;
    __syncthreads();
    for (int d = 1; d < 1024; d <<= 1) {
        int x = (t >= d) ? s[t - d] : 0;
        __syncthreads();
        s[t] += x;
        __syncthreads();
    }
    if (g < NN) offs[g] = s[t] - v;             // block-local exclusive
    if (t == 1023) partials[blockIdx.x] = s[t]; // block total
}

__global__ void k_scan2(int* partials, int nb) {
    if (threadIdx.x == 0 && blockIdx.x == 0) {
        int run = 0;
        for (int b = 0; b < nb; b++) { int v = partials[b]; partials[b] = run; run += v; }
    }
}

__global__ void k_scan3(int* __restrict__ offs, const int* __restrict__ partials,
                        int* __restrict__ cursor) {
    int g = blockIdx.x * 256 + threadIdx.x;
    if (g < NN) {
        int o = offs[g] + partials[g >> 10];
        offs[g] = o;
        cursor[g] = o;
    }
}

__global__ void k_scatter(const int* __restrict__ ei, int* __restrict__ cursor,
                          int* __restrict__ ssrc) {
    int i = blockIdx.x * 256 + threadIdx.x;
    if (i < NE) {
        int s = ei[i];
        int d = ei[NE + i];
        int p = atomicAdd(&cursor[d], 1);
        ssrc[p] = s;
    }
}

// ---------------- layer 1: tiled GEMM + fused alpha dots ----------------
// C[32 x 256] per block. 256 thr: tx=t&63 -> cols tx*4..+3, ty=t>>6 -> rows ty*8..+7.
// LDS: As transposed [BK=32][32], Bs [32][256]. Epilogue computes per-row head
// dots with a_src1/a_dst1 via 16-lane shuffle reduction (head = 64 cols = 16 lanes).
__global__ __launch_bounds__(256) void k_gemm1(const float* __restrict__ x,
                                               const float* __restrict__ W,
                                               const float* __restrict__ aws,
                                               const float* __restrict__ awd,
                                               float* __restrict__ h1,
                                               float* __restrict__ as1,
                                               float* __restrict__ ad1) {
    __shared__ float As[32 * 32];
    __shared__ float Bs[32 * 256];
    int t = threadIdx.x;
    int m0 = blockIdx.x * 32;
    int tx = t & 63;
    int ty = t >> 6;
    float acc[8][4];
#pragma unroll
    for (int r = 0; r < 8; r++)
#pragma unroll
        for (int i = 0; i < 4; i++) acc[r][i] = 0.f;

    int ar = t >> 3;   // tile row 0..31
    int ac4 = t & 7;   // k-f4 offset
    int grow = m0 + ar;
    if (grow >= NN) grow = NN - 1;
    const float* xrp = x + (size_t)grow * FIN;

    for (int k0 = 0; k0 < FIN; k0 += 32) {
        float4 av = *(const float4*)(xrp + k0 + ac4 * 4);
        float4 bv[8];
#pragma unroll
        for (int i = 0; i < 8; i++) {
            int idx = i * 256 + t;
            int br = idx >> 6, bc = idx & 63;
            bv[i] = *(const float4*)(W + (size_t)(k0 + br) * C1 + bc * 4);
        }
        __syncthreads();
        As[(ac4 * 4 + 0) * 32 + ar] = av.x;
        As[(ac4 * 4 + 1) * 32 + ar] = av.y;
        As[(ac4 * 4 + 2) * 32 + ar] = av.z;
        As[(ac4 * 4 + 3) * 32 + ar] = av.w;
#pragma unroll
        for (int i = 0; i < 8; i++) {
            int idx = i * 256 + t;
            int br = idx >> 6, bc = idx & 63;
            *(float4*)&Bs[br * 256 + bc * 4] = bv[i];
        }
        __syncthreads();
#pragma unroll
        for (int kk = 0; kk < 32; kk++) {
            float4 b4 = *(const float4*)&Bs[kk * 256 + tx * 4];
            float4 a0 = *(const float4*)&As[kk * 32 + ty * 8];
            float4 a1 = *(const float4*)&As[kk * 32 + ty * 8 + 4];
            float a8[8] = {a0.x, a0.y, a0.z, a0.w, a1.x, a1.y, a1.z, a1.w};
#pragma unroll
            for (int r = 0; r < 8; r++) {
                acc[r][0] = fmaf(a8[r], b4.x, acc[r][0]);
                acc[r][1] = fmaf(a8[r], b4.y, acc[r][1]);
                acc[r][2] = fmaf(a8[r], b4.z, acc[r][2]);
                acc[r][3] = fmaf(a8[r], b4.w, acc[r][3]);
            }
        }
    }

    int head = tx >> 4;
    float wsv0 = aws[tx * 4 + 0], wsv1 = aws[tx * 4 + 1], wsv2 = aws[tx * 4 + 2], wsv3 = aws[tx * 4 + 3];
    float wdv0 = awd[tx * 4 + 0], wdv1 = awd[tx * 4 + 1], wdv2 = awd[tx * 4 + 2], wdv3 = awd[tx * 4 + 3];
#pragma unroll
    for (int r = 0; r < 8; r++) {
        int row = m0 + ty * 8 + r;
        bool ok = row < NN;
        float4 o = {acc[r][0], acc[r][1], acc[r][2], acc[r][3]};
        if (ok) *(float4*)(h1 + (size_t)row * C1 + tx * 4) = o;
        float ps = o.x * wsv0 + o.y * wsv1 + o.z * wsv2 + o.w * wsv3;
        float pd = o.x * wdv0 + o.y * wdv1 + o.z * wdv2 + o.w * wdv3;
#pragma unroll
        for (int s = 1; s < 16; s <<= 1) {
            ps += __shfl_xor(ps, s);
            pd += __shfl_xor(pd, s);
        }
        if (ok && (tx & 15) == 0) {
            as1[row * 4 + head] = ps;
            ad1[row * 4 + head] = pd;
        }
    }
}

// ---------------- layer 1 aggregation (wave per dst, online softmax) -----

__global__ __launch_bounds__(256) void k_agg1(const float* __restrict__ h1,
                                              const float* __restrict__ as1,
                                              const float* __restrict__ ad1,
                                              const int* __restrict__ offs,
                                              const int* __restrict__ ssrc,
                                              const float* __restrict__ b1,
                                              float* __restrict__ g1) {
    int lane = threadIdx.x & 63;
    int node = blockIdx.x * 4 + (threadIdx.x >> 6);
    int head = lane >> 4;
    int beg = offs[node];
    int end = (node + 1 < NN) ? offs[node + 1] : NE;
    float adh = ad1[node * 4 + head];
    float m = -INFINITY, l = 0.f;
    float4 acc = {0.f, 0.f, 0.f, 0.f};
    const float4* h1v = (const float4*)h1;
    int nsrc = (beg < end) ? ssrc[beg] : 0;
    float nas = as1[nsrc * 4 + head];
    for (int j = beg; j < end; j++) {
        int src = nsrc;
        float asv = nas;
        if (j + 1 < end) {
            nsrc = ssrc[j + 1];
            nas = as1[nsrc * 4 + head];
        }
        float4 hv = h1v[(size_t)src * 64 + lane];
        float e = asv + adh;
        e = e > 0.f ? e : 0.2f * e;
        float nm = fmaxf(m, e);
        float sc = __expf(m - nm);
        float p = __expf(e - nm);
        m = nm;
        l = l * sc + p;
        acc.x = fmaf(p, hv.x, acc.x * sc);
        acc.y = fmaf(p, hv.y, acc.y * sc);
        acc.z = fmaf(p, hv.z, acc.z * sc);
        acc.w = fmaf(p, hv.w, acc.w * sc);
    }
    float inv = 1.f / (l + EPSF);
    float4 b = ((const float4*)b1)[lane];
    float4 o;
    o.x = fmaxf(fmaf(acc.x, inv, b.x), 0.f);
    o.y = fmaxf(fmaf(acc.y, inv, b.y), 0.f);
    o.z = fmaxf(fmaf(acc.z, inv, b.z), 0.f);
    o.w = fmaxf(fmaf(acc.w, inv, b.w), 0.f);
    ((float4*)g1)[(size_t)node * 64 + lane] = o;
}

// ---------------- layer 2: LDS-W2 GEMM + fused alpha2 ----------------
// block = 256 thr = 4 waves x 4 rows. lane = col (40 active). W2 staged in LDS.
// g1 row data loaded coalesced (lane -> (row=lane>>4, k4=lane&15)), broadcast
// to the wave via compile-time __shfl after full unroll.
__global__ __launch_bounds__(256) void k_gemm2(const float* __restrict__ g1,
                                               const float* __restrict__ W2,
                                               const float* __restrict__ aws,
                                               const float* __restrict__ awd,
                                               float* __restrict__ h2,
                                               float* __restrict__ as2,
                                               float* __restrict__ ad2) {
    __shared__ float Ws[10304];  // 256*40 + pad
    int t = threadIdx.x;
#pragma unroll
    for (int i = 0; i < 10; i++) {
        int idx = i * 256 + t;
        *(float4*)&Ws[idx * 4] = *(const float4*)(W2 + idx * 4);
    }
    __syncthreads();
    int lane = t & 63;
    int wid = t >> 6;
    int m0 = blockIdx.x * 16 + wid * 4;
    int lr = lane >> 4;
    int lk = lane & 15;
    bool act = lane < CLS;
    int col = act ? lane : CLS - 1;
    float acc[4] = {0.f, 0.f, 0.f, 0.f};
    const float* gbase = g1 + (size_t)(m0 + lr) * C1;
    for (int k0 = 0; k0 < C1; k0 += 64) {
        float4 gv = *(const float4*)(gbase + k0 + lk * 4);
#pragma unroll
        for (int kk = 0; kk < 64; kk++) {
            float comp = (kk & 3) == 0 ? gv.x : (kk & 3) == 1 ? gv.y : (kk & 3) == 2 ? gv.z : gv.w;
            float w = Ws[(k0 + kk) * 40 + col];
            int sl = kk >> 2;
            acc[0] = fmaf(__shfl(comp, sl), w, acc[0]);
            acc[1] = fmaf(__shfl(comp, 16 + sl), w, acc[1]);
            acc[2] = fmaf(__shfl(comp, 32 + sl), w, acc[2]);
            acc[3] = fmaf(__shfl(comp, 48 + sl), w, acc[3]);
        }
    }
    float was = aws[col];
    float wad = awd[col];
#pragma unroll
    for (int r = 0; r < 4; r++) {
        float v = act ? acc[r] : 0.f;
        float vs = v * was, vd = v * wad;
#pragma unroll
        for (int s = 32; s >= 1; s >>= 1) {
            vs += __shfl_xor(vs, s);
            vd += __shfl_xor(vd, s);
        }
        int row = m0 + r;
        if (act) h2[(size_t)row * CLS + lane] = v;
        if (lane == 0) {
            as2[row] = vs;
            ad2[row] = vd;
        }
    }
}

// ---------------- layer 2 aggregation + fused log_softmax ----------------

__global__ __launch_bounds__(256) void k_agg2(const float* __restrict__ h2,
                                              const float* __restrict__ as2,
                                              const float* __restrict__ ad2,
                                              const int* __restrict__ offs,
                                              const int* __restrict__ ssrc,
                                              const float* __restrict__ b2,
                                              float* __restrict__ out) {
    int lane = threadIdx.x & 63;
    int node = blockIdx.x * 4 + (threadIdx.x >> 6);
    int beg = offs[node];
    int end = (node + 1 < NN) ? offs[node + 1] : NE;
    float adh = ad2[node];
    bool act = lane < CLS;
    float m = -INFINITY, l = 0.f, acc = 0.f;
    int nsrc = (beg < end) ? ssrc[beg] : 0;
    float nas = as2[nsrc];
    for (int j = beg; j < end; j++) {
        int src = nsrc;
        float asv = nas;
        if (j + 1 < end) {
            nsrc = ssrc[j + 1];
            nas = as2[nsrc];
        }
        float hv = act ? h2[(size_t)src * CLS + lane] : 0.f;
        float e = asv + adh;
        e = e > 0.f ? e : 0.2f * e;
        float nm = fmaxf(m, e);
        float sc = __expf(m - nm);
        float p = __expf(e - nm);
        m = nm;
        l = l * sc + p;
        acc = fmaf(p, hv, acc * sc);
    }
    float v = act ? (acc / (l + EPSF) + b2[lane]) : -INFINITY;
    float mx = v;
#pragma unroll
    for (int s = 32; s >= 1; s >>= 1) mx = fmaxf(mx, __shfl_xor(mx, s));
    float ex = act ? __expf(v - mx) : 0.f;
    float sum = ex;
#pragma unroll
    for (int s = 32; s >= 1; s >>= 1) sum += __shfl_xor(sum, s);
    if (act) out[(size_t)node * CLS + lane] = v - mx - __logf(sum);
}

// ---------------- launch ----------------

extern "C" void kernel_launch(void* const* d_in, const int* in_sizes, int n_in,
                              void* d_out, int out_size, void* d_ws, size_t ws_size,
                              hipStream_t stream) {
    const float* x    = (const float*)d_in[0];
    const int*   ei   = (const int*)d_in[1];
    const float* W1   = (const float*)d_in[2];
    const float* as1w = (const float*)d_in[3];
    const float* ad1w = (const float*)d_in[4];
    const float* b1   = (const float*)d_in[5];
    const float* W2   = (const float*)d_in[6];
    const float* as2w = (const float*)d_in[7];
    const float* ad2w = (const float*)d_in[8];
    const float* b2   = (const float*)d_in[9];
    float* out = (float*)d_out;

    char* p = (char*)d_ws;
    auto alloc = [&](size_t bytes) {
        char* r = p;
        p += (bytes + 255) & ~(size_t)255;
        return r;
    };
    float* h1   = (float*)alloc((size_t)NN * C1 * 4);
    float* g1   = (float*)alloc((size_t)NN * C1 * 4);
    float* h2   = (float*)alloc((size_t)NN * CLS * 4);
    float* as1  = (float*)alloc((size_t)NN * 4 * 4);
    float* ad1  = (float*)alloc((size_t)NN * 4 * 4);
    float* as2  = (float*)alloc((size_t)NN * 4);
    float* ad2  = (float*)alloc((size_t)NN * 4);
    int* counts = (int*)alloc((size_t)NN * 4);
    int* offs   = (int*)alloc((size_t)NN * 4);
    int* cursor = (int*)alloc((size_t)NN * 4);
    int* parts  = (int*)alloc(64 * 4);
    int* ssrc   = (int*)alloc((size_t)NE * 4);

    const int nb_scan = (NN + 1023) / 1024;  // 49

    k_zero<<<(NN + 255) / 256, 256, 0, stream>>>(counts, NN);
    k_hist<<<(NE + 255) / 256, 256, 0, stream>>>(ei, counts);
    k_scan1<<<nb_scan, 1024, 0, stream>>>(counts, offs, parts);
    k_scan2<<<1, 64, 0, stream>>>(parts, nb_scan);
    k_scan3<<<(NN + 255) / 256, 256, 0, stream>>>(offs, parts, cursor);
    k_scatter<<<(NE + 255) / 256, 256, 0, stream>>>(ei, cursor, ssrc);

    k_gemm1<<<(NN + 31) / 32, 256, 0, stream>>>(x, W1, as1w, ad1w, h1, as1, ad1);
    k_agg1<<<NN / 4, 256, 0, stream>>>(h1, as1, ad1, offs, ssrc, b1, g1);

    k_gemm2<<<NN / 16, 256, 0, stream>>>(g1, W2, as2w, ad2w, h2, as2, ad2);
    k_agg2<<<NN / 4, 256, 0, stream>>>(h2, as2, ad2, offs, ssrc, b2, out);
}

// Round 3
// 512.514 us; speedup vs baseline: 1.2709x; 1.2709x over previous
//
#include <hip/hip_runtime.h>
#include <math.h>

#define NN 50000
#define NE 800000
#define FIN 128
#define HID 64
#define HEADS 4
#define C1 256   // HEADS*HID
#define CLS 40
#define EPSF 1e-16f

// ---------------- counting sort of edges by dst ----------------

__global__ void k_zero(int* a, int n) {
    int i = blockIdx.x * 256 + threadIdx.x;
    if (i < n) a[i] = 0;
}

__global__ void k_hist(const int* __restrict__ ei, int* __restrict__ counts) {
    int i = blockIdx.x * 256 + threadIdx.x;
    if (i < NE) atomicAdd(&counts[ei[NE + i]], 1);
}

__global__ __launch_bounds__(1024) void k_scan1(const int* __restrict__ counts,
                                                int* __restrict__ offs,
                                                int* __restrict__ partials) {
    __shared__ int s[1024];
    int t = threadIdx.x;
    int g = blockIdx.x * 1024 + t;
    int v = (g < NN) ? counts[g] : 0;
    s[t] = v;
    __syncthreads();
    for (int d = 1; d < 1024; d <<= 1) {
        int x = (t >= d) ? s[t - d] : 0;
        __syncthreads();
        s[t] += x;
        __syncthreads();
    }
    if (g < NN) offs[g] = s[t] - v;             // block-local exclusive
    if (t == 1023) partials[blockIdx.x] = s[t]; // block total
}

__global__ void k_scan2(int* partials, int nb) {
    if (threadIdx.x == 0 && blockIdx.x == 0) {
        int run = 0;
        for (int b = 0; b < nb; b++) { int v = partials[b]; partials[b] = run; run += v; }
    }
}

__global__ void k_scan3(int* __restrict__ offs, const int* __restrict__ partials,
                        int* __restrict__ cursor) {
    int g = blockIdx.x * 256 + threadIdx.x;
    if (g < NN) {
        int o = offs[g] + partials[g >> 10];
        offs[g] = o;
        cursor[g] = o;
    }
}

__global__ void k_scatter(const int* __restrict__ ei, int* __restrict__ cursor,
                          int* __restrict__ ssrc) {
    int i = blockIdx.x * 256 + threadIdx.x;
    if (i < NE) {
        int s = ei[i];
        int d = ei[NE + i];
        int p = atomicAdd(&cursor[d], 1);
        ssrc[p] = s;
    }
}

// ---------------- layer 1: register-tiled GEMM + fused alpha dots --------
// Block tile 64 rows x 256 cols, BK=32. 256 thr: cg=t&63 (cols cg*4..+3),
// rt=t>>6 (wave id) -> rows rt*16..+15. 64 FMA per (1 coalesced b128 B read +
// 4 broadcast b128 A reads). A staged transposed k-major, stride 68.
__global__ __launch_bounds__(256) void k_gemm1(const float* __restrict__ x,
                                               const float* __restrict__ W,
                                               const float* __restrict__ aws,
                                               const float* __restrict__ awd,
                                               float* __restrict__ h1,
                                               float* __restrict__ as1,
                                               float* __restrict__ ad1) {
    __shared__ float As[32 * 68];    // [kk][row<64], stride 68
    __shared__ float Bs[32 * 256];   // [kk][col]
    int t = threadIdx.x;
    int m0 = blockIdx.x * 64;
    int cg = t & 63;
    int rt = t >> 6;

    float acc[16][4];
#pragma unroll
    for (int r = 0; r < 16; r++)
#pragma unroll
        for (int i = 0; i < 4; i++) acc[r][i] = 0.f;

    // staging indices
    int a_kkg = t & 7;          // k f4-group within chunk
    int a_row = t >> 3;         // 0..31 ; +i*32
    int b_bc = t & 63;          // col f4
    int b_br = t >> 6;          // 0..3 ; +i*4

    for (int k0 = 0; k0 < FIN; k0 += 32) {
        float4 av[2], bv[8];
#pragma unroll
        for (int i = 0; i < 2; i++) {
            int row = a_row + i * 32;
            int grow = m0 + row;
            if (grow >= NN) grow = NN - 1;
            av[i] = *(const float4*)(x + (size_t)grow * FIN + k0 + a_kkg * 4);
        }
#pragma unroll
        for (int i = 0; i < 8; i++) {
            int br = b_br + i * 4;
            bv[i] = *(const float4*)(W + (size_t)(k0 + br) * C1 + b_bc * 4);
        }
        __syncthreads();
#pragma unroll
        for (int i = 0; i < 2; i++) {
            int row = a_row + i * 32;
            As[(a_kkg * 4 + 0) * 68 + row] = av[i].x;
            As[(a_kkg * 4 + 1) * 68 + row] = av[i].y;
            As[(a_kkg * 4 + 2) * 68 + row] = av[i].z;
            As[(a_kkg * 4 + 3) * 68 + row] = av[i].w;
        }
#pragma unroll
        for (int i = 0; i < 8; i++) {
            int br = b_br + i * 4;
            *(float4*)&Bs[br * 256 + b_bc * 4] = bv[i];
        }
        __syncthreads();
#pragma unroll 8
        for (int kk = 0; kk < 32; kk++) {
            float4 b4 = *(const float4*)&Bs[kk * 256 + cg * 4];
            float4 a4[4];
#pragma unroll
            for (int j = 0; j < 4; j++)
                a4[j] = *(const float4*)&As[kk * 68 + rt * 16 + j * 4];
#pragma unroll
            for (int j = 0; j < 4; j++) {
                float ar4[4] = {a4[j].x, a4[j].y, a4[j].z, a4[j].w};
#pragma unroll
                for (int rr = 0; rr < 4; rr++) {
                    int r = j * 4 + rr;
                    acc[r][0] = fmaf(ar4[rr], b4.x, acc[r][0]);
                    acc[r][1] = fmaf(ar4[rr], b4.y, acc[r][1]);
                    acc[r][2] = fmaf(ar4[rr], b4.z, acc[r][2]);
                    acc[r][3] = fmaf(ar4[rr], b4.w, acc[r][3]);
                }
            }
        }
    }

    // epilogue: store h1 + head-dot reductions (head = 16-lane group of cg)
    int head = cg >> 4;
    float4 wsv = *(const float4*)(aws + cg * 4);
    float4 wdv = *(const float4*)(awd + cg * 4);
#pragma unroll
    for (int r = 0; r < 16; r++) {
        int row = m0 + rt * 16 + r;
        bool ok = row < NN;
        float4 o = {acc[r][0], acc[r][1], acc[r][2], acc[r][3]};
        if (ok) *(float4*)(h1 + (size_t)row * C1 + cg * 4) = o;
        float ps = o.x * wsv.x + o.y * wsv.y + o.z * wsv.z + o.w * wsv.w;
        float pd = o.x * wdv.x + o.y * wdv.y + o.z * wdv.z + o.w * wdv.w;
#pragma unroll
        for (int s = 1; s < 16; s <<= 1) {
            ps += __shfl_xor(ps, s);
            pd += __shfl_xor(pd, s);
        }
        if (ok && (cg & 15) == 0) {
            as1[row * 4 + head] = ps;
            ad1[row * 4 + head] = pd;
        }
    }
}

// ---------------- layer 1 aggregation (wave per dst, online softmax) -----

__global__ __launch_bounds__(256) void k_agg1(const float* __restrict__ h1,
                                              const float* __restrict__ as1,
                                              const float* __restrict__ ad1,
                                              const int* __restrict__ offs,
                                              const int* __restrict__ ssrc,
                                              const float* __restrict__ b1,
                                              float* __restrict__ g1) {
    int lane = threadIdx.x & 63;
    int node = blockIdx.x * 4 + (threadIdx.x >> 6);
    int head = lane >> 4;
    int beg = offs[node];
    int end = (node + 1 < NN) ? offs[node + 1] : NE;
    float adh = ad1[node * 4 + head];
    float m = -INFINITY, l = 0.f;
    float4 acc = {0.f, 0.f, 0.f, 0.f};
    const float4* h1v = (const float4*)h1;
    int nsrc = (beg < end) ? ssrc[beg] : 0;
    float nas = as1[nsrc * 4 + head];
    for (int j = beg; j < end; j++) {
        int src = nsrc;
        float asv = nas;
        if (j + 1 < end) {
            nsrc = ssrc[j + 1];
            nas = as1[nsrc * 4 + head];
        }
        float4 hv = h1v[(size_t)src * 64 + lane];
        float e = asv + adh;
        e = e > 0.f ? e : 0.2f * e;
        float nm = fmaxf(m, e);
        float sc = __expf(m - nm);
        float p = __expf(e - nm);
        m = nm;
        l = l * sc + p;
        acc.x = fmaf(p, hv.x, acc.x * sc);
        acc.y = fmaf(p, hv.y, acc.y * sc);
        acc.z = fmaf(p, hv.z, acc.z * sc);
        acc.w = fmaf(p, hv.w, acc.w * sc);
    }
    float inv = 1.f / (l + EPSF);
    float4 b = ((const float4*)b1)[lane];
    float4 o;
    o.x = fmaxf(fmaf(acc.x, inv, b.x), 0.f);
    o.y = fmaxf(fmaf(acc.y, inv, b.y), 0.f);
    o.z = fmaxf(fmaf(acc.z, inv, b.z), 0.f);
    o.w = fmaxf(fmaf(acc.w, inv, b.w), 0.f);
    ((float4*)g1)[(size_t)node * 64 + lane] = o;
}

// ---------------- layer 2: register-tiled GEMM + fused alpha2 ------------
// Block tile 128 rows x 48 cols (40 real, zero-padded). Whole W2 in LDS
// [256][48]. 256 thr: cg=t&15 (cols cg*3..+2), rt=t>>4 (rows rt*8..+7).
// 24 FMA per (2 broadcast b128 A reads + 3 conflict-free b32 W reads).
__global__ __launch_bounds__(256) void k_gemm2(const float* __restrict__ g1,
                                               const float* __restrict__ W2,
                                               const float* __restrict__ aws,
                                               const float* __restrict__ awd,
                                               float* __restrict__ h2,
                                               float* __restrict__ as2,
                                               float* __restrict__ ad2) {
    __shared__ float Ws[256 * 48];   // zero-padded cols
    __shared__ float As[32 * 132];   // [kk][row<128], stride 132
    int t = threadIdx.x;
    int m0 = blockIdx.x * 128;
    int cg = t & 15;
    int rt = t >> 4;

    // stage all of W2 (zero-pad cols 40..47)
#pragma unroll
    for (int i = 0; i < 12; i++) {
        int idx = i * 256 + t;          // f4 slot, 3072 total
        int kk = idx / 12;
        int c4 = idx % 12;
        float4 v = {0.f, 0.f, 0.f, 0.f};
        if (c4 < 10) v = *(const float4*)(W2 + kk * CLS + c4 * 4);
        *(float4*)&Ws[kk * 48 + c4 * 4] = v;
    }

    float acc[8][3];
#pragma unroll
    for (int r = 0; r < 8; r++)
#pragma unroll
        for (int i = 0; i < 3; i++) acc[r][i] = 0.f;

    int a_kkg = t & 7;
    int a_row = t >> 3;   // 0..31 ; +i*32

    for (int k0 = 0; k0 < C1; k0 += 32) {
        float4 av[4];
#pragma unroll
        for (int i = 0; i < 4; i++) {
            int row = a_row + i * 32;
            int grow = m0 + row;
            if (grow >= NN) grow = NN - 1;
            av[i] = *(const float4*)(g1 + (size_t)grow * C1 + k0 + a_kkg * 4);
        }
        __syncthreads();
#pragma unroll
        for (int i = 0; i < 4; i++) {
            int row = a_row + i * 32;
            As[(a_kkg * 4 + 0) * 132 + row] = av[i].x;
            As[(a_kkg * 4 + 1) * 132 + row] = av[i].y;
            As[(a_kkg * 4 + 2) * 132 + row] = av[i].z;
            As[(a_kkg * 4 + 3) * 132 + row] = av[i].w;
        }
        __syncthreads();
#pragma unroll 8
        for (int kk = 0; kk < 32; kk++) {
            float4 a0 = *(const float4*)&As[kk * 132 + rt * 8];
            float4 a1 = *(const float4*)&As[kk * 132 + rt * 8 + 4];
            float w0 = Ws[(k0 + kk) * 48 + cg * 3 + 0];
            float w1 = Ws[(k0 + kk) * 48 + cg * 3 + 1];
            float w2 = Ws[(k0 + kk) * 48 + cg * 3 + 2];
            float a8[8] = {a0.x, a0.y, a0.z, a0.w, a1.x, a1.y, a1.z, a1.w};
#pragma unroll
            for (int r = 0; r < 8; r++) {
                acc[r][0] = fmaf(a8[r], w0, acc[r][0]);
                acc[r][1] = fmaf(a8[r], w1, acc[r][1]);
                acc[r][2] = fmaf(a8[r], w2, acc[r][2]);
            }
        }
    }

    // epilogue: h2 stores + as2/ad2 dot reductions over 16-lane cg groups
    float wa[3], wd[3];
#pragma unroll
    for (int j = 0; j < 3; j++) {
        int col = cg * 3 + j;
        wa[j] = (col < CLS) ? aws[col] : 0.f;
        wd[j] = (col < CLS) ? awd[col] : 0.f;
    }
#pragma unroll
    for (int r = 0; r < 8; r++) {
        int row = m0 + rt * 8 + r;
        bool ok = row < NN;
        float ps = acc[r][0] * wa[0] + acc[r][1] * wa[1] + acc[r][2] * wa[2];
        float pd = acc[r][0] * wd[0] + acc[r][1] * wd[1] + acc[r][2] * wd[2];
#pragma unroll
        for (int s = 1; s < 16; s <<= 1) {
            ps += __shfl_xor(ps, s);
            pd += __shfl_xor(pd, s);
        }
        if (ok) {
#pragma unroll
            for (int j = 0; j < 3; j++) {
                int col = cg * 3 + j;
                if (col < CLS) h2[(size_t)row * CLS + col] = acc[r][j];
            }
            if (cg == 0) {
                as2[row] = ps;
                ad2[row] = pd;
            }
        }
    }
}

// ---------------- layer 2 aggregation + fused log_softmax ----------------

__global__ __launch_bounds__(256) void k_agg2(const float* __restrict__ h2,
                                              const float* __restrict__ as2,
                                              const float* __restrict__ ad2,
                                              const int* __restrict__ offs,
                                              const int* __restrict__ ssrc,
                                              const float* __restrict__ b2,
                                              float* __restrict__ out) {
    int lane = threadIdx.x & 63;
    int node = blockIdx.x * 4 + (threadIdx.x >> 6);
    int beg = offs[node];
    int end = (node + 1 < NN) ? offs[node + 1] : NE;
    float adh = ad2[node];
    bool act = lane < CLS;
    float m = -INFINITY, l = 0.f, acc = 0.f;
    int nsrc = (beg < end) ? ssrc[beg] : 0;
    float nas = as2[nsrc];
    for (int j = beg; j < end; j++) {
        int src = nsrc;
        float asv = nas;
        if (j + 1 < end) {
            nsrc = ssrc[j + 1];
            nas = as2[nsrc];
        }
        float hv = act ? h2[(size_t)src * CLS + lane] : 0.f;
        float e = asv + adh;
        e = e > 0.f ? e : 0.2f * e;
        float nm = fmaxf(m, e);
        float sc = __expf(m - nm);
        float p = __expf(e - nm);
        m = nm;
        l = l * sc + p;
        acc = fmaf(p, hv, acc * sc);
    }
    float v = act ? (acc / (l + EPSF) + b2[lane]) : -INFINITY;
    float mx = v;
#pragma unroll
    for (int s = 32; s >= 1; s >>= 1) mx = fmaxf(mx, __shfl_xor(mx, s));
    float ex = act ? __expf(v - mx) : 0.f;
    float sum = ex;
#pragma unroll
    for (int s = 32; s >= 1; s >>= 1) sum += __shfl_xor(sum, s);
    if (act) out[(size_t)node * CLS + lane] = v - mx - __logf(sum);
}

// ---------------- launch ----------------

extern "C" void kernel_launch(void* const* d_in, const int* in_sizes, int n_in,
                              void* d_out, int out_size, void* d_ws, size_t ws_size,
                              hipStream_t stream) {
    const float* x    = (const float*)d_in[0];
    const int*   ei   = (const int*)d_in[1];
    const float* W1   = (const float*)d_in[2];
    const float* as1w = (const float*)d_in[3];
    const float* ad1w = (const float*)d_in[4];
    const float* b1   = (const float*)d_in[5];
    const float* W2   = (const float*)d_in[6];
    const float* as2w = (const float*)d_in[7];
    const float* ad2w = (const float*)d_in[8];
    const float* b2   = (const float*)d_in[9];
    float* out = (float*)d_out;

    char* p = (char*)d_ws;
    auto alloc = [&](size_t bytes) {
        char* r = p;
        p += (bytes + 255) & ~(size_t)255;
        return r;
    };
    float* h1   = (float*)alloc((size_t)NN * C1 * 4);
    float* g1   = (float*)alloc((size_t)NN * C1 * 4);
    float* h2   = (float*)alloc((size_t)NN * CLS * 4);
    float* as1  = (float*)alloc((size_t)NN * 4 * 4);
    float* ad1  = (float*)alloc((size_t)NN * 4 * 4);
    float* as2  = (float*)alloc((size_t)NN * 4);
    float* ad2  = (float*)alloc((size_t)NN * 4);
    int* counts = (int*)alloc((size_t)NN * 4);
    int* offs   = (int*)alloc((size_t)NN * 4);
    int* cursor = (int*)alloc((size_t)NN * 4);
    int* parts  = (int*)alloc(64 * 4);
    int* ssrc   = (int*)alloc((size_t)NE * 4);

    const int nb_scan = (NN + 1023) / 1024;  // 49

    k_zero<<<(NN + 255) / 256, 256, 0, stream>>>(counts, NN);
    k_hist<<<(NE + 255) / 256, 256, 0, stream>>>(ei, counts);
    k_scan1<<<nb_scan, 1024, 0, stream>>>(counts, offs, parts);
    k_scan2<<<1, 64, 0, stream>>>(parts, nb_scan);
    k_scan3<<<(NN + 255) / 256, 256, 0, stream>>>(offs, parts, cursor);
    k_scatter<<<(NE + 255) / 256, 256, 0, stream>>>(ei, cursor, ssrc);

    k_gemm1<<<(NN + 63) / 64, 256, 0, stream>>>(x, W1, as1w, ad1w, h1, as1, ad1);
    k_agg1<<<NN / 4, 256, 0, stream>>>(h1, as1, ad1, offs, ssrc, b1, g1);

    k_gemm2<<<(NN + 127) / 128, 256, 0, stream>>>(g1, W2, as2w, ad2w, h2, as2, ad2);
    k_agg2<<<NN / 4, 256, 0, stream>>>(h2, as2, ad2, offs, ssrc, b2, out);
}

// Round 4
// 478.300 us; speedup vs baseline: 1.3619x; 1.0715x over previous
//
#include <hip/hip_runtime.h>
#include <math.h>

#define NN 50000
#define NE 800000
#define FIN 128
#define HID 64
#define HEADS 4
#define C1 256   // HEADS*HID
#define CLS 40
#define EPSF 1e-16f

__device__ __forceinline__ unsigned short f2bf(float f) {
    unsigned int u = __float_as_uint(f);
    unsigned int r = (u + 0x7fffu + ((u >> 16) & 1u)) >> 16;   // RNE
    return (unsigned short)r;
}
__device__ __forceinline__ float bflo(unsigned int u) { return __uint_as_float(u << 16); }
__device__ __forceinline__ float bfhi(unsigned int u) { return __uint_as_float(u & 0xffff0000u); }

// ---------------- counting sort of edges by dst ----------------

__global__ void k_zero(int* a, int n) {
    int i = blockIdx.x * 256 + threadIdx.x;
    if (i < n) a[i] = 0;
}

__global__ void k_hist(const int* __restrict__ ei, int* __restrict__ counts) {
    int i = blockIdx.x * 256 + threadIdx.x;
    if (i < NE) atomicAdd(&counts[ei[NE + i]], 1);
}

__global__ __launch_bounds__(1024) void k_scan1(const int* __restrict__ counts,
                                                int* __restrict__ offs,
                                                int* __restrict__ partials) {
    __shared__ int s[1024];
    int t = threadIdx.x;
    int g = blockIdx.x * 1024 + t;
    int v = (g < NN) ? counts[g] : 0;
    s[t] = v;
    __syncthreads();
    for (int d = 1; d < 1024; d <<= 1) {
        int x = (t >= d) ? s[t - d] : 0;
        __syncthreads();
        s[t] += x;
        __syncthreads();
    }
    if (g < NN) offs[g] = s[t] - v;             // block-local exclusive
    if (t == 1023) partials[blockIdx.x] = s[t]; // block total
}

__global__ void k_scan2(int* partials, int nb) {
    if (threadIdx.x == 0 && blockIdx.x == 0) {
        int run = 0;
        for (int b = 0; b < nb; b++) { int v = partials[b]; partials[b] = run; run += v; }
    }
}

__global__ void k_scan3(int* __restrict__ offs, const int* __restrict__ partials,
                        int* __restrict__ cursor) {
    int g = blockIdx.x * 256 + threadIdx.x;
    if (g < NN) {
        int o = offs[g] + partials[g >> 10];
        offs[g] = o;
        cursor[g] = o;
    }
}

__global__ void k_scatter(const int* __restrict__ ei, int* __restrict__ cursor,
                          int* __restrict__ ssrc) {
    int i = blockIdx.x * 256 + threadIdx.x;
    if (i < NE) {
        int s = ei[i];
        int d = ei[NE + i];
        int p = atomicAdd(&cursor[d], 1);
        ssrc[p] = s;
    }
}

// ---------------- layer 1: register-tiled GEMM + fused alpha dots --------
// Block tile 64 rows x 256 cols, BK=32. Output: bf16 h1b (messages) + fp32
// as1/ad1 (attention dots, computed from fp32 accumulators).
__global__ __launch_bounds__(256) void k_gemm1(const float* __restrict__ x,
                                               const float* __restrict__ W,
                                               const float* __restrict__ aws,
                                               const float* __restrict__ awd,
                                               unsigned short* __restrict__ h1b,
                                               float* __restrict__ as1,
                                               float* __restrict__ ad1) {
    __shared__ float As[32 * 68];    // [kk][row<64], stride 68
    __shared__ float Bs[32 * 256];   // [kk][col]
    int t = threadIdx.x;
    int m0 = blockIdx.x * 64;
    int cg = t & 63;
    int rt = t >> 6;

    float acc[16][4];
#pragma unroll
    for (int r = 0; r < 16; r++)
#pragma unroll
        for (int i = 0; i < 4; i++) acc[r][i] = 0.f;

    int a_kkg = t & 7;          // k f4-group within chunk
    int a_row = t >> 3;         // 0..31 ; +i*32
    int b_bc = t & 63;          // col f4
    int b_br = t >> 6;          // 0..3 ; +i*4

    for (int k0 = 0; k0 < FIN; k0 += 32) {
        float4 av[2], bv[8];
#pragma unroll
        for (int i = 0; i < 2; i++) {
            int row = a_row + i * 32;
            int grow = m0 + row;
            if (grow >= NN) grow = NN - 1;
            av[i] = *(const float4*)(x + (size_t)grow * FIN + k0 + a_kkg * 4);
        }
#pragma unroll
        for (int i = 0; i < 8; i++) {
            int br = b_br + i * 4;
            bv[i] = *(const float4*)(W + (size_t)(k0 + br) * C1 + b_bc * 4);
        }
        __syncthreads();
#pragma unroll
        for (int i = 0; i < 2; i++) {
            int row = a_row + i * 32;
            As[(a_kkg * 4 + 0) * 68 + row] = av[i].x;
            As[(a_kkg * 4 + 1) * 68 + row] = av[i].y;
            As[(a_kkg * 4 + 2) * 68 + row] = av[i].z;
            As[(a_kkg * 4 + 3) * 68 + row] = av[i].w;
        }
#pragma unroll
        for (int i = 0; i < 8; i++) {
            int br = b_br + i * 4;
            *(float4*)&Bs[br * 256 + b_bc * 4] = bv[i];
        }
        __syncthreads();
#pragma unroll 8
        for (int kk = 0; kk < 32; kk++) {
            float4 b4 = *(const float4*)&Bs[kk * 256 + cg * 4];
            float4 a4[4];
#pragma unroll
            for (int j = 0; j < 4; j++)
                a4[j] = *(const float4*)&As[kk * 68 + rt * 16 + j * 4];
#pragma unroll
            for (int j = 0; j < 4; j++) {
                float ar4[4] = {a4[j].x, a4[j].y, a4[j].z, a4[j].w};
#pragma unroll
                for (int rr = 0; rr < 4; rr++) {
                    int r = j * 4 + rr;
                    acc[r][0] = fmaf(ar4[rr], b4.x, acc[r][0]);
                    acc[r][1] = fmaf(ar4[rr], b4.y, acc[r][1]);
                    acc[r][2] = fmaf(ar4[rr], b4.z, acc[r][2]);
                    acc[r][3] = fmaf(ar4[rr], b4.w, acc[r][3]);
                }
            }
        }
    }

    // epilogue: bf16 message store + head-dot reductions (head = 16-lane group)
    int head = cg >> 4;
    float4 wsv = *(const float4*)(aws + cg * 4);
    float4 wdv = *(const float4*)(awd + cg * 4);
#pragma unroll
    for (int r = 0; r < 16; r++) {
        int row = m0 + rt * 16 + r;
        bool ok = row < NN;
        float4 o = {acc[r][0], acc[r][1], acc[r][2], acc[r][3]};
        if (ok) {
            ushort4 hb;
            hb.x = f2bf(o.x); hb.y = f2bf(o.y); hb.z = f2bf(o.z); hb.w = f2bf(o.w);
            *(ushort4*)(h1b + (size_t)row * C1 + cg * 4) = hb;
        }
        float ps = o.x * wsv.x + o.y * wsv.y + o.z * wsv.z + o.w * wsv.w;
        float pd = o.x * wdv.x + o.y * wdv.y + o.z * wdv.z + o.w * wdv.w;
#pragma unroll
        for (int s = 1; s < 16; s <<= 1) {
            ps += __shfl_xor(ps, s);
            pd += __shfl_xor(pd, s);
        }
        if (ok && (cg & 15) == 0) {
            as1[row * 4 + head] = ps;
            ad1[row * 4 + head] = pd;
        }
    }
}

// ---------------- layer 1 aggregation (wave per dst, online softmax) -----
// bf16 gather: 8 B/lane (uint2), 512 B/row fully coalesced.

__global__ __launch_bounds__(256) void k_agg1(const unsigned short* __restrict__ h1b,
                                              const float* __restrict__ as1,
                                              const float* __restrict__ ad1,
                                              const int* __restrict__ offs,
                                              const int* __restrict__ ssrc,
                                              const float* __restrict__ b1,
                                              float* __restrict__ g1) {
    int lane = threadIdx.x & 63;
    int node = blockIdx.x * 4 + (threadIdx.x >> 6);
    int head = lane >> 4;
    int beg = offs[node];
    int end = (node + 1 < NN) ? offs[node + 1] : NE;
    float adh = ad1[node * 4 + head];
    float m = -INFINITY, l = 0.f;
    float4 acc = {0.f, 0.f, 0.f, 0.f};
    const uint2* hv4 = (const uint2*)h1b;   // 64 uint2 per row
    int nsrc = (beg < end) ? ssrc[beg] : 0;
    float nas = as1[nsrc * 4 + head];
    for (int j = beg; j < end; j++) {
        int src = nsrc;
        float asv = nas;
        if (j + 1 < end) {
            nsrc = ssrc[j + 1];
            nas = as1[nsrc * 4 + head];
        }
        uint2 hv = hv4[(size_t)src * 64 + lane];
        float e = asv + adh;
        e = e > 0.f ? e : 0.2f * e;
        float nm = fmaxf(m, e);
        float sc = __expf(m - nm);
        float p = __expf(e - nm);
        m = nm;
        l = l * sc + p;
        acc.x = fmaf(p, bflo(hv.x), acc.x * sc);
        acc.y = fmaf(p, bfhi(hv.x), acc.y * sc);
        acc.z = fmaf(p, bflo(hv.y), acc.z * sc);
        acc.w = fmaf(p, bfhi(hv.y), acc.w * sc);
    }
    float inv = 1.f / (l + EPSF);
    float4 b = ((const float4*)b1)[lane];
    float4 o;
    o.x = fmaxf(fmaf(acc.x, inv, b.x), 0.f);
    o.y = fmaxf(fmaf(acc.y, inv, b.y), 0.f);
    o.z = fmaxf(fmaf(acc.z, inv, b.z), 0.f);
    o.w = fmaxf(fmaf(acc.w, inv, b.w), 0.f);
    ((float4*)g1)[(size_t)node * 64 + lane] = o;
}

// ---------------- layer 2: register-tiled GEMM + fused alpha2 ------------
// Block tile 128 rows x 48 cols (40 real, zero-padded). Whole W2 in LDS.
// Outputs bf16 h2b (messages) + fp32 as2/ad2.
__global__ __launch_bounds__(256) void k_gemm2(const float* __restrict__ g1,
                                               const float* __restrict__ W2,
                                               const float* __restrict__ aws,
                                               const float* __restrict__ awd,
                                               unsigned short* __restrict__ h2b,
                                               float* __restrict__ as2,
                                               float* __restrict__ ad2) {
    __shared__ float Ws[256 * 48];   // zero-padded cols
    __shared__ float As[32 * 132];   // [kk][row<128], stride 132
    int t = threadIdx.x;
    int m0 = blockIdx.x * 128;
    int cg = t & 15;
    int rt = t >> 4;

#pragma unroll
    for (int i = 0; i < 12; i++) {
        int idx = i * 256 + t;          // f4 slot, 3072 total
        int kk = idx / 12;
        int c4 = idx % 12;
        float4 v = {0.f, 0.f, 0.f, 0.f};
        if (c4 < 10) v = *(const float4*)(W2 + kk * CLS + c4 * 4);
        *(float4*)&Ws[kk * 48 + c4 * 4] = v;
    }

    float acc[8][3];
#pragma unroll
    for (int r = 0; r < 8; r++)
#pragma unroll
        for (int i = 0; i < 3; i++) acc[r][i] = 0.f;

    int a_kkg = t & 7;
    int a_row = t >> 3;   // 0..31 ; +i*32

    for (int k0 = 0; k0 < C1; k0 += 32) {
        float4 av[4];
#pragma unroll
        for (int i = 0; i < 4; i++) {
            int row = a_row + i * 32;
            int grow = m0 + row;
            if (grow >= NN) grow = NN - 1;
            av[i] = *(const float4*)(g1 + (size_t)grow * C1 + k0 + a_kkg * 4);
        }
        __syncthreads();
#pragma unroll
        for (int i = 0; i < 4; i++) {
            int row = a_row + i * 32;
            As[(a_kkg * 4 + 0) * 132 + row] = av[i].x;
            As[(a_kkg * 4 + 1) * 132 + row] = av[i].y;
            As[(a_kkg * 4 + 2) * 132 + row] = av[i].z;
            As[(a_kkg * 4 + 3) * 132 + row] = av[i].w;
        }
        __syncthreads();
#pragma unroll 8
        for (int kk = 0; kk < 32; kk++) {
            float4 a0 = *(const float4*)&As[kk * 132 + rt * 8];
            float4 a1 = *(const float4*)&As[kk * 132 + rt * 8 + 4];
            float w0 = Ws[(k0 + kk) * 48 + cg * 3 + 0];
            float w1 = Ws[(k0 + kk) * 48 + cg * 3 + 1];
            float w2 = Ws[(k0 + kk) * 48 + cg * 3 + 2];
            float a8[8] = {a0.x, a0.y, a0.z, a0.w, a1.x, a1.y, a1.z, a1.w};
#pragma unroll
            for (int r = 0; r < 8; r++) {
                acc[r][0] = fmaf(a8[r], w0, acc[r][0]);
                acc[r][1] = fmaf(a8[r], w1, acc[r][1]);
                acc[r][2] = fmaf(a8[r], w2, acc[r][2]);
            }
        }
    }

    float wa[3], wd[3];
#pragma unroll
    for (int j = 0; j < 3; j++) {
        int col = cg * 3 + j;
        wa[j] = (col < CLS) ? aws[col] : 0.f;
        wd[j] = (col < CLS) ? awd[col] : 0.f;
    }
#pragma unroll
    for (int r = 0; r < 8; r++) {
        int row = m0 + rt * 8 + r;
        bool ok = row < NN;
        float ps = acc[r][0] * wa[0] + acc[r][1] * wa[1] + acc[r][2] * wa[2];
        float pd = acc[r][0] * wd[0] + acc[r][1] * wd[1] + acc[r][2] * wd[2];
#pragma unroll
        for (int s = 1; s < 16; s <<= 1) {
            ps += __shfl_xor(ps, s);
            pd += __shfl_xor(pd, s);
        }
        if (ok) {
#pragma unroll
            for (int j = 0; j < 3; j++) {
                int col = cg * 3 + j;
                if (col < CLS) h2b[(size_t)row * CLS + col] = f2bf(acc[r][j]);
            }
            if (cg == 0) {
                as2[row] = ps;
                ad2[row] = pd;
            }
        }
    }
}

// ---------------- layer 2 aggregation + fused log_softmax ----------------

__global__ __launch_bounds__(256) void k_agg2(const unsigned short* __restrict__ h2b,
                                              const float* __restrict__ as2,
                                              const float* __restrict__ ad2,
                                              const int* __restrict__ offs,
                                              const int* __restrict__ ssrc,
                                              const float* __restrict__ b2,
                                              float* __restrict__ out) {
    int lane = threadIdx.x & 63;
    int node = blockIdx.x * 4 + (threadIdx.x >> 6);
    int beg = offs[node];
    int end = (node + 1 < NN) ? offs[node + 1] : NE;
    float adh = ad2[node];
    bool act = lane < CLS;
    float m = -INFINITY, l = 0.f, acc = 0.f;
    int nsrc = (beg < end) ? ssrc[beg] : 0;
    float nas = as2[nsrc];
    for (int j = beg; j < end; j++) {
        int src = nsrc;
        float asv = nas;
        if (j + 1 < end) {
            nsrc = ssrc[j + 1];
            nas = as2[nsrc];
        }
        unsigned int hu = act ? (unsigned int)h2b[(size_t)src * CLS + lane] : 0u;
        float e = asv + adh;
        e = e > 0.f ? e : 0.2f * e;
        float nm = fmaxf(m, e);
        float sc = __expf(m - nm);
        float p = __expf(e - nm);
        m = nm;
        l = l * sc + p;
        acc = fmaf(p, __uint_as_float(hu << 16), acc * sc);
    }
    float v = act ? (acc / (l + EPSF) + b2[lane]) : -INFINITY;
    float mx = v;
#pragma unroll
    for (int s = 32; s >= 1; s >>= 1) mx = fmaxf(mx, __shfl_xor(mx, s));
    float ex = act ? __expf(v - mx) : 0.f;
    float sum = ex;
#pragma unroll
    for (int s = 32; s >= 1; s >>= 1) sum += __shfl_xor(sum, s);
    if (act) out[(size_t)node * CLS + lane] = v - mx - __logf(sum);
}

// ---------------- launch ----------------

extern "C" void kernel_launch(void* const* d_in, const int* in_sizes, int n_in,
                              void* d_out, int out_size, void* d_ws, size_t ws_size,
                              hipStream_t stream) {
    const float* x    = (const float*)d_in[0];
    const int*   ei   = (const int*)d_in[1];
    const float* W1   = (const float*)d_in[2];
    const float* as1w = (const float*)d_in[3];
    const float* ad1w = (const float*)d_in[4];
    const float* b1   = (const float*)d_in[5];
    const float* W2   = (const float*)d_in[6];
    const float* as2w = (const float*)d_in[7];
    const float* ad2w = (const float*)d_in[8];
    const float* b2   = (const float*)d_in[9];
    float* out = (float*)d_out;

    char* p = (char*)d_ws;
    auto alloc = [&](size_t bytes) {
        char* r = p;
        p += (bytes + 255) & ~(size_t)255;
        return r;
    };
    unsigned short* h1b = (unsigned short*)alloc((size_t)NN * C1 * 2);
    float* g1   = (float*)alloc((size_t)NN * C1 * 4);
    unsigned short* h2b = (unsigned short*)alloc((size_t)NN * CLS * 2);
    float* as1  = (float*)alloc((size_t)NN * 4 * 4);
    float* ad1  = (float*)alloc((size_t)NN * 4 * 4);
    float* as2  = (float*)alloc((size_t)NN * 4);
    float* ad2  = (float*)alloc((size_t)NN * 4);
    int* counts = (int*)alloc((size_t)NN * 4);
    int* offs   = (int*)alloc((size_t)NN * 4);
    int* cursor = (int*)alloc((size_t)NN * 4);
    int* parts  = (int*)alloc(64 * 4);
    int* ssrc   = (int*)alloc((size_t)NE * 4);

    const int nb_scan = (NN + 1023) / 1024;  // 49

    k_zero<<<(NN + 255) / 256, 256, 0, stream>>>(counts, NN);
    k_hist<<<(NE + 255) / 256, 256, 0, stream>>>(ei, counts);
    k_scan1<<<nb_scan, 1024, 0, stream>>>(counts, offs, parts);
    k_scan2<<<1, 64, 0, stream>>>(parts, nb_scan);
    k_scan3<<<(NN + 255) / 256, 256, 0, stream>>>(offs, parts, cursor);
    k_scatter<<<(NE + 255) / 256, 256, 0, stream>>>(ei, cursor, ssrc);

    k_gemm1<<<(NN + 63) / 64, 256, 0, stream>>>(x, W1, as1w, ad1w, h1b, as1, ad1);
    k_agg1<<<NN / 4, 256, 0, stream>>>(h1b, as1, ad1, offs, ssrc, b1, g1);

    k_gemm2<<<(NN + 127) / 128, 256, 0, stream>>>(g1, W2, as2w, ad2w, h2b, as2, ad2);
    k_agg2<<<NN / 4, 256, 0, stream>>>(h2b, as2, ad2, offs, ssrc, b2, out);
}

// Round 5
// 467.425 us; speedup vs baseline: 1.3935x; 1.0233x over previous
//
#include <hip/hip_runtime.h>
#include <math.h>

#define NN 50000
#define NE 800000
#define FIN 128
#define HID 64
#define HEADS 4
#define C1 256   // HEADS*HID
#define CLS 40
#define EPSF 1e-16f

__device__ __forceinline__ unsigned short f2bf(float f) {
    unsigned int u = __float_as_uint(f);
    unsigned int r = (u + 0x7fffu + ((u >> 16) & 1u)) >> 16;   // RNE
    return (unsigned short)r;
}
__device__ __forceinline__ float bflo(unsigned int u) { return __uint_as_float(u << 16); }
__device__ __forceinline__ float bfhi(unsigned int u) { return __uint_as_float(u & 0xffff0000u); }

// ---------------- counting sort of edges by dst ----------------

__global__ void k_zero(int* a, int n) {
    int i = blockIdx.x * 256 + threadIdx.x;
    if (i < n) a[i] = 0;
}

__global__ void k_hist(const int* __restrict__ ei, int* __restrict__ counts) {
    int i = blockIdx.x * 256 + threadIdx.x;
    if (i < NE) atomicAdd(&counts[ei[NE + i]], 1);
}

__global__ __launch_bounds__(1024) void k_scan1(const int* __restrict__ counts,
                                                int* __restrict__ offs,
                                                int* __restrict__ partials) {
    __shared__ int s[1024];
    int t = threadIdx.x;
    int g = blockIdx.x * 1024 + t;
    int v = (g < NN) ? counts[g] : 0;
    s[t] = v;
    __syncthreads();
    for (int d = 1; d < 1024; d <<= 1) {
        int x = (t >= d) ? s[t - d] : 0;
        __syncthreads();
        s[t] += x;
        __syncthreads();
    }
    if (g < NN) offs[g] = s[t] - v;             // block-local exclusive
    if (t == 1023) partials[blockIdx.x] = s[t]; // block total
}

__global__ void k_scan2(int* partials, int nb) {
    if (threadIdx.x == 0 && blockIdx.x == 0) {
        int run = 0;
        for (int b = 0; b < nb; b++) { int v = partials[b]; partials[b] = run; run += v; }
    }
}

__global__ void k_scan3(int* __restrict__ offs, const int* __restrict__ partials,
                        int* __restrict__ cursor) {
    int g = blockIdx.x * 256 + threadIdx.x;
    if (g < NN) {
        int o = offs[g] + partials[g >> 10];
        offs[g] = o;
        cursor[g] = o;
    }
}

__global__ void k_scatter(const int* __restrict__ ei, int* __restrict__ cursor,
                          int* __restrict__ ssrc) {
    int i = blockIdx.x * 256 + threadIdx.x;
    if (i < NE) {
        int s = ei[i];
        int d = ei[NE + i];
        int p = atomicAdd(&cursor[d], 1);
        ssrc[p] = s;
    }
}

// ---------------- layer 1: register-tiled GEMM + fused alpha dots --------
__global__ __launch_bounds__(256) void k_gemm1(const float* __restrict__ x,
                                               const float* __restrict__ W,
                                               const float* __restrict__ aws,
                                               const float* __restrict__ awd,
                                               unsigned short* __restrict__ h1b,
                                               float* __restrict__ as1,
                                               float* __restrict__ ad1) {
    __shared__ float As[32 * 68];    // [kk][row<64], stride 68
    __shared__ float Bs[32 * 256];   // [kk][col]
    int t = threadIdx.x;
    int m0 = blockIdx.x * 64;
    int cg = t & 63;
    int rt = t >> 6;

    float acc[16][4];
#pragma unroll
    for (int r = 0; r < 16; r++)
#pragma unroll
        for (int i = 0; i < 4; i++) acc[r][i] = 0.f;

    int a_kkg = t & 7;          // k f4-group within chunk
    int a_row = t >> 3;         // 0..31 ; +i*32
    int b_bc = t & 63;          // col f4
    int b_br = t >> 6;          // 0..3 ; +i*4

    for (int k0 = 0; k0 < FIN; k0 += 32) {
        float4 av[2], bv[8];
#pragma unroll
        for (int i = 0; i < 2; i++) {
            int row = a_row + i * 32;
            int grow = m0 + row;
            if (grow >= NN) grow = NN - 1;
            av[i] = *(const float4*)(x + (size_t)grow * FIN + k0 + a_kkg * 4);
        }
#pragma unroll
        for (int i = 0; i < 8; i++) {
            int br = b_br + i * 4;
            bv[i] = *(const float4*)(W + (size_t)(k0 + br) * C1 + b_bc * 4);
        }
        __syncthreads();
#pragma unroll
        for (int i = 0; i < 2; i++) {
            int row = a_row + i * 32;
            As[(a_kkg * 4 + 0) * 68 + row] = av[i].x;
            As[(a_kkg * 4 + 1) * 68 + row] = av[i].y;
            As[(a_kkg * 4 + 2) * 68 + row] = av[i].z;
            As[(a_kkg * 4 + 3) * 68 + row] = av[i].w;
        }
#pragma unroll
        for (int i = 0; i < 8; i++) {
            int br = b_br + i * 4;
            *(float4*)&Bs[br * 256 + b_bc * 4] = bv[i];
        }
        __syncthreads();
#pragma unroll 8
        for (int kk = 0; kk < 32; kk++) {
            float4 b4 = *(const float4*)&Bs[kk * 256 + cg * 4];
            float4 a4[4];
#pragma unroll
            for (int j = 0; j < 4; j++)
                a4[j] = *(const float4*)&As[kk * 68 + rt * 16 + j * 4];
#pragma unroll
            for (int j = 0; j < 4; j++) {
                float ar4[4] = {a4[j].x, a4[j].y, a4[j].z, a4[j].w};
#pragma unroll
                for (int rr = 0; rr < 4; rr++) {
                    int r = j * 4 + rr;
                    acc[r][0] = fmaf(ar4[rr], b4.x, acc[r][0]);
                    acc[r][1] = fmaf(ar4[rr], b4.y, acc[r][1]);
                    acc[r][2] = fmaf(ar4[rr], b4.z, acc[r][2]);
                    acc[r][3] = fmaf(ar4[rr], b4.w, acc[r][3]);
                }
            }
        }
    }

    // epilogue: bf16 message store + head-dot reductions (head = 16-lane group)
    int head = cg >> 4;
    float4 wsv = *(const float4*)(aws + cg * 4);
    float4 wdv = *(const float4*)(awd + cg * 4);
#pragma unroll
    for (int r = 0; r < 16; r++) {
        int row = m0 + rt * 16 + r;
        bool ok = row < NN;
        float4 o = {acc[r][0], acc[r][1], acc[r][2], acc[r][3]};
        if (ok) {
            ushort4 hb;
            hb.x = f2bf(o.x); hb.y = f2bf(o.y); hb.z = f2bf(o.z); hb.w = f2bf(o.w);
            *(ushort4*)(h1b + (size_t)row * C1 + cg * 4) = hb;
        }
        float ps = o.x * wsv.x + o.y * wsv.y + o.z * wsv.z + o.w * wsv.w;
        float pd = o.x * wdv.x + o.y * wdv.y + o.z * wdv.z + o.w * wdv.w;
#pragma unroll
        for (int s = 1; s < 16; s <<= 1) {
            ps += __shfl_xor(ps, s);
            pd += __shfl_xor(pd, s);
        }
        if (ok && (cg & 15) == 0) {
            as1[row * 4 + head] = ps;
            ad1[row * 4 + head] = pd;
        }
    }
}

// ---------------- layer 1 aggregation -----------------------------------
// Wave per dst node. No max-subtraction (logits are O(10) max: exp safe in
// fp32 and exactly equivalent after normalization). 4-slot rotating prefetch
// keeps 3 gathers in flight while computing.
__global__ __launch_bounds__(256) void k_agg1(const unsigned short* __restrict__ h1b,
                                              const float* __restrict__ as1,
                                              const float* __restrict__ ad1,
                                              const int* __restrict__ offs,
                                              const int* __restrict__ ssrc,
                                              const float* __restrict__ b1,
                                              float* __restrict__ g1) {
    int lane = threadIdx.x & 63;
    int node = blockIdx.x * 4 + (threadIdx.x >> 6);
    int head = lane >> 4;
    int beg = offs[node];
    int end = (node + 1 < NN) ? offs[node + 1] : NE;
    float adh = ad1[node * 4 + head];
    float l = 0.f;
    float4 acc = {0.f, 0.f, 0.f, 0.f};
    const uint2* hv4 = (const uint2*)h1b;   // 64 uint2 per row

    uint2 hb[4];
    float ab[4];
#pragma unroll
    for (int i = 0; i < 4; i++) {
        int jj = beg + i;
        if (jj < end) {
            int s = ssrc[jj];
            ab[i] = as1[s * 4 + head];
            hb[i] = hv4[(size_t)s * 64 + lane];
        }
    }
    for (int j = beg; j < end; j += 4) {
#pragma unroll
        for (int i = 0; i < 4; i++) {
            if (j + i < end) {
                uint2 hc = hb[i];
                float ac = ab[i];
                int pj = j + i + 4;
                if (pj < end) {
                    int s = ssrc[pj];
                    ab[i] = as1[s * 4 + head];
                    hb[i] = hv4[(size_t)s * 64 + lane];
                }
                float e = ac + adh;
                e = e > 0.f ? e : 0.2f * e;
                float p = __expf(e);
                l += p;
                acc.x = fmaf(p, bflo(hc.x), acc.x);
                acc.y = fmaf(p, bfhi(hc.x), acc.y);
                acc.z = fmaf(p, bflo(hc.y), acc.z);
                acc.w = fmaf(p, bfhi(hc.y), acc.w);
            }
        }
    }
    float inv = 1.f / (l + EPSF);
    float4 b = ((const float4*)b1)[lane];
    float4 o;
    o.x = fmaxf(fmaf(acc.x, inv, b.x), 0.f);
    o.y = fmaxf(fmaf(acc.y, inv, b.y), 0.f);
    o.z = fmaxf(fmaf(acc.z, inv, b.z), 0.f);
    o.w = fmaxf(fmaf(acc.w, inv, b.w), 0.f);
    ((float4*)g1)[(size_t)node * 64 + lane] = o;
}

// ---------------- layer 2: register-tiled GEMM + fused alpha2 ------------
__global__ __launch_bounds__(256) void k_gemm2(const float* __restrict__ g1,
                                               const float* __restrict__ W2,
                                               const float* __restrict__ aws,
                                               const float* __restrict__ awd,
                                               unsigned short* __restrict__ h2b,
                                               float* __restrict__ as2,
                                               float* __restrict__ ad2) {
    __shared__ float Ws[256 * 48];   // zero-padded cols
    __shared__ float As[32 * 132];   // [kk][row<128], stride 132
    int t = threadIdx.x;
    int m0 = blockIdx.x * 128;
    int cg = t & 15;
    int rt = t >> 4;

#pragma unroll
    for (int i = 0; i < 12; i++) {
        int idx = i * 256 + t;          // f4 slot, 3072 total
        int kk = idx / 12;
        int c4 = idx % 12;
        float4 v = {0.f, 0.f, 0.f, 0.f};
        if (c4 < 10) v = *(const float4*)(W2 + kk * CLS + c4 * 4);
        *(float4*)&Ws[kk * 48 + c4 * 4] = v;
    }

    float acc[8][3];
#pragma unroll
    for (int r = 0; r < 8; r++)
#pragma unroll
        for (int i = 0; i < 3; i++) acc[r][i] = 0.f;

    int a_kkg = t & 7;
    int a_row = t >> 3;   // 0..31 ; +i*32

    for (int k0 = 0; k0 < C1; k0 += 32) {
        float4 av[4];
#pragma unroll
        for (int i = 0; i < 4; i++) {
            int row = a_row + i * 32;
            int grow = m0 + row;
            if (grow >= NN) grow = NN - 1;
            av[i] = *(const float4*)(g1 + (size_t)grow * C1 + k0 + a_kkg * 4);
        }
        __syncthreads();
#pragma unroll
        for (int i = 0; i < 4; i++) {
            int row = a_row + i * 32;
            As[(a_kkg * 4 + 0) * 132 + row] = av[i].x;
            As[(a_kkg * 4 + 1) * 132 + row] = av[i].y;
            As[(a_kkg * 4 + 2) * 132 + row] = av[i].z;
            As[(a_kkg * 4 + 3) * 132 + row] = av[i].w;
        }
        __syncthreads();
#pragma unroll 8
        for (int kk = 0; kk < 32; kk++) {
            float4 a0 = *(const float4*)&As[kk * 132 + rt * 8];
            float4 a1 = *(const float4*)&As[kk * 132 + rt * 8 + 4];
            float w0 = Ws[(k0 + kk) * 48 + cg * 3 + 0];
            float w1 = Ws[(k0 + kk) * 48 + cg * 3 + 1];
            float w2 = Ws[(k0 + kk) * 48 + cg * 3 + 2];
            float a8[8] = {a0.x, a0.y, a0.z, a0.w, a1.x, a1.y, a1.z, a1.w};
#pragma unroll
            for (int r = 0; r < 8; r++) {
                acc[r][0] = fmaf(a8[r], w0, acc[r][0]);
                acc[r][1] = fmaf(a8[r], w1, acc[r][1]);
                acc[r][2] = fmaf(a8[r], w2, acc[r][2]);
            }
        }
    }

    float wa[3], wd[3];
#pragma unroll
    for (int j = 0; j < 3; j++) {
        int col = cg * 3 + j;
        wa[j] = (col < CLS) ? aws[col] : 0.f;
        wd[j] = (col < CLS) ? awd[col] : 0.f;
    }
#pragma unroll
    for (int r = 0; r < 8; r++) {
        int row = m0 + rt * 8 + r;
        bool ok = row < NN;
        float ps = acc[r][0] * wa[0] + acc[r][1] * wa[1] + acc[r][2] * wa[2];
        float pd = acc[r][0] * wd[0] + acc[r][1] * wd[1] + acc[r][2] * wd[2];
#pragma unroll
        for (int s = 1; s < 16; s <<= 1) {
            ps += __shfl_xor(ps, s);
            pd += __shfl_xor(pd, s);
        }
        if (ok) {
#pragma unroll
            for (int j = 0; j < 3; j++) {
                int col = cg * 3 + j;
                if (col < CLS) h2b[(size_t)row * CLS + col] = f2bf(acc[r][j]);
            }
            if (cg == 0) {
                as2[row] = ps;
                ad2[row] = pd;
            }
        }
    }
}

// ---------------- layer 2 aggregation + fused log_softmax ----------------
// Same no-max single-pass softmax + 4-slot prefetch. log_softmax keeps its
// own (cheap, per-node) max for stability.
__global__ __launch_bounds__(256) void k_agg2(const unsigned short* __restrict__ h2b,
                                              const float* __restrict__ as2,
                                              const float* __restrict__ ad2,
                                              const int* __restrict__ offs,
                                              const int* __restrict__ ssrc,
                                              const float* __restrict__ b2,
                                              float* __restrict__ out) {
    int lane = threadIdx.x & 63;
    int node = blockIdx.x * 4 + (threadIdx.x >> 6);
    int beg = offs[node];
    int end = (node + 1 < NN) ? offs[node + 1] : NE;
    float adh = ad2[node];
    bool act = lane < CLS;
    float l = 0.f, acc = 0.f;

    unsigned int hbuf[4];
    float ab[4];
#pragma unroll
    for (int i = 0; i < 4; i++) {
        int jj = beg + i;
        if (jj < end) {
            int s = ssrc[jj];
            ab[i] = as2[s];
            hbuf[i] = act ? (unsigned int)h2b[(size_t)s * CLS + lane] : 0u;
        }
    }
    for (int j = beg; j < end; j += 4) {
#pragma unroll
        for (int i = 0; i < 4; i++) {
            if (j + i < end) {
                unsigned int hc = hbuf[i];
                float ac = ab[i];
                int pj = j + i + 4;
                if (pj < end) {
                    int s = ssrc[pj];
                    ab[i] = as2[s];
                    hbuf[i] = act ? (unsigned int)h2b[(size_t)s * CLS + lane] : 0u;
                }
                float e = ac + adh;
                e = e > 0.f ? e : 0.2f * e;
                float p = __expf(e);
                l += p;
                acc = fmaf(p, __uint_as_float(hc << 16), acc);
            }
        }
    }
    float v = act ? (acc / (l + EPSF) + b2[lane]) : -INFINITY;
    float mx = v;
#pragma unroll
    for (int s = 32; s >= 1; s >>= 1) mx = fmaxf(mx, __shfl_xor(mx, s));
    float ex = act ? __expf(v - mx) : 0.f;
    float sum = ex;
#pragma unroll
    for (int s = 32; s >= 1; s >>= 1) sum += __shfl_xor(sum, s);
    if (act) out[(size_t)node * CLS + lane] = v - mx - __logf(sum);
}

// ---------------- launch ----------------

extern "C" void kernel_launch(void* const* d_in, const int* in_sizes, int n_in,
                              void* d_out, int out_size, void* d_ws, size_t ws_size,
                              hipStream_t stream) {
    const float* x    = (const float*)d_in[0];
    const int*   ei   = (const int*)d_in[1];
    const float* W1   = (const float*)d_in[2];
    const float* as1w = (const float*)d_in[3];
    const float* ad1w = (const float*)d_in[4];
    const float* b1   = (const float*)d_in[5];
    const float* W2   = (const float*)d_in[6];
    const float* as2w = (const float*)d_in[7];
    const float* ad2w = (const float*)d_in[8];
    const float* b2   = (const float*)d_in[9];
    float* out = (float*)d_out;

    char* p = (char*)d_ws;
    auto alloc = [&](size_t bytes) {
        char* r = p;
        p += (bytes + 255) & ~(size_t)255;
        return r;
    };
    unsigned short* h1b = (unsigned short*)alloc((size_t)NN * C1 * 2);
    float* g1   = (float*)alloc((size_t)NN * C1 * 4);
    unsigned short* h2b = (unsigned short*)alloc((size_t)NN * CLS * 2);
    float* as1  = (float*)alloc((size_t)NN * 4 * 4);
    float* ad1  = (float*)alloc((size_t)NN * 4 * 4);
    float* as2  = (float*)alloc((size_t)NN * 4);
    float* ad2  = (float*)alloc((size_t)NN * 4);
    int* counts = (int*)alloc((size_t)NN * 4);
    int* offs   = (int*)alloc((size_t)NN * 4);
    int* cursor = (int*)alloc((size_t)NN * 4);
    int* parts  = (int*)alloc(64 * 4);
    int* ssrc   = (int*)alloc((size_t)NE * 4);

    const int nb_scan = (NN + 1023) / 1024;  // 49

    k_zero<<<(NN + 255) / 256, 256, 0, stream>>>(counts, NN);
    k_hist<<<(NE + 255) / 256, 256, 0, stream>>>(ei, counts);
    k_scan1<<<nb_scan, 1024, 0, stream>>>(counts, offs, parts);
    k_scan2<<<1, 64, 0, stream>>>(parts, nb_scan);
    k_scan3<<<(NN + 255) / 256, 256, 0, stream>>>(offs, parts, cursor);
    k_scatter<<<(NE + 255) / 256, 256, 0, stream>>>(ei, cursor, ssrc);

    k_gemm1<<<(NN + 63) / 64, 256, 0, stream>>>(x, W1, as1w, ad1w, h1b, as1, ad1);
    k_agg1<<<NN / 4, 256, 0, stream>>>(h1b, as1, ad1, offs, ssrc, b1, g1);

    k_gemm2<<<(NN + 127) / 128, 256, 0, stream>>>(g1, W2, as2w, ad2w, h2b, as2, ad2);
    k_agg2<<<NN / 4, 256, 0, stream>>>(h2b, as2, ad2, offs, ssrc, b2, out);
}

// Round 6
// 397.658 us; speedup vs baseline: 1.6380x; 1.1754x over previous
//
#include <hip/hip_runtime.h>
#include <math.h>

#define NN 50000
#define NE 800000
#define FIN 128
#define HID 64
#define HEADS 4
#define C1 256   // HEADS*HID
#define CLS 40
#define EPSF 1e-16f

__device__ __forceinline__ unsigned short f2bf(float f) {
    unsigned int u = __float_as_uint(f);
    unsigned int r = (u + 0x7fffu + ((u >> 16) & 1u)) >> 16;   // RNE
    return (unsigned short)r;
}
__device__ __forceinline__ float bflo(unsigned int u) { return __uint_as_float(u << 16); }
__device__ __forceinline__ float bfhi(unsigned int u) { return __uint_as_float(u & 0xffff0000u); }

// ---------------- counting sort of edges by dst ----------------

__global__ void k_zero(int* a, int n) {
    int i = blockIdx.x * 256 + threadIdx.x;
    if (i < n) a[i] = 0;
}

__global__ void k_hist(const int* __restrict__ ei, int* __restrict__ counts) {
    int i = blockIdx.x * 256 + threadIdx.x;
    if (i < NE) atomicAdd(&counts[ei[NE + i]], 1);
}

__global__ __launch_bounds__(1024) void k_scan1(const int* __restrict__ counts,
                                                int* __restrict__ offs,
                                                int* __restrict__ partials) {
    __shared__ int s[1024];
    int t = threadIdx.x;
    int g = blockIdx.x * 1024 + t;
    int v = (g < NN) ? counts[g] : 0;
    s[t] = v;
    __syncthreads();
    for (int d = 1; d < 1024; d <<= 1) {
        int x = (t >= d) ? s[t - d] : 0;
        __syncthreads();
        s[t] += x;
        __syncthreads();
    }
    if (g < NN) offs[g] = s[t] - v;             // block-local exclusive
    if (t == 1023) partials[blockIdx.x] = s[t]; // block total
}

__global__ void k_scan2(int* partials, int nb) {
    if (threadIdx.x == 0 && blockIdx.x == 0) {
        int run = 0;
        for (int b = 0; b < nb; b++) { int v = partials[b]; partials[b] = run; run += v; }
    }
}

__global__ void k_scan3(int* __restrict__ offs, const int* __restrict__ partials,
                        int* __restrict__ cursor) {
    int g = blockIdx.x * 256 + threadIdx.x;
    if (g < NN) {
        int o = offs[g] + partials[g >> 10];
        offs[g] = o;
        cursor[g] = o;
    }
}

__global__ void k_scatter(const int* __restrict__ ei, int* __restrict__ cursor,
                          int* __restrict__ ssrc, int* __restrict__ sdst) {
    int i = blockIdx.x * 256 + threadIdx.x;
    if (i < NE) {
        int s = ei[i];
        int d = ei[NE + i];
        int p = atomicAdd(&cursor[d], 1);
        ssrc[p] = s;
        sdst[p] = d;
    }
}

// ---------------- per-edge softmax weights (coalesced, massively parallel)

__global__ __launch_bounds__(256) void k_ew1(const int* __restrict__ ssrc,
                                             const int* __restrict__ sdst,
                                             const float* __restrict__ as1,
                                             const float* __restrict__ ad1,
                                             float4* __restrict__ pw1) {
    int j = blockIdx.x * 256 + threadIdx.x;
    if (j < NE) {
        int s = ssrc[j], d = sdst[j];
        float4 a = *(const float4*)(as1 + s * 4);
        float4 bb = *(const float4*)(ad1 + d * 4);
        float4 e = {a.x + bb.x, a.y + bb.y, a.z + bb.z, a.w + bb.w};
        e.x = e.x > 0.f ? e.x : 0.2f * e.x;
        e.y = e.y > 0.f ? e.y : 0.2f * e.y;
        e.z = e.z > 0.f ? e.z : 0.2f * e.z;
        e.w = e.w > 0.f ? e.w : 0.2f * e.w;
        float4 p = {__expf(e.x), __expf(e.y), __expf(e.z), __expf(e.w)};
        pw1[j] = p;
    }
}

__global__ __launch_bounds__(256) void k_ew2(const int* __restrict__ ssrc,
                                             const int* __restrict__ sdst,
                                             const float* __restrict__ as2,
                                             const float* __restrict__ ad2,
                                             float* __restrict__ pw2) {
    int j = blockIdx.x * 256 + threadIdx.x;
    if (j < NE) {
        float e = as2[ssrc[j]] + ad2[sdst[j]];
        e = e > 0.f ? e : 0.2f * e;
        pw2[j] = __expf(e);
    }
}

// ---------------- layer 1: register-tiled GEMM + fused alpha dots --------
__global__ __launch_bounds__(256) void k_gemm1(const float* __restrict__ x,
                                               const float* __restrict__ W,
                                               const float* __restrict__ aws,
                                               const float* __restrict__ awd,
                                               unsigned short* __restrict__ h1b,
                                               float* __restrict__ as1,
                                               float* __restrict__ ad1) {
    __shared__ float As[32 * 68];    // [kk][row<64], stride 68
    __shared__ float Bs[32 * 256];   // [kk][col]
    int t = threadIdx.x;
    int m0 = blockIdx.x * 64;
    int cg = t & 63;
    int rt = t >> 6;

    float acc[16][4];
#pragma unroll
    for (int r = 0; r < 16; r++)
#pragma unroll
        for (int i = 0; i < 4; i++) acc[r][i] = 0.f;

    int a_kkg = t & 7;          // k f4-group within chunk
    int a_row = t >> 3;         // 0..31 ; +i*32
    int b_bc = t & 63;          // col f4
    int b_br = t >> 6;          // 0..3 ; +i*4

    for (int k0 = 0; k0 < FIN; k0 += 32) {
        float4 av[2], bv[8];
#pragma unroll
        for (int i = 0; i < 2; i++) {
            int row = a_row + i * 32;
            int grow = m0 + row;
            if (grow >= NN) grow = NN - 1;
            av[i] = *(const float4*)(x + (size_t)grow * FIN + k0 + a_kkg * 4);
        }
#pragma unroll
        for (int i = 0; i < 8; i++) {
            int br = b_br + i * 4;
            bv[i] = *(const float4*)(W + (size_t)(k0 + br) * C1 + b_bc * 4);
        }
        __syncthreads();
#pragma unroll
        for (int i = 0; i < 2; i++) {
            int row = a_row + i * 32;
            As[(a_kkg * 4 + 0) * 68 + row] = av[i].x;
            As[(a_kkg * 4 + 1) * 68 + row] = av[i].y;
            As[(a_kkg * 4 + 2) * 68 + row] = av[i].z;
            As[(a_kkg * 4 + 3) * 68 + row] = av[i].w;
        }
#pragma unroll
        for (int i = 0; i < 8; i++) {
            int br = b_br + i * 4;
            *(float4*)&Bs[br * 256 + b_bc * 4] = bv[i];
        }
        __syncthreads();
#pragma unroll 8
        for (int kk = 0; kk < 32; kk++) {
            float4 b4 = *(const float4*)&Bs[kk * 256 + cg * 4];
            float4 a4[4];
#pragma unroll
            for (int j = 0; j < 4; j++)
                a4[j] = *(const float4*)&As[kk * 68 + rt * 16 + j * 4];
#pragma unroll
            for (int j = 0; j < 4; j++) {
                float ar4[4] = {a4[j].x, a4[j].y, a4[j].z, a4[j].w};
#pragma unroll
                for (int rr = 0; rr < 4; rr++) {
                    int r = j * 4 + rr;
                    acc[r][0] = fmaf(ar4[rr], b4.x, acc[r][0]);
                    acc[r][1] = fmaf(ar4[rr], b4.y, acc[r][1]);
                    acc[r][2] = fmaf(ar4[rr], b4.z, acc[r][2]);
                    acc[r][3] = fmaf(ar4[rr], b4.w, acc[r][3]);
                }
            }
        }
    }

    // epilogue: bf16 message store + head-dot reductions (head = 16-lane group)
    int head = cg >> 4;
    float4 wsv = *(const float4*)(aws + cg * 4);
    float4 wdv = *(const float4*)(awd + cg * 4);
#pragma unroll
    for (int r = 0; r < 16; r++) {
        int row = m0 + rt * 16 + r;
        bool ok = row < NN;
        float4 o = {acc[r][0], acc[r][1], acc[r][2], acc[r][3]};
        if (ok) {
            ushort4 hb;
            hb.x = f2bf(o.x); hb.y = f2bf(o.y); hb.z = f2bf(o.z); hb.w = f2bf(o.w);
            *(ushort4*)(h1b + (size_t)row * C1 + cg * 4) = hb;
        }
        float ps = o.x * wsv.x + o.y * wsv.y + o.z * wsv.z + o.w * wsv.w;
        float pd = o.x * wdv.x + o.y * wdv.y + o.z * wdv.z + o.w * wdv.w;
#pragma unroll
        for (int s = 1; s < 16; s <<= 1) {
            ps += __shfl_xor(ps, s);
            pd += __shfl_xor(pd, s);
        }
        if (ok && (cg & 15) == 0) {
            as1[row * 4 + head] = ps;
            ad1[row * 4 + head] = pd;
        }
    }
}

// ---------------- layer 1 aggregation -----------------------------------
// Wave per dst node. Weights precomputed (k_ew1). 2-stage ring: indices
// loaded 8 ahead, gathers issued 4 ahead using indices already resident —
// no index->gather waitcnt in the loop. Branchless compute (p=0 padding).
__global__ __launch_bounds__(256) void k_agg1(const unsigned short* __restrict__ h1b,
                                              const float* __restrict__ pw1,
                                              const int* __restrict__ offs,
                                              const int* __restrict__ ssrc,
                                              const float* __restrict__ b1,
                                              float* __restrict__ g1) {
    int lane = threadIdx.x & 63;
    int node = blockIdx.x * 4 + (threadIdx.x >> 6);
    int head = lane >> 4;
    int beg = offs[node];
    int end = (node + 1 < NN) ? offs[node + 1] : NE;
    float l = 0.f;
    float4 acc = {0.f, 0.f, 0.f, 0.f};
    const uint2* hv4 = (const uint2*)h1b;

    if (beg < end) {
        int e1 = end - 1;
        uint2 hb[4];
        float pv[4];
        int idxA[4];
#pragma unroll
        for (int i = 0; i < 4; i++) {
            int j0 = beg + i;
            int jc = j0 <= e1 ? j0 : e1;
            int s = ssrc[jc];
            hb[i] = hv4[(size_t)s * 64 + lane];
            float p = pw1[jc * 4 + head];
            pv[i] = (j0 <= e1) ? p : 0.f;
            int j1 = beg + 4 + i;
            idxA[i] = ssrc[j1 <= e1 ? j1 : e1];
        }
        for (int j = beg; j < end; j += 4) {
            int idxB[4];
            float pvN[4];
            uint2 hbN[4];
#pragma unroll
            for (int i = 0; i < 4; i++) {
                int jn = j + 8 + i;
                idxB[i] = ssrc[jn <= e1 ? jn : e1];
            }
#pragma unroll
            for (int i = 0; i < 4; i++) {
                int jp = j + 4 + i;
                float p = pw1[(jp <= e1 ? jp : e1) * 4 + head];
                pvN[i] = (jp <= e1) ? p : 0.f;
            }
#pragma unroll
            for (int i = 0; i < 4; i++)
                hbN[i] = hv4[(size_t)idxA[i] * 64 + lane];
#pragma unroll
            for (int i = 0; i < 4; i++) {
                float p = pv[i];
                uint2 hc = hb[i];
                l += p;
                acc.x = fmaf(p, bflo(hc.x), acc.x);
                acc.y = fmaf(p, bfhi(hc.x), acc.y);
                acc.z = fmaf(p, bflo(hc.y), acc.z);
                acc.w = fmaf(p, bfhi(hc.y), acc.w);
            }
#pragma unroll
            for (int i = 0; i < 4; i++) {
                hb[i] = hbN[i];
                pv[i] = pvN[i];
                idxA[i] = idxB[i];
            }
        }
    }
    float inv = 1.f / (l + EPSF);
    float4 b = ((const float4*)b1)[lane];
    float4 o;
    o.x = fmaxf(fmaf(acc.x, inv, b.x), 0.f);
    o.y = fmaxf(fmaf(acc.y, inv, b.y), 0.f);
    o.z = fmaxf(fmaf(acc.z, inv, b.z), 0.f);
    o.w = fmaxf(fmaf(acc.w, inv, b.w), 0.f);
    ((float4*)g1)[(size_t)node * 64 + lane] = o;
}

// ---------------- layer 2: register-tiled GEMM + fused alpha2 ------------
__global__ __launch_bounds__(256) void k_gemm2(const float* __restrict__ g1,
                                               const float* __restrict__ W2,
                                               const float* __restrict__ aws,
                                               const float* __restrict__ awd,
                                               unsigned short* __restrict__ h2b,
                                               float* __restrict__ as2,
                                               float* __restrict__ ad2) {
    __shared__ float Ws[256 * 48];   // zero-padded cols
    __shared__ float As[32 * 132];   // [kk][row<128], stride 132
    int t = threadIdx.x;
    int m0 = blockIdx.x * 128;
    int cg = t & 15;
    int rt = t >> 4;

#pragma unroll
    for (int i = 0; i < 12; i++) {
        int idx = i * 256 + t;          // f4 slot, 3072 total
        int kk = idx / 12;
        int c4 = idx % 12;
        float4 v = {0.f, 0.f, 0.f, 0.f};
        if (c4 < 10) v = *(const float4*)(W2 + kk * CLS + c4 * 4);
        *(float4*)&Ws[kk * 48 + c4 * 4] = v;
    }

    float acc[8][3];
#pragma unroll
    for (int r = 0; r < 8; r++)
#pragma unroll
        for (int i = 0; i < 3; i++) acc[r][i] = 0.f;

    int a_kkg = t & 7;
    int a_row = t >> 3;   // 0..31 ; +i*32

    for (int k0 = 0; k0 < C1; k0 += 32) {
        float4 av[4];
#pragma unroll
        for (int i = 0; i < 4; i++) {
            int row = a_row + i * 32;
            int grow = m0 + row;
            if (grow >= NN) grow = NN - 1;
            av[i] = *(const float4*)(g1 + (size_t)grow * C1 + k0 + a_kkg * 4);
        }
        __syncthreads();
#pragma unroll
        for (int i = 0; i < 4; i++) {
            int row = a_row + i * 32;
            As[(a_kkg * 4 + 0) * 132 + row] = av[i].x;
            As[(a_kkg * 4 + 1) * 132 + row] = av[i].y;
            As[(a_kkg * 4 + 2) * 132 + row] = av[i].z;
            As[(a_kkg * 4 + 3) * 132 + row] = av[i].w;
        }
        __syncthreads();
#pragma unroll 8
        for (int kk = 0; kk < 32; kk++) {
            float4 a0 = *(const float4*)&As[kk * 132 + rt * 8];
            float4 a1 = *(const float4*)&As[kk * 132 + rt * 8 + 4];
            float w0 = Ws[(k0 + kk) * 48 + cg * 3 + 0];
            float w1 = Ws[(k0 + kk) * 48 + cg * 3 + 1];
            float w2 = Ws[(k0 + kk) * 48 + cg * 3 + 2];
            float a8[8] = {a0.x, a0.y, a0.z, a0.w, a1.x, a1.y, a1.z, a1.w};
#pragma unroll
            for (int r = 0; r < 8; r++) {
                acc[r][0] = fmaf(a8[r], w0, acc[r][0]);
                acc[r][1] = fmaf(a8[r], w1, acc[r][1]);
                acc[r][2] = fmaf(a8[r], w2, acc[r][2]);
            }
        }
    }

    float wa[3], wd[3];
#pragma unroll
    for (int j = 0; j < 3; j++) {
        int col = cg * 3 + j;
        wa[j] = (col < CLS) ? aws[col] : 0.f;
        wd[j] = (col < CLS) ? awd[col] : 0.f;
    }
#pragma unroll
    for (int r = 0; r < 8; r++) {
        int row = m0 + rt * 8 + r;
        bool ok = row < NN;
        float ps = acc[r][0] * wa[0] + acc[r][1] * wa[1] + acc[r][2] * wa[2];
        float pd = acc[r][0] * wd[0] + acc[r][1] * wd[1] + acc[r][2] * wd[2];
#pragma unroll
        for (int s = 1; s < 16; s <<= 1) {
            ps += __shfl_xor(ps, s);
            pd += __shfl_xor(pd, s);
        }
        if (ok) {
#pragma unroll
            for (int j = 0; j < 3; j++) {
                int col = cg * 3 + j;
                if (col < CLS) h2b[(size_t)row * CLS + col] = f2bf(acc[r][j]);
            }
            if (cg == 0) {
                as2[row] = ps;
                ad2[row] = pd;
            }
        }
    }
}

// ---------------- layer 2 aggregation + fused log_softmax ----------------
// Same 2-stage ring structure; scalar payload (lane < 40 meaningful, lanes
// clamped for safe loads, masked at write).
__global__ __launch_bounds__(256) void k_agg2(const unsigned short* __restrict__ h2b,
                                              const float* __restrict__ pw2,
                                              const int* __restrict__ offs,
                                              const int* __restrict__ ssrc,
                                              const float* __restrict__ b2,
                                              float* __restrict__ out) {
    int lane = threadIdx.x & 63;
    int node = blockIdx.x * 4 + (threadIdx.x >> 6);
    int beg = offs[node];
    int end = (node + 1 < NN) ? offs[node + 1] : NE;
    bool act = lane < CLS;
    int cl = act ? lane : CLS - 1;
    float l = 0.f, acc = 0.f;

    if (beg < end) {
        int e1 = end - 1;
        unsigned int hb[4];
        float pv[4];
        int idxA[4];
#pragma unroll
        for (int i = 0; i < 4; i++) {
            int j0 = beg + i;
            int jc = j0 <= e1 ? j0 : e1;
            int s = ssrc[jc];
            hb[i] = (unsigned int)h2b[(size_t)s * CLS + cl];
            float p = pw2[jc];
            pv[i] = (j0 <= e1) ? p : 0.f;
            int j1 = beg + 4 + i;
            idxA[i] = ssrc[j1 <= e1 ? j1 : e1];
        }
        for (int j = beg; j < end; j += 4) {
            int idxB[4];
            float pvN[4];
            unsigned int hbN[4];
#pragma unroll
            for (int i = 0; i < 4; i++) {
                int jn = j + 8 + i;
                idxB[i] = ssrc[jn <= e1 ? jn : e1];
            }
#pragma unroll
            for (int i = 0; i < 4; i++) {
                int jp = j + 4 + i;
                float p = pw2[jp <= e1 ? jp : e1];
                pvN[i] = (jp <= e1) ? p : 0.f;
            }
#pragma unroll
            for (int i = 0; i < 4; i++)
                hbN[i] = (unsigned int)h2b[(size_t)idxA[i] * CLS + cl];
#pragma unroll
            for (int i = 0; i < 4; i++) {
                float p = pv[i];
                l += p;
                acc = fmaf(p, __uint_as_float(hb[i] << 16), acc);
            }
#pragma unroll
            for (int i = 0; i < 4; i++) {
                hb[i] = hbN[i];
                pv[i] = pvN[i];
                idxA[i] = idxB[i];
            }
        }
    }
    float v = act ? (acc / (l + EPSF) + b2[cl]) : -INFINITY;
    float mx = v;
#pragma unroll
    for (int s = 32; s >= 1; s >>= 1) mx = fmaxf(mx, __shfl_xor(mx, s));
    float ex = act ? __expf(v - mx) : 0.f;
    float sum = ex;
#pragma unroll
    for (int s = 32; s >= 1; s >>= 1) sum += __shfl_xor(sum, s);
    if (act) out[(size_t)node * CLS + lane] = v - mx - __logf(sum);
}

// ---------------- launch ----------------

extern "C" void kernel_launch(void* const* d_in, const int* in_sizes, int n_in,
                              void* d_out, int out_size, void* d_ws, size_t ws_size,
                              hipStream_t stream) {
    const float* x    = (const float*)d_in[0];
    const int*   ei   = (const int*)d_in[1];
    const float* W1   = (const float*)d_in[2];
    const float* as1w = (const float*)d_in[3];
    const float* ad1w = (const float*)d_in[4];
    const float* b1   = (const float*)d_in[5];
    const float* W2   = (const float*)d_in[6];
    const float* as2w = (const float*)d_in[7];
    const float* ad2w = (const float*)d_in[8];
    const float* b2   = (const float*)d_in[9];
    float* out = (float*)d_out;

    char* p = (char*)d_ws;
    auto alloc = [&](size_t bytes) {
        char* r = p;
        p += (bytes + 255) & ~(size_t)255;
        return r;
    };
    unsigned short* h1b = (unsigned short*)alloc((size_t)NN * C1 * 2);
    float* g1   = (float*)alloc((size_t)NN * C1 * 4);
    unsigned short* h2b = (unsigned short*)alloc((size_t)NN * CLS * 2);
    float* as1  = (float*)alloc((size_t)NN * 4 * 4);
    float* ad1  = (float*)alloc((size_t)NN * 4 * 4);
    float* as2  = (float*)alloc((size_t)NN * 4);
    float* ad2  = (float*)alloc((size_t)NN * 4);
    int* counts = (int*)alloc((size_t)NN * 4);
    int* offs   = (int*)alloc((size_t)NN * 4);
    int* cursor = (int*)alloc((size_t)NN * 4);
    int* parts  = (int*)alloc(64 * 4);
    int* ssrc   = (int*)alloc((size_t)NE * 4);
    int* sdst   = (int*)alloc((size_t)NE * 4);
    float4* pw1 = (float4*)alloc((size_t)NE * 16);
    float* pw2  = (float*)alloc((size_t)NE * 4);

    const int nb_scan = (NN + 1023) / 1024;  // 49
    const int nb_e = (NE + 255) / 256;

    k_zero<<<(NN + 255) / 256, 256, 0, stream>>>(counts, NN);
    k_hist<<<nb_e, 256, 0, stream>>>(ei, counts);
    k_scan1<<<nb_scan, 1024, 0, stream>>>(counts, offs, parts);
    k_scan2<<<1, 64, 0, stream>>>(parts, nb_scan);
    k_scan3<<<(NN + 255) / 256, 256, 0, stream>>>(offs, parts, cursor);
    k_scatter<<<nb_e, 256, 0, stream>>>(ei, cursor, ssrc, sdst);

    k_gemm1<<<(NN + 63) / 64, 256, 0, stream>>>(x, W1, as1w, ad1w, h1b, as1, ad1);
    k_ew1<<<nb_e, 256, 0, stream>>>(ssrc, sdst, as1, ad1, pw1);
    k_agg1<<<NN / 4, 256, 0, stream>>>(h1b, (const float*)pw1, offs, ssrc, b1, g1);

    k_gemm2<<<(NN + 127) / 128, 256, 0, stream>>>(g1, W2, as2w, ad2w, h2b, as2, ad2);
    k_ew2<<<nb_e, 256, 0, stream>>>(ssrc, sdst, as2, ad2, pw2);
    k_agg2<<<NN / 4, 256, 0, stream>>>(h2b, pw2, offs, ssrc, b2, out);
}

// Round 7
// 377.993 us; speedup vs baseline: 1.7233x; 1.0520x over previous
//
#include <hip/hip_runtime.h>
#include <math.h>

#define NN 50000
#define NE 800000
#define FIN 128
#define HID 64
#define HEADS 4
#define C1 256   // HEADS*HID
#define CLS 40
#define EPSF 1e-16f

__device__ __forceinline__ unsigned short f2bf(float f) {
    unsigned int u = __float_as_uint(f);
    unsigned int r = (u + 0x7fffu + ((u >> 16) & 1u)) >> 16;   // RNE
    return (unsigned short)r;
}
__device__ __forceinline__ float bflo(unsigned int u) { return __uint_as_float(u << 16); }
__device__ __forceinline__ float bfhi(unsigned int u) { return __uint_as_float(u & 0xffff0000u); }

// ---------------- counting sort of edges by dst ----------------

__global__ void k_zero(int* a, int n) {
    int i = blockIdx.x * 256 + threadIdx.x;
    if (i < n) a[i] = 0;
}

__global__ void k_hist(const int* __restrict__ ei, int* __restrict__ counts) {
    int i = blockIdx.x * 256 + threadIdx.x;
    if (i < NE) atomicAdd(&counts[ei[NE + i]], 1);
}

__global__ __launch_bounds__(1024) void k_scan1(const int* __restrict__ counts,
                                                int* __restrict__ offs,
                                                int* __restrict__ partials) {
    __shared__ int s[1024];
    int t = threadIdx.x;
    int g = blockIdx.x * 1024 + t;
    int v = (g < NN) ? counts[g] : 0;
    s[t] = v;
    __syncthreads();
    for (int d = 1; d < 1024; d <<= 1) {
        int x = (t >= d) ? s[t - d] : 0;
        __syncthreads();
        s[t] += x;
        __syncthreads();
    }
    if (g < NN) offs[g] = s[t] - v;             // block-local exclusive
    if (t == 1023) partials[blockIdx.x] = s[t]; // block total
}

__global__ void k_scan2(int* partials, int nb) {
    if (threadIdx.x == 0 && blockIdx.x == 0) {
        int run = 0;
        for (int b = 0; b < nb; b++) { int v = partials[b]; partials[b] = run; run += v; }
    }
}

__global__ void k_scan3(int* __restrict__ offs, const int* __restrict__ partials,
                        int* __restrict__ cursor) {
    int g = blockIdx.x * 256 + threadIdx.x;
    if (g < NN) {
        int o = offs[g] + partials[g >> 10];
        offs[g] = o;
        cursor[g] = o;
    }
}

__global__ void k_scatter(const int* __restrict__ ei, int* __restrict__ cursor,
                          int* __restrict__ ssrc, int* __restrict__ sdst) {
    int i = blockIdx.x * 256 + threadIdx.x;
    if (i < NE) {
        int s = ei[i];
        int d = ei[NE + i];
        int p = atomicAdd(&cursor[d], 1);
        ssrc[p] = s;
        sdst[p] = d;
    }
}

// ---------------- per-edge softmax weights (coalesced, massively parallel)

__global__ __launch_bounds__(256) void k_ew1(const int* __restrict__ ssrc,
                                             const int* __restrict__ sdst,
                                             const float* __restrict__ as1,
                                             const float* __restrict__ ad1,
                                             float4* __restrict__ pw1) {
    int j = blockIdx.x * 256 + threadIdx.x;
    if (j < NE) {
        int s = ssrc[j], d = sdst[j];
        float4 a = *(const float4*)(as1 + s * 4);
        float4 bb = *(const float4*)(ad1 + d * 4);
        float4 e = {a.x + bb.x, a.y + bb.y, a.z + bb.z, a.w + bb.w};
        e.x = e.x > 0.f ? e.x : 0.2f * e.x;
        e.y = e.y > 0.f ? e.y : 0.2f * e.y;
        e.z = e.z > 0.f ? e.z : 0.2f * e.z;
        e.w = e.w > 0.f ? e.w : 0.2f * e.w;
        float4 p = {__expf(e.x), __expf(e.y), __expf(e.z), __expf(e.w)};
        pw1[j] = p;
    }
}

__global__ __launch_bounds__(256) void k_ew2(const int* __restrict__ ssrc,
                                             const int* __restrict__ sdst,
                                             const float* __restrict__ as2,
                                             const float* __restrict__ ad2,
                                             float* __restrict__ pw2) {
    int j = blockIdx.x * 256 + threadIdx.x;
    if (j < NE) {
        float e = as2[ssrc[j]] + ad2[sdst[j]];
        e = e > 0.f ? e : 0.2f * e;
        pw2[j] = __expf(e);
    }
}

// ---------------- layer 1: barrier-free register-tiled GEMM --------------
// Block = 64 rows x 256 cols. Entire 64x128 A-tile staged ONCE in LDS
// (row-major, stride 132, float4 writes -> conflict-free; reads are
// wave-uniform b128 broadcasts). W1 streamed from global (L2-resident,
// coalesced 1KB/wave) with depth-1 register double-buffer. No barriers in
// the K loop. Epilogue: bf16 message store + fused head dots.
__global__ __launch_bounds__(256) void k_gemm1(const float* __restrict__ x,
                                               const float* __restrict__ W,
                                               const float* __restrict__ aws,
                                               const float* __restrict__ awd,
                                               unsigned short* __restrict__ h1b,
                                               float* __restrict__ as1,
                                               float* __restrict__ ad1) {
    __shared__ float As[64 * 132];
    int t = threadIdx.x;
    int m0 = blockIdx.x * 64;
    int cg = t & 63;
    int rt = t >> 6;

    // stage 64 rows x 128 k (2048 float4 slots, 8 per thread)
#pragma unroll
    for (int i = 0; i < 8; i++) {
        int idx = i * 256 + t;
        int row = idx >> 5;
        int c4 = idx & 31;
        int grow = m0 + row;
        if (grow >= NN) grow = NN - 1;
        float4 v = *(const float4*)(x + (size_t)grow * FIN + c4 * 4);
        *(float4*)&As[row * 132 + c4 * 4] = v;
    }
    __syncthreads();

    float acc[16][4];
#pragma unroll
    for (int r = 0; r < 16; r++)
#pragma unroll
        for (int i = 0; i < 4; i++) acc[r][i] = 0.f;

    const float* wp = W + cg * 4;
    float4 bcur[4], bnext[4];
#pragma unroll
    for (int u = 0; u < 4; u++) bcur[u] = *(const float4*)(wp + (size_t)u * C1);

    int arow0 = rt * 16;
    for (int kk0 = 0; kk0 < FIN; kk0 += 4) {
        int kp = kk0 + 4;
        if (kp >= FIN) kp = 0;   // harmless dummy prefetch on last step
#pragma unroll
        for (int u = 0; u < 4; u++) bnext[u] = *(const float4*)(wp + (size_t)(kp + u) * C1);
#pragma unroll
        for (int h = 0; h < 2; h++) {
            float4 a[8];
#pragma unroll
            for (int r = 0; r < 8; r++)
                a[r] = *(const float4*)&As[(arow0 + h * 8 + r) * 132 + kk0];
#pragma unroll
            for (int r = 0; r < 8; r++) {
                int rr = h * 8 + r;
                float av[4] = {a[r].x, a[r].y, a[r].z, a[r].w};
#pragma unroll
                for (int u = 0; u < 4; u++) {
                    acc[rr][0] = fmaf(av[u], bcur[u].x, acc[rr][0]);
                    acc[rr][1] = fmaf(av[u], bcur[u].y, acc[rr][1]);
                    acc[rr][2] = fmaf(av[u], bcur[u].z, acc[rr][2]);
                    acc[rr][3] = fmaf(av[u], bcur[u].w, acc[rr][3]);
                }
            }
        }
#pragma unroll
        for (int u = 0; u < 4; u++) bcur[u] = bnext[u];
    }

    // epilogue: bf16 message store + head-dot reductions (head = 16-lane group)
    int head = cg >> 4;
    float4 wsv = *(const float4*)(aws + cg * 4);
    float4 wdv = *(const float4*)(awd + cg * 4);
#pragma unroll
    for (int r = 0; r < 16; r++) {
        int row = m0 + rt * 16 + r;
        bool ok = row < NN;
        float4 o = {acc[r][0], acc[r][1], acc[r][2], acc[r][3]};
        if (ok) {
            ushort4 hb;
            hb.x = f2bf(o.x); hb.y = f2bf(o.y); hb.z = f2bf(o.z); hb.w = f2bf(o.w);
            *(ushort4*)(h1b + (size_t)row * C1 + cg * 4) = hb;
        }
        float ps = o.x * wsv.x + o.y * wsv.y + o.z * wsv.z + o.w * wsv.w;
        float pd = o.x * wdv.x + o.y * wdv.y + o.z * wdv.z + o.w * wdv.w;
#pragma unroll
        for (int s = 1; s < 16; s <<= 1) {
            ps += __shfl_xor(ps, s);
            pd += __shfl_xor(pd, s);
        }
        if (ok && (cg & 15) == 0) {
            as1[row * 4 + head] = ps;
            ad1[row * 4 + head] = pd;
        }
    }
}

// ---------------- layer 1 aggregation -----------------------------------
// Wave per dst node. Weights precomputed (k_ew1). 2-stage ring: indices
// loaded 8 ahead, gathers issued 4 ahead using indices already resident.
__global__ __launch_bounds__(256) void k_agg1(const unsigned short* __restrict__ h1b,
                                              const float* __restrict__ pw1,
                                              const int* __restrict__ offs,
                                              const int* __restrict__ ssrc,
                                              const float* __restrict__ b1,
                                              float* __restrict__ g1) {
    int lane = threadIdx.x & 63;
    int node = blockIdx.x * 4 + (threadIdx.x >> 6);
    int head = lane >> 4;
    int beg = offs[node];
    int end = (node + 1 < NN) ? offs[node + 1] : NE;
    float l = 0.f;
    float4 acc = {0.f, 0.f, 0.f, 0.f};
    const uint2* hv4 = (const uint2*)h1b;

    if (beg < end) {
        int e1 = end - 1;
        uint2 hb[4];
        float pv[4];
        int idxA[4];
#pragma unroll
        for (int i = 0; i < 4; i++) {
            int j0 = beg + i;
            int jc = j0 <= e1 ? j0 : e1;
            int s = ssrc[jc];
            hb[i] = hv4[(size_t)s * 64 + lane];
            float p = pw1[jc * 4 + head];
            pv[i] = (j0 <= e1) ? p : 0.f;
            int j1 = beg + 4 + i;
            idxA[i] = ssrc[j1 <= e1 ? j1 : e1];
        }
        for (int j = beg; j < end; j += 4) {
            int idxB[4];
            float pvN[4];
            uint2 hbN[4];
#pragma unroll
            for (int i = 0; i < 4; i++) {
                int jn = j + 8 + i;
                idxB[i] = ssrc[jn <= e1 ? jn : e1];
            }
#pragma unroll
            for (int i = 0; i < 4; i++) {
                int jp = j + 4 + i;
                float p = pw1[(jp <= e1 ? jp : e1) * 4 + head];
                pvN[i] = (jp <= e1) ? p : 0.f;
            }
#pragma unroll
            for (int i = 0; i < 4; i++)
                hbN[i] = hv4[(size_t)idxA[i] * 64 + lane];
#pragma unroll
            for (int i = 0; i < 4; i++) {
                float p = pv[i];
                uint2 hc = hb[i];
                l += p;
                acc.x = fmaf(p, bflo(hc.x), acc.x);
                acc.y = fmaf(p, bfhi(hc.x), acc.y);
                acc.z = fmaf(p, bflo(hc.y), acc.z);
                acc.w = fmaf(p, bfhi(hc.y), acc.w);
            }
#pragma unroll
            for (int i = 0; i < 4; i++) {
                hb[i] = hbN[i];
                pv[i] = pvN[i];
                idxA[i] = idxB[i];
            }
        }
    }
    float inv = 1.f / (l + EPSF);
    float4 b = ((const float4*)b1)[lane];
    float4 o;
    o.x = fmaxf(fmaf(acc.x, inv, b.x), 0.f);
    o.y = fmaxf(fmaf(acc.y, inv, b.y), 0.f);
    o.z = fmaxf(fmaf(acc.z, inv, b.z), 0.f);
    o.w = fmaxf(fmaf(acc.w, inv, b.w), 0.f);
    ((float4*)g1)[(size_t)node * 64 + lane] = o;
}

// ---------------- layer 2: register-tiled GEMM + fused alpha2 ------------
__global__ __launch_bounds__(256) void k_gemm2(const float* __restrict__ g1,
                                               const float* __restrict__ W2,
                                               const float* __restrict__ aws,
                                               const float* __restrict__ awd,
                                               unsigned short* __restrict__ h2b,
                                               float* __restrict__ as2,
                                               float* __restrict__ ad2) {
    __shared__ float Ws[256 * 48];   // zero-padded cols
    __shared__ float As[32 * 132];   // [kk][row<128], stride 132
    int t = threadIdx.x;
    int m0 = blockIdx.x * 128;
    int cg = t & 15;
    int rt = t >> 4;

#pragma unroll
    for (int i = 0; i < 12; i++) {
        int idx = i * 256 + t;          // f4 slot, 3072 total
        int kk = idx / 12;
        int c4 = idx % 12;
        float4 v = {0.f, 0.f, 0.f, 0.f};
        if (c4 < 10) v = *(const float4*)(W2 + kk * CLS + c4 * 4);
        *(float4*)&Ws[kk * 48 + c4 * 4] = v;
    }

    float acc[8][3];
#pragma unroll
    for (int r = 0; r < 8; r++)
#pragma unroll
        for (int i = 0; i < 3; i++) acc[r][i] = 0.f;

    int a_kkg = t & 7;
    int a_row = t >> 3;   // 0..31 ; +i*32

    for (int k0 = 0; k0 < C1; k0 += 32) {
        float4 av[4];
#pragma unroll
        for (int i = 0; i < 4; i++) {
            int row = a_row + i * 32;
            int grow = m0 + row;
            if (grow >= NN) grow = NN - 1;
            av[i] = *(const float4*)(g1 + (size_t)grow * C1 + k0 + a_kkg * 4);
        }
        __syncthreads();
#pragma unroll
        for (int i = 0; i < 4; i++) {
            int row = a_row + i * 32;
            As[(a_kkg * 4 + 0) * 132 + row] = av[i].x;
            As[(a_kkg * 4 + 1) * 132 + row] = av[i].y;
            As[(a_kkg * 4 + 2) * 132 + row] = av[i].z;
            As[(a_kkg * 4 + 3) * 132 + row] = av[i].w;
        }
        __syncthreads();
#pragma unroll 8
        for (int kk = 0; kk < 32; kk++) {
            float4 a0 = *(const float4*)&As[kk * 132 + rt * 8];
            float4 a1 = *(const float4*)&As[kk * 132 + rt * 8 + 4];
            float w0 = Ws[(k0 + kk) * 48 + cg * 3 + 0];
            float w1 = Ws[(k0 + kk) * 48 + cg * 3 + 1];
            float w2 = Ws[(k0 + kk) * 48 + cg * 3 + 2];
            float a8[8] = {a0.x, a0.y, a0.z, a0.w, a1.x, a1.y, a1.z, a1.w};
#pragma unroll
            for (int r = 0; r < 8; r++) {
                acc[r][0] = fmaf(a8[r], w0, acc[r][0]);
                acc[r][1] = fmaf(a8[r], w1, acc[r][1]);
                acc[r][2] = fmaf(a8[r], w2, acc[r][2]);
            }
        }
    }

    float wa[3], wd[3];
#pragma unroll
    for (int j = 0; j < 3; j++) {
        int col = cg * 3 + j;
        wa[j] = (col < CLS) ? aws[col] : 0.f;
        wd[j] = (col < CLS) ? awd[col] : 0.f;
    }
#pragma unroll
    for (int r = 0; r < 8; r++) {
        int row = m0 + rt * 8 + r;
        bool ok = row < NN;
        float ps = acc[r][0] * wa[0] + acc[r][1] * wa[1] + acc[r][2] * wa[2];
        float pd = acc[r][0] * wd[0] + acc[r][1] * wd[1] + acc[r][2] * wd[2];
#pragma unroll
        for (int s = 1; s < 16; s <<= 1) {
            ps += __shfl_xor(ps, s);
            pd += __shfl_xor(pd, s);
        }
        if (ok) {
#pragma unroll
            for (int j = 0; j < 3; j++) {
                int col = cg * 3 + j;
                if (col < CLS) h2b[(size_t)row * CLS + col] = f2bf(acc[r][j]);
            }
            if (cg == 0) {
                as2[row] = ps;
                ad2[row] = pd;
            }
        }
    }
}

// ---------------- layer 2 aggregation + fused log_softmax ----------------
__global__ __launch_bounds__(256) void k_agg2(const unsigned short* __restrict__ h2b,
                                              const float* __restrict__ pw2,
                                              const int* __restrict__ offs,
                                              const int* __restrict__ ssrc,
                                              const float* __restrict__ b2,
                                              float* __restrict__ out) {
    int lane = threadIdx.x & 63;
    int node = blockIdx.x * 4 + (threadIdx.x >> 6);
    int beg = offs[node];
    int end = (node + 1 < NN) ? offs[node + 1] : NE;
    bool act = lane < CLS;
    int cl = act ? lane : CLS - 1;
    float l = 0.f, acc = 0.f;

    if (beg < end) {
        int e1 = end - 1;
        unsigned int hb[4];
        float pv[4];
        int idxA[4];
#pragma unroll
        for (int i = 0; i < 4; i++) {
            int j0 = beg + i;
            int jc = j0 <= e1 ? j0 : e1;
            int s = ssrc[jc];
            hb[i] = (unsigned int)h2b[(size_t)s * CLS + cl];
            float p = pw2[jc];
            pv[i] = (j0 <= e1) ? p : 0.f;
            int j1 = beg + 4 + i;
            idxA[i] = ssrc[j1 <= e1 ? j1 : e1];
        }
        for (int j = beg; j < end; j += 4) {
            int idxB[4];
            float pvN[4];
            unsigned int hbN[4];
#pragma unroll
            for (int i = 0; i < 4; i++) {
                int jn = j + 8 + i;
                idxB[i] = ssrc[jn <= e1 ? jn : e1];
            }
#pragma unroll
            for (int i = 0; i < 4; i++) {
                int jp = j + 4 + i;
                float p = pw2[jp <= e1 ? jp : e1];
                pvN[i] = (jp <= e1) ? p : 0.f;
            }
#pragma unroll
            for (int i = 0; i < 4; i++)
                hbN[i] = (unsigned int)h2b[(size_t)idxA[i] * CLS + cl];
#pragma unroll
            for (int i = 0; i < 4; i++) {
                float p = pv[i];
                l += p;
                acc = fmaf(p, __uint_as_float(hb[i] << 16), acc);
            }
#pragma unroll
            for (int i = 0; i < 4; i++) {
                hb[i] = hbN[i];
                pv[i] = pvN[i];
                idxA[i] = idxB[i];
            }
        }
    }
    float v = act ? (acc / (l + EPSF) + b2[cl]) : -INFINITY;
    float mx = v;
#pragma unroll
    for (int s = 32; s >= 1; s >>= 1) mx = fmaxf(mx, __shfl_xor(mx, s));
    float ex = act ? __expf(v - mx) : 0.f;
    float sum = ex;
#pragma unroll
    for (int s = 32; s >= 1; s >>= 1) sum += __shfl_xor(sum, s);
    if (act) out[(size_t)node * CLS + lane] = v - mx - __logf(sum);
}

// ---------------- launch ----------------

extern "C" void kernel_launch(void* const* d_in, const int* in_sizes, int n_in,
                              void* d_out, int out_size, void* d_ws, size_t ws_size,
                              hipStream_t stream) {
    const float* x    = (const float*)d_in[0];
    const int*   ei   = (const int*)d_in[1];
    const float* W1   = (const float*)d_in[2];
    const float* as1w = (const float*)d_in[3];
    const float* ad1w = (const float*)d_in[4];
    const float* b1   = (const float*)d_in[5];
    const float* W2   = (const float*)d_in[6];
    const float* as2w = (const float*)d_in[7];
    const float* ad2w = (const float*)d_in[8];
    const float* b2   = (const float*)d_in[9];
    float* out = (float*)d_out;

    char* p = (char*)d_ws;
    auto alloc = [&](size_t bytes) {
        char* r = p;
        p += (bytes + 255) & ~(size_t)255;
        return r;
    };
    unsigned short* h1b = (unsigned short*)alloc((size_t)NN * C1 * 2);
    float* g1   = (float*)alloc((size_t)NN * C1 * 4);
    unsigned short* h2b = (unsigned short*)alloc((size_t)NN * CLS * 2);
    float* as1  = (float*)alloc((size_t)NN * 4 * 4);
    float* ad1  = (float*)alloc((size_t)NN * 4 * 4);
    float* as2  = (float*)alloc((size_t)NN * 4);
    float* ad2  = (float*)alloc((size_t)NN * 4);
    int* counts = (int*)alloc((size_t)NN * 4);
    int* offs   = (int*)alloc((size_t)NN * 4);
    int* cursor = (int*)alloc((size_t)NN * 4);
    int* parts  = (int*)alloc(64 * 4);
    int* ssrc   = (int*)alloc((size_t)NE * 4);
    int* sdst   = (int*)alloc((size_t)NE * 4);
    float4* pw1 = (float4*)alloc((size_t)NE * 16);
    float* pw2  = (float*)alloc((size_t)NE * 4);

    const int nb_scan = (NN + 1023) / 1024;  // 49
    const int nb_e = (NE + 255) / 256;

    k_zero<<<(NN + 255) / 256, 256, 0, stream>>>(counts, NN);
    k_hist<<<nb_e, 256, 0, stream>>>(ei, counts);
    k_scan1<<<nb_scan, 1024, 0, stream>>>(counts, offs, parts);
    k_scan2<<<1, 64, 0, stream>>>(parts, nb_scan);
    k_scan3<<<(NN + 255) / 256, 256, 0, stream>>>(offs, parts, cursor);
    k_scatter<<<nb_e, 256, 0, stream>>>(ei, cursor, ssrc, sdst);

    k_gemm1<<<(NN + 63) / 64, 256, 0, stream>>>(x, W1, as1w, ad1w, h1b, as1, ad1);
    k_ew1<<<nb_e, 256, 0, stream>>>(ssrc, sdst, as1, ad1, pw1);
    k_agg1<<<NN / 4, 256, 0, stream>>>(h1b, (const float*)pw1, offs, ssrc, b1, g1);

    k_gemm2<<<(NN + 127) / 128, 256, 0, stream>>>(g1, W2, as2w, ad2w, h2b, as2, ad2);
    k_ew2<<<nb_e, 256, 0, stream>>>(ssrc, sdst, as2, ad2, pw2);
    k_agg2<<<NN / 4, 256, 0, stream>>>(h2b, pw2, offs, ssrc, b2, out);
}

// Round 8
// 359.125 us; speedup vs baseline: 1.8138x; 1.0525x over previous
//
#include <hip/hip_runtime.h>
#include <math.h>

#define NN 50000
#define NE 800000
#define FIN 128
#define HID 64
#define HEADS 4
#define C1 256   // HEADS*HID
#define CLS 40
#define EPSF 1e-16f

typedef __attribute__((ext_vector_type(8))) short bf16x8;
typedef __attribute__((ext_vector_type(4))) float f32x4;

__device__ __forceinline__ unsigned short f2bf(float f) {
    unsigned int u = __float_as_uint(f);
    unsigned int r = (u + 0x7fffu + ((u >> 16) & 1u)) >> 16;   // RNE
    return (unsigned short)r;
}
__device__ __forceinline__ float bflo(unsigned int u) { return __uint_as_float(u << 16); }
__device__ __forceinline__ float bfhi(unsigned int u) { return __uint_as_float(u & 0xffff0000u); }

// ---------------- counting sort of edges by dst ----------------

__global__ void k_zero(int* a, int n) {
    int i = blockIdx.x * 256 + threadIdx.x;
    if (i < n) a[i] = 0;
}

__global__ void k_hist(const int* __restrict__ ei, int* __restrict__ counts) {
    int i = blockIdx.x * 256 + threadIdx.x;
    if (i < NE) atomicAdd(&counts[ei[NE + i]], 1);
}

__global__ __launch_bounds__(1024) void k_scan1(const int* __restrict__ counts,
                                                int* __restrict__ offs,
                                                int* __restrict__ partials) {
    __shared__ int s[1024];
    int t = threadIdx.x;
    int g = blockIdx.x * 1024 + t;
    int v = (g < NN) ? counts[g] : 0;
    s[t] = v;
    __syncthreads();
    for (int d = 1; d < 1024; d <<= 1) {
        int x = (t >= d) ? s[t - d] : 0;
        __syncthreads();
        s[t] += x;
        __syncthreads();
    }
    if (g < NN) offs[g] = s[t] - v;             // block-local exclusive
    if (t == 1023) partials[blockIdx.x] = s[t]; // block total
}

__global__ void k_scan2(int* partials, int nb) {
    if (threadIdx.x == 0 && blockIdx.x == 0) {
        int run = 0;
        for (int b = 0; b < nb; b++) { int v = partials[b]; partials[b] = run; run += v; }
    }
}

__global__ void k_scan3(int* __restrict__ offs, const int* __restrict__ partials,
                        int* __restrict__ cursor) {
    int g = blockIdx.x * 256 + threadIdx.x;
    if (g < NN) {
        int o = offs[g] + partials[g >> 10];
        offs[g] = o;
        cursor[g] = o;
    }
}

__global__ void k_scatter(const int* __restrict__ ei, int* __restrict__ cursor,
                          int* __restrict__ ssrc, int* __restrict__ sdst) {
    int i = blockIdx.x * 256 + threadIdx.x;
    if (i < NE) {
        int s = ei[i];
        int d = ei[NE + i];
        int p = atomicAdd(&cursor[d], 1);
        ssrc[p] = s;
        sdst[p] = d;
    }
}

// ---------------- per-edge softmax weights (coalesced, massively parallel)

__global__ __launch_bounds__(256) void k_ew1(const int* __restrict__ ssrc,
                                             const int* __restrict__ sdst,
                                             const float* __restrict__ as1,
                                             const float* __restrict__ ad1,
                                             float4* __restrict__ pw1) {
    int j = blockIdx.x * 256 + threadIdx.x;
    if (j < NE) {
        int s = ssrc[j], d = sdst[j];
        float4 a = *(const float4*)(as1 + s * 4);
        float4 bb = *(const float4*)(ad1 + d * 4);
        float4 e = {a.x + bb.x, a.y + bb.y, a.z + bb.z, a.w + bb.w};
        e.x = e.x > 0.f ? e.x : 0.2f * e.x;
        e.y = e.y > 0.f ? e.y : 0.2f * e.y;
        e.z = e.z > 0.f ? e.z : 0.2f * e.z;
        e.w = e.w > 0.f ? e.w : 0.2f * e.w;
        float4 p = {__expf(e.x), __expf(e.y), __expf(e.z), __expf(e.w)};
        pw1[j] = p;
    }
}

__global__ __launch_bounds__(256) void k_ew2(const int* __restrict__ ssrc,
                                             const int* __restrict__ sdst,
                                             const float* __restrict__ as2,
                                             const float* __restrict__ ad2,
                                             float* __restrict__ pw2) {
    int j = blockIdx.x * 256 + threadIdx.x;
    if (j < NE) {
        float e = as2[ssrc[j]] + ad2[sdst[j]];
        e = e > 0.f ? e : 0.2f * e;
        pw2[j] = __expf(e);
    }
}

// ---------------- W1 -> bf16 MFMA B-fragment buffer (one-time, tiny) -----
// wB[tn][kc][lane] = 8 bf16: B[k = kc*32 + (lane>>4)*8 + j][n = tn*16 + (lane&15)]
__global__ __launch_bounds__(256) void k_wconv(const float* __restrict__ W,
                                               unsigned short* __restrict__ wB) {
    int t = blockIdx.x * 256 + threadIdx.x;
    if (t < 4096) {
        int tn = t >> 8;
        int kc = (t >> 6) & 3;
        int l = t & 63;
        int n = tn * 16 + (l & 15);
        int k0 = kc * 32 + (l >> 4) * 8;
        unsigned short* o = wB + (size_t)t * 8;
#pragma unroll
        for (int j = 0; j < 8; j++) o[j] = f2bf(W[(size_t)(k0 + j) * C1 + n]);
    }
}

// ---------------- layer 1: bf16 MFMA GEMM + fused alpha dots -------------
// Block = 64 rows x 256 cols. A (x rows) converted fp32->bf16 during LDS
// staging, stored in FRAGMENT order [mt][kc][lane] so K-loop ds_reads are
// lane-contiguous b128 (conflict-free; only 4 per wave). B fragments
// streamed from the 64KB L2-resident wB buffer. No in-loop barriers.
// Wave wv handles rows wv*16..+15, all 256 cols: 16 tiles x 4 kc = 64 MFMA.
__global__ __launch_bounds__(256) void k_gemm1(const float* __restrict__ x,
                                               const unsigned short* __restrict__ wB,
                                               const float* __restrict__ aws,
                                               const float* __restrict__ awd,
                                               unsigned short* __restrict__ h1b,
                                               float* __restrict__ as1,
                                               float* __restrict__ ad1) {
    __shared__ uint4 Af[4][4][64];   // [mt][kc][lane], 16 KB
    int t = threadIdx.x;
    int m0 = blockIdx.x * 64;

    // stage: 2048 float4 of x (64 rows x 32 f4), coalesced reads
#pragma unroll
    for (int i = 0; i < 8; i++) {
        int g = i * 256 + t;
        int row = g >> 5;
        int c4 = g & 31;
        int grow = m0 + row;
        if (grow >= NN) grow = NN - 1;
        float4 v = *(const float4*)(x + (size_t)grow * FIN + c4 * 4);
        uint2 pk;
        pk.x = (unsigned int)f2bf(v.x) | ((unsigned int)f2bf(v.y) << 16);
        pk.y = (unsigned int)f2bf(v.z) | ((unsigned int)f2bf(v.w) << 16);
        int kc = c4 >> 3;
        int rem = (c4 & 7) * 4;       // k offset within 32-chunk
        int q = rem >> 3;             // quad
        int hh = (rem >> 2) & 1;      // half of the 8-elem fragment
        int l = q * 16 + (row & 15);
        int mt = row >> 4;
        ((uint2*)&Af[mt][kc][l])[hh] = pk;
    }
    __syncthreads();

    int l = t & 63;
    int wv = t >> 6;

    bf16x8 a[4];
#pragma unroll
    for (int kc = 0; kc < 4; kc++) a[kc] = *(const bf16x8*)&Af[wv][kc][l];

    f32x4 acc[16];
#pragma unroll
    for (int tn = 0; tn < 16; tn++) acc[tn] = (f32x4){0.f, 0.f, 0.f, 0.f};

    const bf16x8* wb = (const bf16x8*)wB + l;
#pragma unroll
    for (int tn = 0; tn < 16; tn++) {
        bf16x8 b0 = wb[(tn * 4 + 0) * 64];
        bf16x8 b1 = wb[(tn * 4 + 1) * 64];
        bf16x8 b2 = wb[(tn * 4 + 2) * 64];
        bf16x8 b3 = wb[(tn * 4 + 3) * 64];
        acc[tn] = __builtin_amdgcn_mfma_f32_16x16x32_bf16(a[0], b0, acc[tn], 0, 0, 0);
        acc[tn] = __builtin_amdgcn_mfma_f32_16x16x32_bf16(a[1], b1, acc[tn], 0, 0, 0);
        acc[tn] = __builtin_amdgcn_mfma_f32_16x16x32_bf16(a[2], b2, acc[tn], 0, 0, 0);
        acc[tn] = __builtin_amdgcn_mfma_f32_16x16x32_bf16(a[3], b3, acc[tn], 0, 0, 0);
    }

    // epilogue: C/D layout col=lane&15, row=(lane>>4)*4+reg  [m89-verified]
    int q = l >> 4;
    int c = l & 15;
    int row0 = m0 + wv * 16 + q * 4;
    float psum[4][4], pdsum[4][4];
#pragma unroll
    for (int h = 0; h < 4; h++)
#pragma unroll
        for (int r = 0; r < 4; r++) { psum[h][r] = 0.f; pdsum[h][r] = 0.f; }

#pragma unroll
    for (int tn = 0; tn < 16; tn++) {
        int col = tn * 16 + c;
        int h = tn >> 2;
        float wsv = aws[col];
        float wdv = awd[col];
#pragma unroll
        for (int r = 0; r < 4; r++) {
            float v = acc[tn][r];
            int row = row0 + r;
            if (row < NN) h1b[(size_t)row * C1 + col] = f2bf(v);
            psum[h][r] = fmaf(v, wsv, psum[h][r]);
            pdsum[h][r] = fmaf(v, wdv, pdsum[h][r]);
        }
    }
#pragma unroll
    for (int h = 0; h < 4; h++)
#pragma unroll
        for (int r = 0; r < 4; r++) {
            float ps = psum[h][r], pd = pdsum[h][r];
#pragma unroll
            for (int s = 1; s < 16; s <<= 1) {
                ps += __shfl_xor(ps, s);
                pd += __shfl_xor(pd, s);
            }
            int row = row0 + r;
            if (c == 0 && row < NN) {
                as1[row * 4 + h] = ps;
                ad1[row * 4 + h] = pd;
            }
        }
}

// ---------------- layer 1 aggregation -----------------------------------
// Wave per dst node. Weights precomputed (k_ew1). 2-stage ring: indices
// loaded 8 ahead, gathers issued 4 ahead using indices already resident.
__global__ __launch_bounds__(256) void k_agg1(const unsigned short* __restrict__ h1b,
                                              const float* __restrict__ pw1,
                                              const int* __restrict__ offs,
                                              const int* __restrict__ ssrc,
                                              const float* __restrict__ b1,
                                              float* __restrict__ g1) {
    int lane = threadIdx.x & 63;
    int node = blockIdx.x * 4 + (threadIdx.x >> 6);
    int head = lane >> 4;
    int beg = offs[node];
    int end = (node + 1 < NN) ? offs[node + 1] : NE;
    float l = 0.f;
    float4 acc = {0.f, 0.f, 0.f, 0.f};
    const uint2* hv4 = (const uint2*)h1b;

    if (beg < end) {
        int e1 = end - 1;
        uint2 hb[4];
        float pv[4];
        int idxA[4];
#pragma unroll
        for (int i = 0; i < 4; i++) {
            int j0 = beg + i;
            int jc = j0 <= e1 ? j0 : e1;
            int s = ssrc[jc];
            hb[i] = hv4[(size_t)s * 64 + lane];
            float p = pw1[jc * 4 + head];
            pv[i] = (j0 <= e1) ? p : 0.f;
            int j1 = beg + 4 + i;
            idxA[i] = ssrc[j1 <= e1 ? j1 : e1];
        }
        for (int j = beg; j < end; j += 4) {
            int idxB[4];
            float pvN[4];
            uint2 hbN[4];
#pragma unroll
            for (int i = 0; i < 4; i++) {
                int jn = j + 8 + i;
                idxB[i] = ssrc[jn <= e1 ? jn : e1];
            }
#pragma unroll
            for (int i = 0; i < 4; i++) {
                int jp = j + 4 + i;
                float p = pw1[(jp <= e1 ? jp : e1) * 4 + head];
                pvN[i] = (jp <= e1) ? p : 0.f;
            }
#pragma unroll
            for (int i = 0; i < 4; i++)
                hbN[i] = hv4[(size_t)idxA[i] * 64 + lane];
#pragma unroll
            for (int i = 0; i < 4; i++) {
                float p = pv[i];
                uint2 hc = hb[i];
                l += p;
                acc.x = fmaf(p, bflo(hc.x), acc.x);
                acc.y = fmaf(p, bfhi(hc.x), acc.y);
                acc.z = fmaf(p, bflo(hc.y), acc.z);
                acc.w = fmaf(p, bfhi(hc.y), acc.w);
            }
#pragma unroll
            for (int i = 0; i < 4; i++) {
                hb[i] = hbN[i];
                pv[i] = pvN[i];
                idxA[i] = idxB[i];
            }
        }
    }
    float inv = 1.f / (l + EPSF);
    float4 b = ((const float4*)b1)[lane];
    float4 o;
    o.x = fmaxf(fmaf(acc.x, inv, b.x), 0.f);
    o.y = fmaxf(fmaf(acc.y, inv, b.y), 0.f);
    o.z = fmaxf(fmaf(acc.z, inv, b.z), 0.f);
    o.w = fmaxf(fmaf(acc.w, inv, b.w), 0.f);
    ((float4*)g1)[(size_t)node * 64 + lane] = o;
}

// ---------------- layer 2: register-tiled GEMM + fused alpha2 ------------
__global__ __launch_bounds__(256) void k_gemm2(const float* __restrict__ g1,
                                               const float* __restrict__ W2,
                                               const float* __restrict__ aws,
                                               const float* __restrict__ awd,
                                               unsigned short* __restrict__ h2b,
                                               float* __restrict__ as2,
                                               float* __restrict__ ad2) {
    __shared__ float Ws[256 * 48];   // zero-padded cols
    __shared__ float As[32 * 132];   // [kk][row<128], stride 132
    int t = threadIdx.x;
    int m0 = blockIdx.x * 128;
    int cg = t & 15;
    int rt = t >> 4;

#pragma unroll
    for (int i = 0; i < 12; i++) {
        int idx = i * 256 + t;          // f4 slot, 3072 total
        int kk = idx / 12;
        int c4 = idx % 12;
        float4 v = {0.f, 0.f, 0.f, 0.f};
        if (c4 < 10) v = *(const float4*)(W2 + kk * CLS + c4 * 4);
        *(float4*)&Ws[kk * 48 + c4 * 4] = v;
    }

    float acc[8][3];
#pragma unroll
    for (int r = 0; r < 8; r++)
#pragma unroll
        for (int i = 0; i < 3; i++) acc[r][i] = 0.f;

    int a_kkg = t & 7;
    int a_row = t >> 3;   // 0..31 ; +i*32

    for (int k0 = 0; k0 < C1; k0 += 32) {
        float4 av[4];
#pragma unroll
        for (int i = 0; i < 4; i++) {
            int row = a_row + i * 32;
            int grow = m0 + row;
            if (grow >= NN) grow = NN - 1;
            av[i] = *(const float4*)(g1 + (size_t)grow * C1 + k0 + a_kkg * 4);
        }
        __syncthreads();
#pragma unroll
        for (int i = 0; i < 4; i++) {
            int row = a_row + i * 32;
            As[(a_kkg * 4 + 0) * 132 + row] = av[i].x;
            As[(a_kkg * 4 + 1) * 132 + row] = av[i].y;
            As[(a_kkg * 4 + 2) * 132 + row] = av[i].z;
            As[(a_kkg * 4 + 3) * 132 + row] = av[i].w;
        }
        __syncthreads();
#pragma unroll 8
        for (int kk = 0; kk < 32; kk++) {
            float4 a0 = *(const float4*)&As[kk * 132 + rt * 8];
            float4 a1 = *(const float4*)&As[kk * 132 + rt * 8 + 4];
            float w0 = Ws[(k0 + kk) * 48 + cg * 3 + 0];
            float w1 = Ws[(k0 + kk) * 48 + cg * 3 + 1];
            float w2 = Ws[(k0 + kk) * 48 + cg * 3 + 2];
            float a8[8] = {a0.x, a0.y, a0.z, a0.w, a1.x, a1.y, a1.z, a1.w};
#pragma unroll
            for (int r = 0; r < 8; r++) {
                acc[r][0] = fmaf(a8[r], w0, acc[r][0]);
                acc[r][1] = fmaf(a8[r], w1, acc[r][1]);
                acc[r][2] = fmaf(a8[r], w2, acc[r][2]);
            }
        }
    }

    float wa[3], wd[3];
#pragma unroll
    for (int j = 0; j < 3; j++) {
        int col = cg * 3 + j;
        wa[j] = (col < CLS) ? aws[col] : 0.f;
        wd[j] = (col < CLS) ? awd[col] : 0.f;
    }
#pragma unroll
    for (int r = 0; r < 8; r++) {
        int row = m0 + rt * 8 + r;
        bool ok = row < NN;
        float ps = acc[r][0] * wa[0] + acc[r][1] * wa[1] + acc[r][2] * wa[2];
        float pd = acc[r][0] * wd[0] + acc[r][1] * wd[1] + acc[r][2] * wd[2];
#pragma unroll
        for (int s = 1; s < 16; s <<= 1) {
            ps += __shfl_xor(ps, s);
            pd += __shfl_xor(pd, s);
        }
        if (ok) {
#pragma unroll
            for (int j = 0; j < 3; j++) {
                int col = cg * 3 + j;
                if (col < CLS) h2b[(size_t)row * CLS + col] = f2bf(acc[r][j]);
            }
            if (cg == 0) {
                as2[row] = ps;
                ad2[row] = pd;
            }
        }
    }
}

// ---------------- layer 2 aggregation + fused log_softmax ----------------
__global__ __launch_bounds__(256) void k_agg2(const unsigned short* __restrict__ h2b,
                                              const float* __restrict__ pw2,
                                              const int* __restrict__ offs,
                                              const int* __restrict__ ssrc,
                                              const float* __restrict__ b2,
                                              float* __restrict__ out) {
    int lane = threadIdx.x & 63;
    int node = blockIdx.x * 4 + (threadIdx.x >> 6);
    int beg = offs[node];
    int end = (node + 1 < NN) ? offs[node + 1] : NE;
    bool act = lane < CLS;
    int cl = act ? lane : CLS - 1;
    float l = 0.f, acc = 0.f;

    if (beg < end) {
        int e1 = end - 1;
        unsigned int hb[4];
        float pv[4];
        int idxA[4];
#pragma unroll
        for (int i = 0; i < 4; i++) {
            int j0 = beg + i;
            int jc = j0 <= e1 ? j0 : e1;
            int s = ssrc[jc];
            hb[i] = (unsigned int)h2b[(size_t)s * CLS + cl];
            float p = pw2[jc];
            pv[i] = (j0 <= e1) ? p : 0.f;
            int j1 = beg + 4 + i;
            idxA[i] = ssrc[j1 <= e1 ? j1 : e1];
        }
        for (int j = beg; j < end; j += 4) {
            int idxB[4];
            float pvN[4];
            unsigned int hbN[4];
#pragma unroll
            for (int i = 0; i < 4; i++) {
                int jn = j + 8 + i;
                idxB[i] = ssrc[jn <= e1 ? jn : e1];
            }
#pragma unroll
            for (int i = 0; i < 4; i++) {
                int jp = j + 4 + i;
                float p = pw2[jp <= e1 ? jp : e1];
                pvN[i] = (jp <= e1) ? p : 0.f;
            }
#pragma unroll
            for (int i = 0; i < 4; i++)
                hbN[i] = (unsigned int)h2b[(size_t)idxA[i] * CLS + cl];
#pragma unroll
            for (int i = 0; i < 4; i++) {
                float p = pv[i];
                l += p;
                acc = fmaf(p, __uint_as_float(hb[i] << 16), acc);
            }
#pragma unroll
            for (int i = 0; i < 4; i++) {
                hb[i] = hbN[i];
                pv[i] = pvN[i];
                idxA[i] = idxB[i];
            }
        }
    }
    float v = act ? (acc / (l + EPSF) + b2[cl]) : -INFINITY;
    float mx = v;
#pragma unroll
    for (int s = 32; s >= 1; s >>= 1) mx = fmaxf(mx, __shfl_xor(mx, s));
    float ex = act ? __expf(v - mx) : 0.f;
    float sum = ex;
#pragma unroll
    for (int s = 32; s >= 1; s >>= 1) sum += __shfl_xor(sum, s);
    if (act) out[(size_t)node * CLS + lane] = v - mx - __logf(sum);
}

// ---------------- launch ----------------

extern "C" void kernel_launch(void* const* d_in, const int* in_sizes, int n_in,
                              void* d_out, int out_size, void* d_ws, size_t ws_size,
                              hipStream_t stream) {
    const float* x    = (const float*)d_in[0];
    const int*   ei   = (const int*)d_in[1];
    const float* W1   = (const float*)d_in[2];
    const float* as1w = (const float*)d_in[3];
    const float* ad1w = (const float*)d_in[4];
    const float* b1   = (const float*)d_in[5];
    const float* W2   = (const float*)d_in[6];
    const float* as2w = (const float*)d_in[7];
    const float* ad2w = (const float*)d_in[8];
    const float* b2   = (const float*)d_in[9];
    float* out = (float*)d_out;

    char* p = (char*)d_ws;
    auto alloc = [&](size_t bytes) {
        char* r = p;
        p += (bytes + 255) & ~(size_t)255;
        return r;
    };
    unsigned short* h1b = (unsigned short*)alloc((size_t)NN * C1 * 2);
    float* g1   = (float*)alloc((size_t)NN * C1 * 4);
    unsigned short* h2b = (unsigned short*)alloc((size_t)NN * CLS * 2);
    float* as1  = (float*)alloc((size_t)NN * 4 * 4);
    float* ad1  = (float*)alloc((size_t)NN * 4 * 4);
    float* as2  = (float*)alloc((size_t)NN * 4);
    float* ad2  = (float*)alloc((size_t)NN * 4);
    int* counts = (int*)alloc((size_t)NN * 4);
    int* offs   = (int*)alloc((size_t)NN * 4);
    int* cursor = (int*)alloc((size_t)NN * 4);
    int* parts  = (int*)alloc(64 * 4);
    int* ssrc   = (int*)alloc((size_t)NE * 4);
    int* sdst   = (int*)alloc((size_t)NE * 4);
    float4* pw1 = (float4*)alloc((size_t)NE * 16);
    float* pw2  = (float*)alloc((size_t)NE * 4);
    unsigned short* wB = (unsigned short*)alloc((size_t)4096 * 8 * 2);

    const int nb_scan = (NN + 1023) / 1024;  // 49
    const int nb_e = (NE + 255) / 256;

    k_zero<<<(NN + 255) / 256, 256, 0, stream>>>(counts, NN);
    k_hist<<<nb_e, 256, 0, stream>>>(ei, counts);
    k_scan1<<<nb_scan, 1024, 0, stream>>>(counts, offs, parts);
    k_scan2<<<1, 64, 0, stream>>>(parts, nb_scan);
    k_scan3<<<(NN + 255) / 256, 256, 0, stream>>>(offs, parts, cursor);
    k_scatter<<<nb_e, 256, 0, stream>>>(ei, cursor, ssrc, sdst);

    k_wconv<<<16, 256, 0, stream>>>(W1, wB);
    k_gemm1<<<(NN + 63) / 64, 256, 0, stream>>>(x, wB, as1w, ad1w, h1b, as1, ad1);
    k_ew1<<<nb_e, 256, 0, stream>>>(ssrc, sdst, as1, ad1, pw1);
    k_agg1<<<NN / 4, 256, 0, stream>>>(h1b, (const float*)pw1, offs, ssrc, b1, g1);

    k_gemm2<<<(NN + 127) / 128, 256, 0, stream>>>(g1, W2, as2w, ad2w, h2b, as2, ad2);
    k_ew2<<<nb_e, 256, 0, stream>>>(ssrc, sdst, as2, ad2, pw2);
    k_agg2<<<NN / 4, 256, 0, stream>>>(h2b, pw2, offs, ssrc, b2, out);
}

// Round 9
// 329.255 us; speedup vs baseline: 1.9783x; 1.0907x over previous
//
#include <hip/hip_runtime.h>
#include <math.h>

#define NN 50000
#define NE 800000
#define FIN 128
#define HID 64
#define HEADS 4
#define C1 256   // HEADS*HID
#define CLS 40
#define EPSF 1e-16f

typedef __attribute__((ext_vector_type(8))) short bf16x8;
typedef __attribute__((ext_vector_type(4))) float f32x4;

__device__ __forceinline__ unsigned short f2bf(float f) {
    unsigned int u = __float_as_uint(f);
    unsigned int r = (u + 0x7fffu + ((u >> 16) & 1u)) >> 16;   // RNE
    return (unsigned short)r;
}
__device__ __forceinline__ float bflo(unsigned int u) { return __uint_as_float(u << 16); }
__device__ __forceinline__ float bfhi(unsigned int u) { return __uint_as_float(u & 0xffff0000u); }

// ---------------- counting sort of edges by dst ----------------

__global__ void k_zero(int* a, int n) {
    int i = blockIdx.x * 256 + threadIdx.x;
    if (i < n) a[i] = 0;
}

__global__ void k_hist(const int* __restrict__ ei, int* __restrict__ counts) {
    int i = blockIdx.x * 256 + threadIdx.x;
    if (i < NE) atomicAdd(&counts[ei[NE + i]], 1);
}

__global__ __launch_bounds__(1024) void k_scan1(const int* __restrict__ counts,
                                                int* __restrict__ offs,
                                                int* __restrict__ partials) {
    __shared__ int s[1024];
    int t = threadIdx.x;
    int g = blockIdx.x * 1024 + t;
    int v = (g < NN) ? counts[g] : 0;
    s[t] = v;
    __syncthreads();
    for (int d = 1; d < 1024; d <<= 1) {
        int x = (t >= d) ? s[t - d] : 0;
        __syncthreads();
        s[t] += x;
        __syncthreads();
    }
    if (g < NN) offs[g] = s[t] - v;             // block-local exclusive
    if (t == 1023) partials[blockIdx.x] = s[t]; // block total
}

__global__ void k_scan2(int* partials, int nb) {
    if (threadIdx.x == 0 && blockIdx.x == 0) {
        int run = 0;
        for (int b = 0; b < nb; b++) { int v = partials[b]; partials[b] = run; run += v; }
    }
}

__global__ void k_scan3(int* __restrict__ offs, const int* __restrict__ partials,
                        int* __restrict__ cursor) {
    int g = blockIdx.x * 256 + threadIdx.x;
    if (g < NN) {
        int o = offs[g] + partials[g >> 10];
        offs[g] = o;
        cursor[g] = o;
    }
}

__global__ void k_scatter(const int* __restrict__ ei, int* __restrict__ cursor,
                          int* __restrict__ ssrc, int* __restrict__ sdst) {
    int i = blockIdx.x * 256 + threadIdx.x;
    if (i < NE) {
        int s = ei[i];
        int d = ei[NE + i];
        int p = atomicAdd(&cursor[d], 1);
        ssrc[p] = s;
        sdst[p] = d;
    }
}

// ---------------- per-edge softmax weights + tail padding ----------------

__global__ __launch_bounds__(256) void k_ew1(const int* __restrict__ ssrc,
                                             const int* __restrict__ sdst,
                                             const float* __restrict__ as1,
                                             const float* __restrict__ ad1,
                                             float4* __restrict__ pw1,
                                             int* __restrict__ ssrc_pad) {
    int j = blockIdx.x * 256 + threadIdx.x;
    if (j < NE) {
        int s = ssrc[j], d = sdst[j];
        float4 a = *(const float4*)(as1 + s * 4);
        float4 bb = *(const float4*)(ad1 + d * 4);
        float4 e = {a.x + bb.x, a.y + bb.y, a.z + bb.z, a.w + bb.w};
        e.x = e.x > 0.f ? e.x : 0.2f * e.x;
        e.y = e.y > 0.f ? e.y : 0.2f * e.y;
        e.z = e.z > 0.f ? e.z : 0.2f * e.z;
        e.w = e.w > 0.f ? e.w : 0.2f * e.w;
        float4 p = {__expf(e.x), __expf(e.y), __expf(e.z), __expf(e.w)};
        pw1[j] = p;
    } else {
        if (j < NE + 16) pw1[j] = (float4){0.f, 0.f, 0.f, 0.f};
        if (j < NE + 32) ssrc_pad[j] = 0;
    }
}

__global__ __launch_bounds__(256) void k_ew2(const int* __restrict__ ssrc,
                                             const int* __restrict__ sdst,
                                             const float* __restrict__ as2,
                                             const float* __restrict__ ad2,
                                             float* __restrict__ pw2) {
    int j = blockIdx.x * 256 + threadIdx.x;
    if (j < NE) {
        float e = as2[ssrc[j]] + ad2[sdst[j]];
        e = e > 0.f ? e : 0.2f * e;
        pw2[j] = __expf(e);
    } else if (j < NE + 16) {
        pw2[j] = 0.f;
    }
}

// ---------------- W1/W2 -> bf16 MFMA B-fragment buffers (one-time) -------
// wB1[tn*4+kc][lane]: B[k=kc*32+(lane>>4)*8+j][n=tn*16+(lane&15)], tn<16,kc<4
// wB2[tn*8+kc][lane]: same from W2 (zero-padded cols >=40), tn<3, kc<8
__global__ __launch_bounds__(256) void k_wconv(const float* __restrict__ W1,
                                               const float* __restrict__ W2,
                                               unsigned short* __restrict__ wB1,
                                               unsigned short* __restrict__ wB2) {
    int t = blockIdx.x * 256 + threadIdx.x;
    if (t < 4096) {
        int tn = t >> 8;
        int kc = (t >> 6) & 3;
        int l = t & 63;
        int n = tn * 16 + (l & 15);
        int k0 = kc * 32 + (l >> 4) * 8;
        unsigned short* o = wB1 + (size_t)t * 8;
#pragma unroll
        for (int j = 0; j < 8; j++) o[j] = f2bf(W1[(size_t)(k0 + j) * C1 + n]);
    } else if (t < 4096 + 1536) {
        int u = t - 4096;
        int tn = u >> 9;
        int kc = (u >> 6) & 7;
        int l = u & 63;
        int n = tn * 16 + (l & 15);
        int k0 = kc * 32 + (l >> 4) * 8;
        unsigned short* o = wB2 + (size_t)u * 8;
#pragma unroll
        for (int j = 0; j < 8; j++)
            o[j] = (n < CLS) ? f2bf(W2[(size_t)(k0 + j) * CLS + n]) : (unsigned short)0;
    }
}

// ---------------- layer 1: bf16 MFMA GEMM + fused alpha dots -------------
__global__ __launch_bounds__(256) void k_gemm1(const float* __restrict__ x,
                                               const unsigned short* __restrict__ wB,
                                               const float* __restrict__ aws,
                                               const float* __restrict__ awd,
                                               unsigned short* __restrict__ h1b,
                                               float* __restrict__ as1,
                                               float* __restrict__ ad1) {
    __shared__ uint4 Af[4][4][64];   // [mt][kc][lane], 16 KB
    int t = threadIdx.x;
    int m0 = blockIdx.x * 64;

#pragma unroll
    for (int i = 0; i < 8; i++) {
        int g = i * 256 + t;
        int row = g >> 5;
        int c4 = g & 31;
        int grow = m0 + row;
        if (grow >= NN) grow = NN - 1;
        float4 v = *(const float4*)(x + (size_t)grow * FIN + c4 * 4);
        uint2 pk;
        pk.x = (unsigned int)f2bf(v.x) | ((unsigned int)f2bf(v.y) << 16);
        pk.y = (unsigned int)f2bf(v.z) | ((unsigned int)f2bf(v.w) << 16);
        int kc = c4 >> 3;
        int rem = (c4 & 7) * 4;
        int q = rem >> 3;
        int hh = (rem >> 2) & 1;
        int l = q * 16 + (row & 15);
        int mt = row >> 4;
        ((uint2*)&Af[mt][kc][l])[hh] = pk;
    }
    __syncthreads();

    int l = t & 63;
    int wv = t >> 6;

    bf16x8 a[4];
#pragma unroll
    for (int kc = 0; kc < 4; kc++) a[kc] = *(const bf16x8*)&Af[wv][kc][l];

    f32x4 acc[16];
#pragma unroll
    for (int tn = 0; tn < 16; tn++) acc[tn] = (f32x4){0.f, 0.f, 0.f, 0.f};

    const bf16x8* wb = (const bf16x8*)wB + l;
#pragma unroll
    for (int tn = 0; tn < 16; tn++) {
        bf16x8 b0 = wb[(tn * 4 + 0) * 64];
        bf16x8 b1 = wb[(tn * 4 + 1) * 64];
        bf16x8 b2 = wb[(tn * 4 + 2) * 64];
        bf16x8 b3 = wb[(tn * 4 + 3) * 64];
        acc[tn] = __builtin_amdgcn_mfma_f32_16x16x32_bf16(a[0], b0, acc[tn], 0, 0, 0);
        acc[tn] = __builtin_amdgcn_mfma_f32_16x16x32_bf16(a[1], b1, acc[tn], 0, 0, 0);
        acc[tn] = __builtin_amdgcn_mfma_f32_16x16x32_bf16(a[2], b2, acc[tn], 0, 0, 0);
        acc[tn] = __builtin_amdgcn_mfma_f32_16x16x32_bf16(a[3], b3, acc[tn], 0, 0, 0);
    }

    int q = l >> 4;
    int c = l & 15;
    int row0 = m0 + wv * 16 + q * 4;
    float psum[4][4], pdsum[4][4];
#pragma unroll
    for (int h = 0; h < 4; h++)
#pragma unroll
        for (int r = 0; r < 4; r++) { psum[h][r] = 0.f; pdsum[h][r] = 0.f; }

#pragma unroll
    for (int tn = 0; tn < 16; tn++) {
        int col = tn * 16 + c;
        int h = tn >> 2;
        float wsv = aws[col];
        float wdv = awd[col];
#pragma unroll
        for (int r = 0; r < 4; r++) {
            float v = acc[tn][r];
            int row = row0 + r;
            if (row < NN) h1b[(size_t)row * C1 + col] = f2bf(v);
            psum[h][r] = fmaf(v, wsv, psum[h][r]);
            pdsum[h][r] = fmaf(v, wdv, pdsum[h][r]);
        }
    }
#pragma unroll
    for (int h = 0; h < 4; h++)
#pragma unroll
        for (int r = 0; r < 4; r++) {
            float ps = psum[h][r], pd = pdsum[h][r];
#pragma unroll
            for (int s = 1; s < 16; s <<= 1) {
                ps += __shfl_xor(ps, s);
                pd += __shfl_xor(pd, s);
            }
            int row = row0 + r;
            if (c == 0 && row < NN) {
                as1[row * 4 + h] = ps;
                ad1[row * 4 + h] = pd;
            }
        }
}

// ---------------- layer 1 aggregation -----------------------------------
// Wave per dst node. Copy-free A/B double-buffered ring over 8-edge strides.
// All loads unconditional (arrays globally padded); per-slot validity is one
// wave-uniform compare masking p to 0.
__global__ __launch_bounds__(256) void k_agg1(const unsigned short* __restrict__ h1b,
                                              const float* __restrict__ pw1,
                                              const int* __restrict__ offs,
                                              const int* __restrict__ ssrc,
                                              const float* __restrict__ b1,
                                              unsigned short* __restrict__ g1b) {
    int lane = threadIdx.x & 63;
    int node = blockIdx.x * 4 + (threadIdx.x >> 6);
    int head = lane >> 4;
    int beg = offs[node];
    int end = (node + 1 < NN) ? offs[node + 1] : NE;
    float l = 0.f;
    float4 acc = {0.f, 0.f, 0.f, 0.f};
    const uint2* hv4 = (const uint2*)h1b;

    if (beg < end) {
        int idx[8];
#pragma unroll
        for (int i = 0; i < 8; i++) idx[i] = ssrc[beg + i];
        uint2 hbA[4];
        float pA[4];
#pragma unroll
        for (int i = 0; i < 4; i++) {
            hbA[i] = hv4[(size_t)idx[i] * 64 + lane];
            float p = pw1[(beg + i) * 4 + head];
            pA[i] = (beg + i < end) ? p : 0.f;
        }
        for (int j = beg; j < end; j += 8) {
            int idxN[8];
#pragma unroll
            for (int i = 0; i < 8; i++) idxN[i] = ssrc[j + 8 + i];
            uint2 hbB[4];
            float pB[4];
#pragma unroll
            for (int i = 0; i < 4; i++) {
                hbB[i] = hv4[(size_t)idx[4 + i] * 64 + lane];
                float p = pw1[(j + 4 + i) * 4 + head];
                pB[i] = (j + 4 + i < end) ? p : 0.f;
            }
#pragma unroll
            for (int i = 0; i < 4; i++) {
                float p = pA[i];
                uint2 hc = hbA[i];
                l += p;
                acc.x = fmaf(p, bflo(hc.x), acc.x);
                acc.y = fmaf(p, bfhi(hc.x), acc.y);
                acc.z = fmaf(p, bflo(hc.y), acc.z);
                acc.w = fmaf(p, bfhi(hc.y), acc.w);
            }
#pragma unroll
            for (int i = 0; i < 4; i++) {
                hbA[i] = hv4[(size_t)idxN[i] * 64 + lane];
                float p = pw1[(j + 8 + i) * 4 + head];
                pA[i] = (j + 8 + i < end) ? p : 0.f;
            }
#pragma unroll
            for (int i = 0; i < 4; i++) {
                float p = pB[i];
                uint2 hc = hbB[i];
                l += p;
                acc.x = fmaf(p, bflo(hc.x), acc.x);
                acc.y = fmaf(p, bfhi(hc.x), acc.y);
                acc.z = fmaf(p, bflo(hc.y), acc.z);
                acc.w = fmaf(p, bfhi(hc.y), acc.w);
            }
#pragma unroll
            for (int i = 0; i < 8; i++) idx[i] = idxN[i];
        }
    }
    float inv = 1.f / (l + EPSF);
    float4 b = ((const float4*)b1)[lane];
    float4 o;
    o.x = fmaxf(fmaf(acc.x, inv, b.x), 0.f);
    o.y = fmaxf(fmaf(acc.y, inv, b.y), 0.f);
    o.z = fmaxf(fmaf(acc.z, inv, b.z), 0.f);
    o.w = fmaxf(fmaf(acc.w, inv, b.w), 0.f);
    ushort4 ob;
    ob.x = f2bf(o.x); ob.y = f2bf(o.y); ob.z = f2bf(o.z); ob.w = f2bf(o.w);
    *(ushort4*)(g1b + (size_t)node * C1 + lane * 4) = ob;
}

// ---------------- layer 2: bf16 MFMA GEMM + fused alpha2 -----------------
// Block = 64 rows x 48 cols (3 n-tiles, cols>=40 zero). A = g1b staged in
// fragment order (32 KB). B frags from 24KB L2-resident wB2. 24 MFMA/wave.
__global__ __launch_bounds__(256) void k_gemm2(const unsigned short* __restrict__ g1b,
                                               const unsigned short* __restrict__ wB2,
                                               const float* __restrict__ aws,
                                               const float* __restrict__ awd,
                                               unsigned short* __restrict__ h2b,
                                               float* __restrict__ as2,
                                               float* __restrict__ ad2) {
    __shared__ uint4 Af[4][8][64];   // [mt][kc][lane], 32 KB
    int t = threadIdx.x;
    int m0 = blockIdx.x * 64;

#pragma unroll
    for (int i = 0; i < 8; i++) {
        int g = i * 256 + t;
        int row = g >> 5;
        int c8 = g & 31;        // uint4 (8 bf16) index within row
        int grow = m0 + row;
        if (grow >= NN) grow = NN - 1;
        uint4 v = *(const uint4*)(g1b + (size_t)grow * C1 + c8 * 8);
        int kc = c8 >> 2;
        int q = c8 & 3;
        Af[row >> 4][kc][q * 16 + (row & 15)] = v;
    }
    __syncthreads();

    int l = t & 63;
    int wv = t >> 6;

    bf16x8 a[8];
#pragma unroll
    for (int kc = 0; kc < 8; kc++) a[kc] = *(const bf16x8*)&Af[wv][kc][l];

    f32x4 acc[3];
#pragma unroll
    for (int tn = 0; tn < 3; tn++) acc[tn] = (f32x4){0.f, 0.f, 0.f, 0.f};

    const bf16x8* wb = (const bf16x8*)wB2 + l;
#pragma unroll
    for (int tn = 0; tn < 3; tn++) {
#pragma unroll
        for (int kc = 0; kc < 8; kc++) {
            bf16x8 b = wb[(tn * 8 + kc) * 64];
            acc[tn] = __builtin_amdgcn_mfma_f32_16x16x32_bf16(a[kc], b, acc[tn], 0, 0, 0);
        }
    }

    int q = l >> 4;
    int c = l & 15;
    int row0 = m0 + wv * 16 + q * 4;
    float ps[4] = {0.f, 0.f, 0.f, 0.f}, pd[4] = {0.f, 0.f, 0.f, 0.f};
#pragma unroll
    for (int tn = 0; tn < 3; tn++) {
        int col = tn * 16 + c;
        bool cok = col < CLS;
        float wsv = cok ? aws[col] : 0.f;
        float wdv = cok ? awd[col] : 0.f;
#pragma unroll
        for (int r = 0; r < 4; r++) {
            float v = acc[tn][r];
            int row = row0 + r;
            if (cok && row < NN) h2b[(size_t)row * CLS + col] = f2bf(v);
            ps[r] = fmaf(v, wsv, ps[r]);
            pd[r] = fmaf(v, wdv, pd[r]);
        }
    }
#pragma unroll
    for (int r = 0; r < 4; r++) {
        float a_ = ps[r], d_ = pd[r];
#pragma unroll
        for (int s = 1; s < 16; s <<= 1) {
            a_ += __shfl_xor(a_, s);
            d_ += __shfl_xor(d_, s);
        }
        int row = row0 + r;
        if (c == 0 && row < NN) {
            as2[row] = a_;
            ad2[row] = d_;
        }
    }
}

// ---------------- layer 2 aggregation + fused log_softmax ----------------
__global__ __launch_bounds__(256) void k_agg2(const unsigned short* __restrict__ h2b,
                                              const float* __restrict__ pw2,
                                              const int* __restrict__ offs,
                                              const int* __restrict__ ssrc,
                                              const float* __restrict__ b2,
                                              float* __restrict__ out) {
    int lane = threadIdx.x & 63;
    int node = blockIdx.x * 4 + (threadIdx.x >> 6);
    int beg = offs[node];
    int end = (node + 1 < NN) ? offs[node + 1] : NE;
    bool act = lane < CLS;
    int cl = act ? lane : CLS - 1;
    float l = 0.f, acc = 0.f;

    if (beg < end) {
        int idx[8];
#pragma unroll
        for (int i = 0; i < 8; i++) idx[i] = ssrc[beg + i];
        unsigned int hbA[4];
        float pA[4];
#pragma unroll
        for (int i = 0; i < 4; i++) {
            hbA[i] = (unsigned int)h2b[(size_t)idx[i] * CLS + cl];
            float p = pw2[beg + i];
            pA[i] = (beg + i < end) ? p : 0.f;
        }
        for (int j = beg; j < end; j += 8) {
            int idxN[8];
#pragma unroll
            for (int i = 0; i < 8; i++) idxN[i] = ssrc[j + 8 + i];
            unsigned int hbB[4];
            float pB[4];
#pragma unroll
            for (int i = 0; i < 4; i++) {
                hbB[i] = (unsigned int)h2b[(size_t)idx[4 + i] * CLS + cl];
                float p = pw2[j + 4 + i];
                pB[i] = (j + 4 + i < end) ? p : 0.f;
            }
#pragma unroll
            for (int i = 0; i < 4; i++) {
                float p = pA[i];
                l += p;
                acc = fmaf(p, __uint_as_float(hbA[i] << 16), acc);
            }
#pragma unroll
            for (int i = 0; i < 4; i++) {
                hbA[i] = (unsigned int)h2b[(size_t)idxN[i] * CLS + cl];
                float p = pw2[j + 8 + i];
                pA[i] = (j + 8 + i < end) ? p : 0.f;
            }
#pragma unroll
            for (int i = 0; i < 4; i++) {
                float p = pB[i];
                l += p;
                acc = fmaf(p, __uint_as_float(hbB[i] << 16), acc);
            }
#pragma unroll
            for (int i = 0; i < 8; i++) idx[i] = idxN[i];
        }
    }
    float v = act ? (acc / (l + EPSF) + b2[cl]) : -INFINITY;
    float mx = v;
#pragma unroll
    for (int s = 32; s >= 1; s >>= 1) mx = fmaxf(mx, __shfl_xor(mx, s));
    float ex = act ? __expf(v - mx) : 0.f;
    float sum = ex;
#pragma unroll
    for (int s = 32; s >= 1; s >>= 1) sum += __shfl_xor(sum, s);
    if (act) out[(size_t)node * CLS + lane] = v - mx - __logf(sum);
}

// ---------------- launch ----------------

extern "C" void kernel_launch(void* const* d_in, const int* in_sizes, int n_in,
                              void* d_out, int out_size, void* d_ws, size_t ws_size,
                              hipStream_t stream) {
    const float* x    = (const float*)d_in[0];
    const int*   ei   = (const int*)d_in[1];
    const float* W1   = (const float*)d_in[2];
    const float* as1w = (const float*)d_in[3];
    const float* ad1w = (const float*)d_in[4];
    const float* b1   = (const float*)d_in[5];
    const float* W2   = (const float*)d_in[6];
    const float* as2w = (const float*)d_in[7];
    const float* ad2w = (const float*)d_in[8];
    const float* b2   = (const float*)d_in[9];
    float* out = (float*)d_out;

    char* p = (char*)d_ws;
    auto alloc = [&](size_t bytes) {
        char* r = p;
        p += (bytes + 255) & ~(size_t)255;
        return r;
    };
    unsigned short* h1b = (unsigned short*)alloc((size_t)NN * C1 * 2);
    unsigned short* g1b = (unsigned short*)alloc((size_t)NN * C1 * 2);
    unsigned short* h2b = (unsigned short*)alloc((size_t)NN * CLS * 2);
    float* as1  = (float*)alloc((size_t)NN * 4 * 4);
    float* ad1  = (float*)alloc((size_t)NN * 4 * 4);
    float* as2  = (float*)alloc((size_t)NN * 4);
    float* ad2  = (float*)alloc((size_t)NN * 4);
    int* counts = (int*)alloc((size_t)NN * 4);
    int* offs   = (int*)alloc((size_t)NN * 4);
    int* cursor = (int*)alloc((size_t)NN * 4);
    int* parts  = (int*)alloc(64 * 4);
    int* ssrc   = (int*)alloc((size_t)(NE + 32) * 4);
    int* sdst   = (int*)alloc((size_t)NE * 4);
    float4* pw1 = (float4*)alloc((size_t)(NE + 16) * 16);
    float* pw2  = (float*)alloc((size_t)(NE + 16) * 4);
    unsigned short* wB1 = (unsigned short*)alloc((size_t)4096 * 8 * 2);
    unsigned short* wB2 = (unsigned short*)alloc((size_t)1536 * 8 * 2);

    const int nb_scan = (NN + 1023) / 1024;  // 49
    const int nb_e = (NE + 255) / 256;       // 3125
    const int nb_ep = nb_e + 1;              // covers NE..NE+255 pad writers

    k_zero<<<(NN + 255) / 256, 256, 0, stream>>>(counts, NN);
    k_hist<<<nb_e, 256, 0, stream>>>(ei, counts);
    k_scan1<<<nb_scan, 1024, 0, stream>>>(counts, offs, parts);
    k_scan2<<<1, 64, 0, stream>>>(parts, nb_scan);
    k_scan3<<<(NN + 255) / 256, 256, 0, stream>>>(offs, parts, cursor);
    k_scatter<<<nb_e, 256, 0, stream>>>(ei, cursor, ssrc, sdst);

    k_wconv<<<22, 256, 0, stream>>>(W1, W2, wB1, wB2);
    k_gemm1<<<(NN + 63) / 64, 256, 0, stream>>>(x, wB1, as1w, ad1w, h1b, as1, ad1);
    k_ew1<<<nb_ep, 256, 0, stream>>>(ssrc, sdst, as1, ad1, pw1, ssrc);
    k_agg1<<<NN / 4, 256, 0, stream>>>(h1b, (const float*)pw1, offs, ssrc, b1, g1b);

    k_gemm2<<<(NN + 63) / 64, 256, 0, stream>>>(g1b, wB2, as2w, ad2w, h2b, as2, ad2);
    k_ew2<<<nb_ep, 256, 0, stream>>>(ssrc, sdst, as2, ad2, pw2);
    k_agg2<<<NN / 4, 256, 0, stream>>>(h2b, pw2, offs, ssrc, b2, out);
}

// Round 11
// 326.349 us; speedup vs baseline: 1.9960x; 1.0089x over previous
//
#include <hip/hip_runtime.h>
#include <math.h>

#define NN 50000
#define NE 800000
#define FIN 128
#define HID 64
#define HEADS 4
#define C1 256   // HEADS*HID
#define CLS 40
#define EPSF 1e-16f

typedef __attribute__((ext_vector_type(8))) short bf16x8;
typedef __attribute__((ext_vector_type(4))) float f32x4;

__device__ __forceinline__ unsigned short f2bf(float f) {
    unsigned int u = __float_as_uint(f);
    unsigned int r = (u + 0x7fffu + ((u >> 16) & 1u)) >> 16;   // RNE
    return (unsigned short)r;
}
__device__ __forceinline__ float bflo(unsigned int u) { return __uint_as_float(u << 16); }
__device__ __forceinline__ float bfhi(unsigned int u) { return __uint_as_float(u & 0xffff0000u); }

// ---------------- counting sort of edges by dst ----------------

__global__ void k_zero(int* a, int n) {
    int i = blockIdx.x * 256 + threadIdx.x;
    if (i < n) a[i] = 0;
}

__global__ void k_hist(const int* __restrict__ ei, int* __restrict__ counts) {
    int i = blockIdx.x * 256 + threadIdx.x;
    if (i < NE) atomicAdd(&counts[ei[NE + i]], 1);
}

__global__ __launch_bounds__(1024) void k_scan1(const int* __restrict__ counts,
                                                int* __restrict__ offs,
                                                int* __restrict__ partials) {
    __shared__ int s[1024];
    int t = threadIdx.x;
    int g = blockIdx.x * 1024 + t;
    int v = (g < NN) ? counts[g] : 0;
    s[t] = v;
    __syncthreads();
    for (int d = 1; d < 1024; d <<= 1) {
        int x = (t >= d) ? s[t - d] : 0;
        __syncthreads();
        s[t] += x;
        __syncthreads();
    }
    if (g < NN) offs[g] = s[t] - v;             // block-local exclusive
    if (t == 1023) partials[blockIdx.x] = s[t]; // block total
}

__global__ void k_scan2(int* partials, int nb) {
    if (threadIdx.x == 0 && blockIdx.x == 0) {
        int run = 0;
        for (int b = 0; b < nb; b++) { int v = partials[b]; partials[b] = run; run += v; }
    }
}

__global__ void k_scan3(int* __restrict__ offs, const int* __restrict__ partials,
                        int* __restrict__ cursor) {
    int g = blockIdx.x * 256 + threadIdx.x;
    if (g < NN) {
        int o = offs[g] + partials[g >> 10];
        offs[g] = o;
        cursor[g] = o;
    }
}

__global__ void k_scatter(const int* __restrict__ ei, int* __restrict__ cursor,
                          int* __restrict__ ssrc, int* __restrict__ sdst) {
    int i = blockIdx.x * 256 + threadIdx.x;
    if (i < NE) {
        int s = ei[i];
        int d = ei[NE + i];
        int p = atomicAdd(&cursor[d], 1);
        ssrc[p] = s;
        sdst[p] = d;
    }
}

// ---------------- per-edge softmax weights + tail padding ----------------

__global__ __launch_bounds__(256) void k_ew1(const int* __restrict__ ssrc,
                                             const int* __restrict__ sdst,
                                             const float* __restrict__ as1,
                                             const float* __restrict__ ad1,
                                             float4* __restrict__ pw1,
                                             int* __restrict__ ssrc_pad) {
    int j = blockIdx.x * 256 + threadIdx.x;
    if (j < NE) {
        int s = ssrc[j], d = sdst[j];
        float4 a = *(const float4*)(as1 + s * 4);
        float4 bb = *(const float4*)(ad1 + d * 4);
        float4 e = {a.x + bb.x, a.y + bb.y, a.z + bb.z, a.w + bb.w};
        e.x = e.x > 0.f ? e.x : 0.2f * e.x;
        e.y = e.y > 0.f ? e.y : 0.2f * e.y;
        e.z = e.z > 0.f ? e.z : 0.2f * e.z;
        e.w = e.w > 0.f ? e.w : 0.2f * e.w;
        float4 p = {__expf(e.x), __expf(e.y), __expf(e.z), __expf(e.w)};
        pw1[j] = p;
    } else {
        if (j < NE + 16) pw1[j] = (float4){0.f, 0.f, 0.f, 0.f};
        if (j < NE + 32) ssrc_pad[j] = 0;
    }
}

__global__ __launch_bounds__(256) void k_ew2(const int* __restrict__ ssrc,
                                             const int* __restrict__ sdst,
                                             const float* __restrict__ as2,
                                             const float* __restrict__ ad2,
                                             float* __restrict__ pw2) {
    int j = blockIdx.x * 256 + threadIdx.x;
    if (j < NE) {
        float e = as2[ssrc[j]] + ad2[sdst[j]];
        e = e > 0.f ? e : 0.2f * e;
        pw2[j] = __expf(e);
    } else if (j < NE + 16) {
        pw2[j] = 0.f;
    }
}

// ---------------- W1/W2 -> bf16 MFMA B-fragment buffers (one-time) -------
__global__ __launch_bounds__(256) void k_wconv(const float* __restrict__ W1,
                                               const float* __restrict__ W2,
                                               unsigned short* __restrict__ wB1,
                                               unsigned short* __restrict__ wB2) {
    int t = blockIdx.x * 256 + threadIdx.x;
    if (t < 4096) {
        int tn = t >> 8;
        int kc = (t >> 6) & 3;
        int l = t & 63;
        int n = tn * 16 + (l & 15);
        int k0 = kc * 32 + (l >> 4) * 8;
        unsigned short* o = wB1 + (size_t)t * 8;
#pragma unroll
        for (int j = 0; j < 8; j++) o[j] = f2bf(W1[(size_t)(k0 + j) * C1 + n]);
    } else if (t < 4096 + 1536) {
        int u = t - 4096;
        int tn = u >> 9;
        int kc = (u >> 6) & 7;
        int l = u & 63;
        int n = tn * 16 + (l & 15);
        int k0 = kc * 32 + (l >> 4) * 8;
        unsigned short* o = wB2 + (size_t)u * 8;
#pragma unroll
        for (int j = 0; j < 8; j++)
            o[j] = (n < CLS) ? f2bf(W2[(size_t)(k0 + j) * CLS + n]) : (unsigned short)0;
    }
}

// ---------------- layer 1: bf16 MFMA GEMM + fused alpha dots -------------
__global__ __launch_bounds__(256) void k_gemm1(const float* __restrict__ x,
                                               const unsigned short* __restrict__ wB,
                                               const float* __restrict__ aws,
                                               const float* __restrict__ awd,
                                               unsigned short* __restrict__ h1b,
                                               float* __restrict__ as1,
                                               float* __restrict__ ad1) {
    __shared__ uint4 Af[4][4][64];   // [mt][kc][lane], 16 KB
    int t = threadIdx.x;
    int m0 = blockIdx.x * 64;

#pragma unroll
    for (int i = 0; i < 8; i++) {
        int g = i * 256 + t;
        int row = g >> 5;
        int c4 = g & 31;
        int grow = m0 + row;
        if (grow >= NN) grow = NN - 1;
        float4 v = *(const float4*)(x + (size_t)grow * FIN + c4 * 4);
        uint2 pk;
        pk.x = (unsigned int)f2bf(v.x) | ((unsigned int)f2bf(v.y) << 16);
        pk.y = (unsigned int)f2bf(v.z) | ((unsigned int)f2bf(v.w) << 16);
        int kc = c4 >> 3;
        int rem = (c4 & 7) * 4;
        int q = rem >> 3;
        int hh = (rem >> 2) & 1;
        int l = q * 16 + (row & 15);
        int mt = row >> 4;
        ((uint2*)&Af[mt][kc][l])[hh] = pk;
    }
    __syncthreads();

    int l = t & 63;
    int wv = t >> 6;

    bf16x8 a[4];
#pragma unroll
    for (int kc = 0; kc < 4; kc++) a[kc] = *(const bf16x8*)&Af[wv][kc][l];

    f32x4 acc[16];
#pragma unroll
    for (int tn = 0; tn < 16; tn++) acc[tn] = (f32x4){0.f, 0.f, 0.f, 0.f};

    const bf16x8* wb = (const bf16x8*)wB + l;
#pragma unroll
    for (int tn = 0; tn < 16; tn++) {
        bf16x8 b0 = wb[(tn * 4 + 0) * 64];
        bf16x8 b1 = wb[(tn * 4 + 1) * 64];
        bf16x8 b2 = wb[(tn * 4 + 2) * 64];
        bf16x8 b3 = wb[(tn * 4 + 3) * 64];
        acc[tn] = __builtin_amdgcn_mfma_f32_16x16x32_bf16(a[0], b0, acc[tn], 0, 0, 0);
        acc[tn] = __builtin_amdgcn_mfma_f32_16x16x32_bf16(a[1], b1, acc[tn], 0, 0, 0);
        acc[tn] = __builtin_amdgcn_mfma_f32_16x16x32_bf16(a[2], b2, acc[tn], 0, 0, 0);
        acc[tn] = __builtin_amdgcn_mfma_f32_16x16x32_bf16(a[3], b3, acc[tn], 0, 0, 0);
    }

    int q = l >> 4;
    int c = l & 15;
    int row0 = m0 + wv * 16 + q * 4;
    float psum[4][4], pdsum[4][4];
#pragma unroll
    for (int h = 0; h < 4; h++)
#pragma unroll
        for (int r = 0; r < 4; r++) { psum[h][r] = 0.f; pdsum[h][r] = 0.f; }

#pragma unroll
    for (int tn = 0; tn < 16; tn++) {
        int col = tn * 16 + c;
        int h = tn >> 2;
        float wsv = aws[col];
        float wdv = awd[col];
#pragma unroll
        for (int r = 0; r < 4; r++) {
            float v = acc[tn][r];
            int row = row0 + r;
            if (row < NN) h1b[(size_t)row * C1 + col] = f2bf(v);
            psum[h][r] = fmaf(v, wsv, psum[h][r]);
            pdsum[h][r] = fmaf(v, wdv, pdsum[h][r]);
        }
    }
#pragma unroll
    for (int h = 0; h < 4; h++)
#pragma unroll
        for (int r = 0; r < 4; r++) {
            float ps = psum[h][r], pd = pdsum[h][r];
#pragma unroll
            for (int s = 1; s < 16; s <<= 1) {
                ps += __shfl_xor(ps, s);
                pd += __shfl_xor(pd, s);
            }
            int row = row0 + r;
            if (c == 0 && row < NN) {
                as1[row * 4 + h] = ps;
                ad1[row * 4 + h] = pd;
            }
        }
}

// ---------------- layer 1 aggregation (2 edges per wave-slot) ------------
// Lanes split into two 32-lane halves; each half gathers one full 512B row
// via uint4 (8 bf16 ch/lane). A/B double-buffered ring over 2-unit groups
// (unit = edge pair). Cross-half combine at the end via shfl_xor(32).
__global__ __launch_bounds__(256) void k_agg1(const unsigned short* __restrict__ h1b,
                                              const float* __restrict__ pw1,
                                              const int* __restrict__ offs,
                                              const int* __restrict__ ssrc,
                                              const float* __restrict__ b1,
                                              unsigned short* __restrict__ g1b) {
    int lane = threadIdx.x & 63;
    int half = lane >> 5;
    int hl = lane & 31;          // channel group: ch hl*8..+7
    int head = hl >> 3;
    int node = blockIdx.x * 4 + (threadIdx.x >> 6);
    int beg = offs[node];
    int end = (node + 1 < NN) ? offs[node + 1] : NE;
    float l = 0.f;
    float acc[8];
#pragma unroll
    for (int c = 0; c < 8; c++) acc[c] = 0.f;
    const uint4* hv = (const uint4*)h1b;   // 32 uint4 per row

    if (beg < end) {
        int idx[4];
#pragma unroll
        for (int i = 0; i < 4; i++) idx[i] = ssrc[beg + 2 * i + half];
        uint4 hbA[2];
        float pA[2];
#pragma unroll
        for (int i = 0; i < 2; i++) {
            hbA[i] = hv[(size_t)idx[i] * 32 + hl];
            int e = beg + 2 * i + half;
            float p = pw1[e * 4 + head];
            pA[i] = (e < end) ? p : 0.f;
        }
        for (int j = beg; j < end; j += 8) {
            int idxN[4];
#pragma unroll
            for (int i = 0; i < 4; i++) idxN[i] = ssrc[j + 8 + 2 * i + half];
            uint4 hbB[2];
            float pB[2];
#pragma unroll
            for (int i = 0; i < 2; i++) {
                hbB[i] = hv[(size_t)idx[2 + i] * 32 + hl];
                int e = j + 4 + 2 * i + half;
                float p = pw1[e * 4 + head];
                pB[i] = (e < end) ? p : 0.f;
            }
#pragma unroll
            for (int i = 0; i < 2; i++) {
                float p = pA[i];
                uint4 hc = hbA[i];
                l += p;
                acc[0] = fmaf(p, bflo(hc.x), acc[0]);
                acc[1] = fmaf(p, bfhi(hc.x), acc[1]);
                acc[2] = fmaf(p, bflo(hc.y), acc[2]);
                acc[3] = fmaf(p, bfhi(hc.y), acc[3]);
                acc[4] = fmaf(p, bflo(hc.z), acc[4]);
                acc[5] = fmaf(p, bfhi(hc.z), acc[5]);
                acc[6] = fmaf(p, bflo(hc.w), acc[6]);
                acc[7] = fmaf(p, bfhi(hc.w), acc[7]);
            }
#pragma unroll
            for (int i = 0; i < 2; i++) {
                hbA[i] = hv[(size_t)idxN[i] * 32 + hl];
                int e = j + 8 + 2 * i + half;
                float p = pw1[e * 4 + head];
                pA[i] = (e < end) ? p : 0.f;
            }
#pragma unroll
            for (int i = 0; i < 2; i++) {
                float p = pB[i];
                uint4 hc = hbB[i];
                l += p;
                acc[0] = fmaf(p, bflo(hc.x), acc[0]);
                acc[1] = fmaf(p, bfhi(hc.x), acc[1]);
                acc[2] = fmaf(p, bflo(hc.y), acc[2]);
                acc[3] = fmaf(p, bfhi(hc.y), acc[3]);
                acc[4] = fmaf(p, bflo(hc.z), acc[4]);
                acc[5] = fmaf(p, bfhi(hc.z), acc[5]);
                acc[6] = fmaf(p, bflo(hc.w), acc[6]);
                acc[7] = fmaf(p, bfhi(hc.w), acc[7]);
            }
#pragma unroll
            for (int i = 0; i < 4; i++) idx[i] = idxN[i];
        }
    }
    // combine the two halves (same channels, disjoint edge subsets)
    l += __shfl_xor(l, 32);
#pragma unroll
    for (int c = 0; c < 8; c++) acc[c] += __shfl_xor(acc[c], 32);

    if (half == 0) {
        float inv = 1.f / (l + EPSF);
        const float4* b1v = (const float4*)b1;
        float4 b0 = b1v[hl * 2];
        float4 b1_ = b1v[hl * 2 + 1];
        float o[8];
        o[0] = fmaxf(fmaf(acc[0], inv, b0.x), 0.f);
        o[1] = fmaxf(fmaf(acc[1], inv, b0.y), 0.f);
        o[2] = fmaxf(fmaf(acc[2], inv, b0.z), 0.f);
        o[3] = fmaxf(fmaf(acc[3], inv, b0.w), 0.f);
        o[4] = fmaxf(fmaf(acc[4], inv, b1_.x), 0.f);
        o[5] = fmaxf(fmaf(acc[5], inv, b1_.y), 0.f);
        o[6] = fmaxf(fmaf(acc[6], inv, b1_.z), 0.f);
        o[7] = fmaxf(fmaf(acc[7], inv, b1_.w), 0.f);
        uint4 ob;
        ob.x = (unsigned int)f2bf(o[0]) | ((unsigned int)f2bf(o[1]) << 16);
        ob.y = (unsigned int)f2bf(o[2]) | ((unsigned int)f2bf(o[3]) << 16);
        ob.z = (unsigned int)f2bf(o[4]) | ((unsigned int)f2bf(o[5]) << 16);
        ob.w = (unsigned int)f2bf(o[6]) | ((unsigned int)f2bf(o[7]) << 16);
        ((uint4*)g1b)[(size_t)node * 32 + hl] = ob;
    }
}

// ---------------- layer 2: bf16 MFMA GEMM + fused alpha2 -----------------
__global__ __launch_bounds__(256) void k_gemm2(const unsigned short* __restrict__ g1b,
                                               const unsigned short* __restrict__ wB2,
                                               const float* __restrict__ aws,
                                               const float* __restrict__ awd,
                                               unsigned short* __restrict__ h2b,
                                               float* __restrict__ as2,
                                               float* __restrict__ ad2) {
    __shared__ uint4 Af[4][8][64];   // [mt][kc][lane], 32 KB
    int t = threadIdx.x;
    int m0 = blockIdx.x * 64;

#pragma unroll
    for (int i = 0; i < 8; i++) {
        int g = i * 256 + t;
        int row = g >> 5;
        int c8 = g & 31;
        int grow = m0 + row;
        if (grow >= NN) grow = NN - 1;
        uint4 v = *(const uint4*)(g1b + (size_t)grow * C1 + c8 * 8);
        int kc = c8 >> 2;
        int q = c8 & 3;
        Af[row >> 4][kc][q * 16 + (row & 15)] = v;
    }
    __syncthreads();

    int l = t & 63;
    int wv = t >> 6;

    bf16x8 a[8];
#pragma unroll
    for (int kc = 0; kc < 8; kc++) a[kc] = *(const bf16x8*)&Af[wv][kc][l];

    f32x4 acc[3];
#pragma unroll
    for (int tn = 0; tn < 3; tn++) acc[tn] = (f32x4){0.f, 0.f, 0.f, 0.f};

    const bf16x8* wb = (const bf16x8*)wB2 + l;
#pragma unroll
    for (int tn = 0; tn < 3; tn++) {
#pragma unroll
        for (int kc = 0; kc < 8; kc++) {
            bf16x8 b = wb[(tn * 8 + kc) * 64];
            acc[tn] = __builtin_amdgcn_mfma_f32_16x16x32_bf16(a[kc], b, acc[tn], 0, 0, 0);
        }
    }

    int q = l >> 4;
    int c = l & 15;
    int row0 = m0 + wv * 16 + q * 4;
    float ps[4] = {0.f, 0.f, 0.f, 0.f}, pd[4] = {0.f, 0.f, 0.f, 0.f};
#pragma unroll
    for (int tn = 0; tn < 3; tn++) {
        int col = tn * 16 + c;
        bool cok = col < CLS;
        float wsv = cok ? aws[col] : 0.f;
        float wdv = cok ? awd[col] : 0.f;
#pragma unroll
        for (int r = 0; r < 4; r++) {
            float v = acc[tn][r];
            int row = row0 + r;
            if (cok && row < NN) h2b[(size_t)row * CLS + col] = f2bf(v);
            ps[r] = fmaf(v, wsv, ps[r]);
            pd[r] = fmaf(v, wdv, pd[r]);
        }
    }
#pragma unroll
    for (int r = 0; r < 4; r++) {
        float a_ = ps[r], d_ = pd[r];
#pragma unroll
        for (int s = 1; s < 16; s <<= 1) {
            a_ += __shfl_xor(a_, s);
            d_ += __shfl_xor(d_, s);
        }
        int row = row0 + r;
        if (c == 0 && row < NN) {
            as2[row] = a_;
            ad2[row] = d_;
        }
    }
}

// ---------------- layer 2 aggregation + fused log_softmax ----------------
// Same 2-edges-per-slot split: each half gathers one 80B row via uint
// (2 ch/lane, 20 active lanes). Cross-half combine + per-node log_softmax.
__global__ __launch_bounds__(256) void k_agg2(const unsigned short* __restrict__ h2b,
                                              const float* __restrict__ pw2,
                                              const int* __restrict__ offs,
                                              const int* __restrict__ ssrc,
                                              const float* __restrict__ b2,
                                              float* __restrict__ out) {
    int lane = threadIdx.x & 63;
    int half = lane >> 5;
    int hl = lane & 31;
    int cl = hl < 20 ? hl : 19;   // uint index within row (2 channels)
    int node = blockIdx.x * 4 + (threadIdx.x >> 6);
    int beg = offs[node];
    int end = (node + 1 < NN) ? offs[node + 1] : NE;
    float l = 0.f, aL = 0.f, aH = 0.f;
    const unsigned int* hv = (const unsigned int*)h2b;   // 20 uints per row

    if (beg < end) {
        int idx[4];
#pragma unroll
        for (int i = 0; i < 4; i++) idx[i] = ssrc[beg + 2 * i + half];
        unsigned int hbA[2];
        float pA[2];
#pragma unroll
        for (int i = 0; i < 2; i++) {
            hbA[i] = hv[(size_t)idx[i] * 20 + cl];
            int e = beg + 2 * i + half;
            float p = pw2[e];
            pA[i] = (e < end) ? p : 0.f;
        }
        for (int j = beg; j < end; j += 8) {
            int idxN[4];
#pragma unroll
            for (int i = 0; i < 4; i++) idxN[i] = ssrc[j + 8 + 2 * i + half];
            unsigned int hbB[2];
            float pB[2];
#pragma unroll
            for (int i = 0; i < 2; i++) {
                hbB[i] = hv[(size_t)idx[2 + i] * 20 + cl];
                int e = j + 4 + 2 * i + half;
                float p = pw2[e];
                pB[i] = (e < end) ? p : 0.f;
            }
#pragma unroll
            for (int i = 0; i < 2; i++) {
                float p = pA[i];
                l += p;
                aL = fmaf(p, bflo(hbA[i]), aL);
                aH = fmaf(p, bfhi(hbA[i]), aH);
            }
#pragma unroll
            for (int i = 0; i < 2; i++) {
                hbA[i] = hv[(size_t)idxN[i] * 20 + cl];
                int e = j + 8 + 2 * i + half;
                float p = pw2[e];
                pA[i] = (e < end) ? p : 0.f;
            }
#pragma unroll
            for (int i = 0; i < 2; i++) {
                float p = pB[i];
                l += p;
                aL = fmaf(p, bflo(hbB[i]), aL);
                aH = fmaf(p, bfhi(hbB[i]), aH);
            }
#pragma unroll
            for (int i = 0; i < 4; i++) idx[i] = idxN[i];
        }
    }
    l += __shfl_xor(l, 32);
    aL += __shfl_xor(aL, 32);
    aH += __shfl_xor(aH, 32);

    if (half == 0) {
        bool act = hl < 20;
        float inv = 1.f / (l + EPSF);
        float vL = -INFINITY, vH = -INFINITY;
        if (act) {
            float2 b = ((const float2*)b2)[cl];
            vL = aL * inv + b.x;
            vH = aH * inv + b.y;
        }
        float mx = fmaxf(vL, vH);
#pragma unroll
        for (int s = 16; s >= 1; s >>= 1) mx = fmaxf(mx, __shfl_xor(mx, s));
        float ex = act ? (__expf(vL - mx) + __expf(vH - mx)) : 0.f;
#pragma unroll
        for (int s = 16; s >= 1; s >>= 1) ex += __shfl_xor(ex, s);
        if (act) {
            float ls = __logf(ex);
            float2 o = {vL - mx - ls, vH - mx - ls};
            *(float2*)(out + (size_t)node * CLS + cl * 2) = o;
        }
    }
}

// ---------------- launch ----------------

extern "C" void kernel_launch(void* const* d_in, const int* in_sizes, int n_in,
                              void* d_out, int out_size, void* d_ws, size_t ws_size,
                              hipStream_t stream) {
    const float* x    = (const float*)d_in[0];
    const int*   ei   = (const int*)d_in[1];
    const float* W1   = (const float*)d_in[2];
    const float* as1w = (const float*)d_in[3];
    const float* ad1w = (const float*)d_in[4];
    const float* b1   = (const float*)d_in[5];
    const float* W2   = (const float*)d_in[6];
    const float* as2w = (const float*)d_in[7];
    const float* ad2w = (const float*)d_in[8];
    const float* b2   = (const float*)d_in[9];
    float* out = (float*)d_out;

    char* p = (char*)d_ws;
    auto alloc = [&](size_t bytes) {
        char* r = p;
        p += (bytes + 255) & ~(size_t)255;
        return r;
    };
    unsigned short* h1b = (unsigned short*)alloc((size_t)NN * C1 * 2);
    unsigned short* g1b = (unsigned short*)alloc((size_t)NN * C1 * 2);
    unsigned short* h2b = (unsigned short*)alloc((size_t)NN * CLS * 2);
    float* as1  = (float*)alloc((size_t)NN * 4 * 4);
    float* ad1  = (float*)alloc((size_t)NN * 4 * 4);
    float* as2  = (float*)alloc((size_t)NN * 4);
    float* ad2  = (float*)alloc((size_t)NN * 4);
    int* counts = (int*)alloc((size_t)NN * 4);
    int* offs   = (int*)alloc((size_t)NN * 4);
    int* cursor = (int*)alloc((size_t)NN * 4);
    int* parts  = (int*)alloc(64 * 4);
    int* ssrc   = (int*)alloc((size_t)(NE + 32) * 4);
    int* sdst   = (int*)alloc((size_t)NE * 4);
    float4* pw1 = (float4*)alloc((size_t)(NE + 16) * 16);
    float* pw2  = (float*)alloc((size_t)(NE + 16) * 4);
    unsigned short* wB1 = (unsigned short*)alloc((size_t)4096 * 8 * 2);
    unsigned short* wB2 = (unsigned short*)alloc((size_t)1536 * 8 * 2);

    const int nb_scan = (NN + 1023) / 1024;  // 49
    const int nb_e = (NE + 255) / 256;       // 3125
    const int nb_ep = nb_e + 1;              // covers NE..NE+255 pad writers

    k_zero<<<(NN + 255) / 256, 256, 0, stream>>>(counts, NN);
    k_hist<<<nb_e, 256, 0, stream>>>(ei, counts);
    k_scan1<<<nb_scan, 1024, 0, stream>>>(counts, offs, parts);
    k_scan2<<<1, 64, 0, stream>>>(parts, nb_scan);
    k_scan3<<<(NN + 255) / 256, 256, 0, stream>>>(offs, parts, cursor);
    k_scatter<<<nb_e, 256, 0, stream>>>(ei, cursor, ssrc, sdst);

    k_wconv<<<22, 256, 0, stream>>>(W1, W2, wB1, wB2);
    k_gemm1<<<(NN + 63) / 64, 256, 0, stream>>>(x, wB1, as1w, ad1w, h1b, as1, ad1);
    k_ew1<<<nb_ep, 256, 0, stream>>>(ssrc, sdst, as1, ad1, pw1, ssrc);
    k_agg1<<<NN / 4, 256, 0, stream>>>(h1b, (const float*)pw1, offs, ssrc, b1, g1b);

    k_gemm2<<<(NN + 63) / 64, 256, 0, stream>>>(g1b, wB2, as2w, ad2w, h2b, as2, ad2);
    k_ew2<<<nb_ep, 256, 0, stream>>>(ssrc, sdst, as2, ad2, pw2);
    k_agg2<<<NN / 4, 256, 0, stream>>>(h2b, pw2, offs, ssrc, b2, out);
}

// Round 12
// 291.875 us; speedup vs baseline: 2.2317x; 1.1181x over previous
//
#include <hip/hip_runtime.h>
#include <math.h>

#define NN 50000
#define NE 800000
#define FIN 128
#define HID 64
#define HEADS 4
#define C1 256   // HEADS*HID
#define CLS 40
#define EPSF 1e-16f

typedef __attribute__((ext_vector_type(8))) short bf16x8;
typedef __attribute__((ext_vector_type(4))) float f32x4;
typedef __attribute__((ext_vector_type(2))) float f32x2;

__device__ __forceinline__ unsigned short f2bf(float f) {
    unsigned int u = __float_as_uint(f);
    unsigned int r = (u + 0x7fffu + ((u >> 16) & 1u)) >> 16;   // RNE
    return (unsigned short)r;
}
__device__ __forceinline__ float bflo(unsigned int u) { return __uint_as_float(u << 16); }
__device__ __forceinline__ float bfhi(unsigned int u) { return __uint_as_float(u & 0xffff0000u); }
__device__ __forceinline__ unsigned char f2fp8(float v) {
    int pk = __builtin_amdgcn_cvt_pk_fp8_f32(v, v, 0, false);
    return (unsigned char)(pk & 0xff);
}

// ---------------- counting sort of edges by dst ----------------

__global__ void k_zero(int* a, int n) {
    int i = blockIdx.x * 256 + threadIdx.x;
    if (i < n) a[i] = 0;
}

__global__ void k_hist(const int* __restrict__ ei, int* __restrict__ counts) {
    int i = blockIdx.x * 256 + threadIdx.x;
    if (i < NE) atomicAdd(&counts[ei[NE + i]], 1);
}

__global__ __launch_bounds__(1024) void k_scan1(const int* __restrict__ counts,
                                                int* __restrict__ offs,
                                                int* __restrict__ partials) {
    __shared__ int s[1024];
    int t = threadIdx.x;
    int g = blockIdx.x * 1024 + t;
    int v = (g < NN) ? counts[g] : 0;
    s[t] = v;
    __syncthreads();
    for (int d = 1; d < 1024; d <<= 1) {
        int x = (t >= d) ? s[t - d] : 0;
        __syncthreads();
        s[t] += x;
        __syncthreads();
    }
    if (g < NN) offs[g] = s[t] - v;             // block-local exclusive
    if (t == 1023) partials[blockIdx.x] = s[t]; // block total
}

__global__ void k_scan2(int* partials, int nb) {
    if (threadIdx.x == 0 && blockIdx.x == 0) {
        int run = 0;
        for (int b = 0; b < nb; b++) { int v = partials[b]; partials[b] = run; run += v; }
    }
}

__global__ void k_scan3(int* __restrict__ offs, const int* __restrict__ partials,
                        int* __restrict__ cursor) {
    int g = blockIdx.x * 256 + threadIdx.x;
    if (g < NN) {
        int o = offs[g] + partials[g >> 10];
        offs[g] = o;
        cursor[g] = o;
    }
}

__global__ void k_scatter(const int* __restrict__ ei, int* __restrict__ cursor,
                          int* __restrict__ ssrc, int* __restrict__ sdst) {
    int i = blockIdx.x * 256 + threadIdx.x;
    if (i < NE) {
        int s = ei[i];
        int d = ei[NE + i];
        int p = atomicAdd(&cursor[d], 1);
        ssrc[p] = s;
        sdst[p] = d;
    }
}

// ---------------- per-edge softmax weights + tail padding ----------------

__global__ __launch_bounds__(256) void k_ew1(const int* __restrict__ ssrc,
                                             const int* __restrict__ sdst,
                                             const float* __restrict__ as1,
                                             const float* __restrict__ ad1,
                                             float4* __restrict__ pw1,
                                             int* __restrict__ ssrc_pad) {
    int j = blockIdx.x * 256 + threadIdx.x;
    if (j < NE) {
        int s = ssrc[j], d = sdst[j];
        float4 a = *(const float4*)(as1 + s * 4);
        float4 bb = *(const float4*)(ad1 + d * 4);
        float4 e = {a.x + bb.x, a.y + bb.y, a.z + bb.z, a.w + bb.w};
        e.x = e.x > 0.f ? e.x : 0.2f * e.x;
        e.y = e.y > 0.f ? e.y : 0.2f * e.y;
        e.z = e.z > 0.f ? e.z : 0.2f * e.z;
        e.w = e.w > 0.f ? e.w : 0.2f * e.w;
        float4 p = {__expf(e.x), __expf(e.y), __expf(e.z), __expf(e.w)};
        pw1[j] = p;
    } else {
        if (j < NE + 16) pw1[j] = (float4){0.f, 0.f, 0.f, 0.f};
        if (j < NE + 32) ssrc_pad[j] = 0;
    }
}

__global__ __launch_bounds__(256) void k_ew2(const int* __restrict__ ssrc,
                                             const int* __restrict__ sdst,
                                             const float* __restrict__ as2,
                                             const float* __restrict__ ad2,
                                             float* __restrict__ pw2) {
    int j = blockIdx.x * 256 + threadIdx.x;
    if (j < NE) {
        float e = as2[ssrc[j]] + ad2[sdst[j]];
        e = e > 0.f ? e : 0.2f * e;
        pw2[j] = __expf(e);
    } else if (j < NE + 16) {
        pw2[j] = 0.f;
    }
}

// ---------------- W1/W2 -> bf16 MFMA B-fragment buffers (one-time) -------
__global__ __launch_bounds__(256) void k_wconv(const float* __restrict__ W1,
                                               const float* __restrict__ W2,
                                               unsigned short* __restrict__ wB1,
                                               unsigned short* __restrict__ wB2) {
    int t = blockIdx.x * 256 + threadIdx.x;
    if (t < 4096) {
        int tn = t >> 8;
        int kc = (t >> 6) & 3;
        int l = t & 63;
        int n = tn * 16 + (l & 15);
        int k0 = kc * 32 + (l >> 4) * 8;
        unsigned short* o = wB1 + (size_t)t * 8;
#pragma unroll
        for (int j = 0; j < 8; j++) o[j] = f2bf(W1[(size_t)(k0 + j) * C1 + n]);
    } else if (t < 4096 + 1536) {
        int u = t - 4096;
        int tn = u >> 9;
        int kc = (u >> 6) & 7;
        int l = u & 63;
        int n = tn * 16 + (l & 15);
        int k0 = kc * 32 + (l >> 4) * 8;
        unsigned short* o = wB2 + (size_t)u * 8;
#pragma unroll
        for (int j = 0; j < 8; j++)
            o[j] = (n < CLS) ? f2bf(W2[(size_t)(k0 + j) * CLS + n]) : (unsigned short)0;
    }
}

// ---------------- layer 1: bf16 MFMA GEMM + fused alpha dots -------------
// Messages now stored as fp8 e4m3 (256 B/row) to halve agg1's gather bytes.
__global__ __launch_bounds__(256) void k_gemm1(const float* __restrict__ x,
                                               const unsigned short* __restrict__ wB,
                                               const float* __restrict__ aws,
                                               const float* __restrict__ awd,
                                               unsigned char* __restrict__ h1f8,
                                               float* __restrict__ as1,
                                               float* __restrict__ ad1) {
    __shared__ uint4 Af[4][4][64];   // [mt][kc][lane], 16 KB
    int t = threadIdx.x;
    int m0 = blockIdx.x * 64;

#pragma unroll
    for (int i = 0; i < 8; i++) {
        int g = i * 256 + t;
        int row = g >> 5;
        int c4 = g & 31;
        int grow = m0 + row;
        if (grow >= NN) grow = NN - 1;
        float4 v = *(const float4*)(x + (size_t)grow * FIN + c4 * 4);
        uint2 pk;
        pk.x = (unsigned int)f2bf(v.x) | ((unsigned int)f2bf(v.y) << 16);
        pk.y = (unsigned int)f2bf(v.z) | ((unsigned int)f2bf(v.w) << 16);
        int kc = c4 >> 3;
        int rem = (c4 & 7) * 4;
        int q = rem >> 3;
        int hh = (rem >> 2) & 1;
        int l = q * 16 + (row & 15);
        int mt = row >> 4;
        ((uint2*)&Af[mt][kc][l])[hh] = pk;
    }
    __syncthreads();

    int l = t & 63;
    int wv = t >> 6;

    bf16x8 a[4];
#pragma unroll
    for (int kc = 0; kc < 4; kc++) a[kc] = *(const bf16x8*)&Af[wv][kc][l];

    f32x4 acc[16];
#pragma unroll
    for (int tn = 0; tn < 16; tn++) acc[tn] = (f32x4){0.f, 0.f, 0.f, 0.f};

    const bf16x8* wb = (const bf16x8*)wB + l;
#pragma unroll
    for (int tn = 0; tn < 16; tn++) {
        bf16x8 b0 = wb[(tn * 4 + 0) * 64];
        bf16x8 b1 = wb[(tn * 4 + 1) * 64];
        bf16x8 b2 = wb[(tn * 4 + 2) * 64];
        bf16x8 b3 = wb[(tn * 4 + 3) * 64];
        acc[tn] = __builtin_amdgcn_mfma_f32_16x16x32_bf16(a[0], b0, acc[tn], 0, 0, 0);
        acc[tn] = __builtin_amdgcn_mfma_f32_16x16x32_bf16(a[1], b1, acc[tn], 0, 0, 0);
        acc[tn] = __builtin_amdgcn_mfma_f32_16x16x32_bf16(a[2], b2, acc[tn], 0, 0, 0);
        acc[tn] = __builtin_amdgcn_mfma_f32_16x16x32_bf16(a[3], b3, acc[tn], 0, 0, 0);
    }

    int q = l >> 4;
    int c = l & 15;
    int row0 = m0 + wv * 16 + q * 4;
    float psum[4][4], pdsum[4][4];
#pragma unroll
    for (int h = 0; h < 4; h++)
#pragma unroll
        for (int r = 0; r < 4; r++) { psum[h][r] = 0.f; pdsum[h][r] = 0.f; }

#pragma unroll
    for (int tn = 0; tn < 16; tn++) {
        int col = tn * 16 + c;
        int h = tn >> 2;
        float wsv = aws[col];
        float wdv = awd[col];
#pragma unroll
        for (int r = 0; r < 4; r++) {
            float v = acc[tn][r];
            int row = row0 + r;
            if (row < NN) h1f8[(size_t)row * C1 + col] = f2fp8(v);
            psum[h][r] = fmaf(v, wsv, psum[h][r]);
            pdsum[h][r] = fmaf(v, wdv, pdsum[h][r]);
        }
    }
#pragma unroll
    for (int h = 0; h < 4; h++)
#pragma unroll
        for (int r = 0; r < 4; r++) {
            float ps = psum[h][r], pd = pdsum[h][r];
#pragma unroll
            for (int s = 1; s < 16; s <<= 1) {
                ps += __shfl_xor(ps, s);
                pd += __shfl_xor(pd, s);
            }
            int row = row0 + r;
            if (c == 0 && row < NN) {
                as1[row * 4 + h] = ps;
                ad1[row * 4 + h] = pd;
            }
        }
}

// ---------------- layer 1 aggregation (fp8 messages, 2 edges/slot) -------
// Lanes split into two 32-lane halves; each half gathers one full 256B fp8
// row via uint2 (8 fp8 ch/lane). Decode with HW cvt_pk_f32_fp8 (2 ch/op).
__global__ __launch_bounds__(256) void k_agg1(const unsigned char* __restrict__ h1f8,
                                              const float* __restrict__ pw1,
                                              const int* __restrict__ offs,
                                              const int* __restrict__ ssrc,
                                              const float* __restrict__ b1,
                                              unsigned short* __restrict__ g1b) {
    int lane = threadIdx.x & 63;
    int half = lane >> 5;
    int hl = lane & 31;          // channel group: ch hl*8..+7
    int head = hl >> 3;
    int node = blockIdx.x * 4 + (threadIdx.x >> 6);
    int beg = offs[node];
    int end = (node + 1 < NN) ? offs[node + 1] : NE;
    float l = 0.f;
    float acc[8];
#pragma unroll
    for (int c = 0; c < 8; c++) acc[c] = 0.f;
    const uint2* hv = (const uint2*)h1f8;   // 32 uint2 per row

    if (beg < end) {
        int idx[4];
#pragma unroll
        for (int i = 0; i < 4; i++) idx[i] = ssrc[beg + 2 * i + half];
        uint2 hbA[2];
        float pA[2];
#pragma unroll
        for (int i = 0; i < 2; i++) {
            hbA[i] = hv[(size_t)idx[i] * 32 + hl];
            int e = beg + 2 * i + half;
            float p = pw1[e * 4 + head];
            pA[i] = (e < end) ? p : 0.f;
        }
        for (int j = beg; j < end; j += 8) {
            int idxN[4];
#pragma unroll
            for (int i = 0; i < 4; i++) idxN[i] = ssrc[j + 8 + 2 * i + half];
            uint2 hbB[2];
            float pB[2];
#pragma unroll
            for (int i = 0; i < 2; i++) {
                hbB[i] = hv[(size_t)idx[2 + i] * 32 + hl];
                int e = j + 4 + 2 * i + half;
                float p = pw1[e * 4 + head];
                pB[i] = (e < end) ? p : 0.f;
            }
#pragma unroll
            for (int i = 0; i < 2; i++) {
                float p = pA[i];
                f32x2 v0 = __builtin_amdgcn_cvt_pk_f32_fp8(hbA[i].x, false);
                f32x2 v1 = __builtin_amdgcn_cvt_pk_f32_fp8(hbA[i].x, true);
                f32x2 v2 = __builtin_amdgcn_cvt_pk_f32_fp8(hbA[i].y, false);
                f32x2 v3 = __builtin_amdgcn_cvt_pk_f32_fp8(hbA[i].y, true);
                l += p;
                acc[0] = fmaf(p, v0.x, acc[0]);
                acc[1] = fmaf(p, v0.y, acc[1]);
                acc[2] = fmaf(p, v1.x, acc[2]);
                acc[3] = fmaf(p, v1.y, acc[3]);
                acc[4] = fmaf(p, v2.x, acc[4]);
                acc[5] = fmaf(p, v2.y, acc[5]);
                acc[6] = fmaf(p, v3.x, acc[6]);
                acc[7] = fmaf(p, v3.y, acc[7]);
            }
#pragma unroll
            for (int i = 0; i < 2; i++) {
                hbA[i] = hv[(size_t)idxN[i] * 32 + hl];
                int e = j + 8 + 2 * i + half;
                float p = pw1[e * 4 + head];
                pA[i] = (e < end) ? p : 0.f;
            }
#pragma unroll
            for (int i = 0; i < 2; i++) {
                float p = pB[i];
                f32x2 v0 = __builtin_amdgcn_cvt_pk_f32_fp8(hbB[i].x, false);
                f32x2 v1 = __builtin_amdgcn_cvt_pk_f32_fp8(hbB[i].x, true);
                f32x2 v2 = __builtin_amdgcn_cvt_pk_f32_fp8(hbB[i].y, false);
                f32x2 v3 = __builtin_amdgcn_cvt_pk_f32_fp8(hbB[i].y, true);
                l += p;
                acc[0] = fmaf(p, v0.x, acc[0]);
                acc[1] = fmaf(p, v0.y, acc[1]);
                acc[2] = fmaf(p, v1.x, acc[2]);
                acc[3] = fmaf(p, v1.y, acc[3]);
                acc[4] = fmaf(p, v2.x, acc[4]);
                acc[5] = fmaf(p, v2.y, acc[5]);
                acc[6] = fmaf(p, v3.x, acc[6]);
                acc[7] = fmaf(p, v3.y, acc[7]);
            }
#pragma unroll
            for (int i = 0; i < 4; i++) idx[i] = idxN[i];
        }
    }
    // combine the two halves (same channels, disjoint edge subsets)
    l += __shfl_xor(l, 32);
#pragma unroll
    for (int c = 0; c < 8; c++) acc[c] += __shfl_xor(acc[c], 32);

    if (half == 0) {
        float inv = 1.f / (l + EPSF);
        const float4* b1v = (const float4*)b1;
        float4 b0 = b1v[hl * 2];
        float4 b1_ = b1v[hl * 2 + 1];
        float o[8];
        o[0] = fmaxf(fmaf(acc[0], inv, b0.x), 0.f);
        o[1] = fmaxf(fmaf(acc[1], inv, b0.y), 0.f);
        o[2] = fmaxf(fmaf(acc[2], inv, b0.z), 0.f);
        o[3] = fmaxf(fmaf(acc[3], inv, b0.w), 0.f);
        o[4] = fmaxf(fmaf(acc[4], inv, b1_.x), 0.f);
        o[5] = fmaxf(fmaf(acc[5], inv, b1_.y), 0.f);
        o[6] = fmaxf(fmaf(acc[6], inv, b1_.z), 0.f);
        o[7] = fmaxf(fmaf(acc[7], inv, b1_.w), 0.f);
        uint4 ob;
        ob.x = (unsigned int)f2bf(o[0]) | ((unsigned int)f2bf(o[1]) << 16);
        ob.y = (unsigned int)f2bf(o[2]) | ((unsigned int)f2bf(o[3]) << 16);
        ob.z = (unsigned int)f2bf(o[4]) | ((unsigned int)f2bf(o[5]) << 16);
        ob.w = (unsigned int)f2bf(o[6]) | ((unsigned int)f2bf(o[7]) << 16);
        ((uint4*)g1b)[(size_t)node * 32 + hl] = ob;
    }
}

// ---------------- layer 2: bf16 MFMA GEMM + fused alpha2 -----------------
__global__ __launch_bounds__(256) void k_gemm2(const unsigned short* __restrict__ g1b,
                                               const unsigned short* __restrict__ wB2,
                                               const float* __restrict__ aws,
                                               const float* __restrict__ awd,
                                               unsigned short* __restrict__ h2b,
                                               float* __restrict__ as2,
                                               float* __restrict__ ad2) {
    __shared__ uint4 Af[4][8][64];   // [mt][kc][lane], 32 KB
    int t = threadIdx.x;
    int m0 = blockIdx.x * 64;

#pragma unroll
    for (int i = 0; i < 8; i++) {
        int g = i * 256 + t;
        int row = g >> 5;
        int c8 = g & 31;
        int grow = m0 + row;
        if (grow >= NN) grow = NN - 1;
        uint4 v = *(const uint4*)(g1b + (size_t)grow * C1 + c8 * 8);
        int kc = c8 >> 2;
        int q = c8 & 3;
        Af[row >> 4][kc][q * 16 + (row & 15)] = v;
    }
    __syncthreads();

    int l = t & 63;
    int wv = t >> 6;

    bf16x8 a[8];
#pragma unroll
    for (int kc = 0; kc < 8; kc++) a[kc] = *(const bf16x8*)&Af[wv][kc][l];

    f32x4 acc[3];
#pragma unroll
    for (int tn = 0; tn < 3; tn++) acc[tn] = (f32x4){0.f, 0.f, 0.f, 0.f};

    const bf16x8* wb = (const bf16x8*)wB2 + l;
#pragma unroll
    for (int tn = 0; tn < 3; tn++) {
#pragma unroll
        for (int kc = 0; kc < 8; kc++) {
            bf16x8 b = wb[(tn * 8 + kc) * 64];
            acc[tn] = __builtin_amdgcn_mfma_f32_16x16x32_bf16(a[kc], b, acc[tn], 0, 0, 0);
        }
    }

    int q = l >> 4;
    int c = l & 15;
    int row0 = m0 + wv * 16 + q * 4;
    float ps[4] = {0.f, 0.f, 0.f, 0.f}, pd[4] = {0.f, 0.f, 0.f, 0.f};
#pragma unroll
    for (int tn = 0; tn < 3; tn++) {
        int col = tn * 16 + c;
        bool cok = col < CLS;
        float wsv = cok ? aws[col] : 0.f;
        float wdv = cok ? awd[col] : 0.f;
#pragma unroll
        for (int r = 0; r < 4; r++) {
            float v = acc[tn][r];
            int row = row0 + r;
            if (cok && row < NN) h2b[(size_t)row * CLS + col] = f2bf(v);
            ps[r] = fmaf(v, wsv, ps[r]);
            pd[r] = fmaf(v, wdv, pd[r]);
        }
    }
#pragma unroll
    for (int r = 0; r < 4; r++) {
        float a_ = ps[r], d_ = pd[r];
#pragma unroll
        for (int s = 1; s < 16; s <<= 1) {
            a_ += __shfl_xor(a_, s);
            d_ += __shfl_xor(d_, s);
        }
        int row = row0 + r;
        if (c == 0 && row < NN) {
            as2[row] = a_;
            ad2[row] = d_;
        }
    }
}

// ---------------- layer 2 aggregation + fused log_softmax ----------------
__global__ __launch_bounds__(256) void k_agg2(const unsigned short* __restrict__ h2b,
                                              const float* __restrict__ pw2,
                                              const int* __restrict__ offs,
                                              const int* __restrict__ ssrc,
                                              const float* __restrict__ b2,
                                              float* __restrict__ out) {
    int lane = threadIdx.x & 63;
    int half = lane >> 5;
    int hl = lane & 31;
    int cl = hl < 20 ? hl : 19;   // uint index within row (2 channels)
    int node = blockIdx.x * 4 + (threadIdx.x >> 6);
    int beg = offs[node];
    int end = (node + 1 < NN) ? offs[node + 1] : NE;
    float l = 0.f, aL = 0.f, aH = 0.f;
    const unsigned int* hv = (const unsigned int*)h2b;   // 20 uints per row

    if (beg < end) {
        int idx[4];
#pragma unroll
        for (int i = 0; i < 4; i++) idx[i] = ssrc[beg + 2 * i + half];
        unsigned int hbA[2];
        float pA[2];
#pragma unroll
        for (int i = 0; i < 2; i++) {
            hbA[i] = hv[(size_t)idx[i] * 20 + cl];
            int e = beg + 2 * i + half;
            float p = pw2[e];
            pA[i] = (e < end) ? p : 0.f;
        }
        for (int j = beg; j < end; j += 8) {
            int idxN[4];
#pragma unroll
            for (int i = 0; i < 4; i++) idxN[i] = ssrc[j + 8 + 2 * i + half];
            unsigned int hbB[2];
            float pB[2];
#pragma unroll
            for (int i = 0; i < 2; i++) {
                hbB[i] = hv[(size_t)idx[2 + i] * 20 + cl];
                int e = j + 4 + 2 * i + half;
                float p = pw2[e];
                pB[i] = (e < end) ? p : 0.f;
            }
#pragma unroll
            for (int i = 0; i < 2; i++) {
                float p = pA[i];
                l += p;
                aL = fmaf(p, bflo(hbA[i]), aL);
                aH = fmaf(p, bfhi(hbA[i]), aH);
            }
#pragma unroll
            for (int i = 0; i < 2; i++) {
                hbA[i] = hv[(size_t)idxN[i] * 20 + cl];
                int e = j + 8 + 2 * i + half;
                float p = pw2[e];
                pA[i] = (e < end) ? p : 0.f;
            }
#pragma unroll
            for (int i = 0; i < 2; i++) {
                float p = pB[i];
                l += p;
                aL = fmaf(p, bflo(hbB[i]), aL);
                aH = fmaf(p, bfhi(hbB[i]), aH);
            }
#pragma unroll
            for (int i = 0; i < 4; i++) idx[i] = idxN[i];
        }
    }
    l += __shfl_xor(l, 32);
    aL += __shfl_xor(aL, 32);
    aH += __shfl_xor(aH, 32);

    if (half == 0) {
        bool act = hl < 20;
        float inv = 1.f / (l + EPSF);
        float vL = -INFINITY, vH = -INFINITY;
        if (act) {
            float2 b = ((const float2*)b2)[cl];
            vL = aL * inv + b.x;
            vH = aH * inv + b.y;
        }
        float mx = fmaxf(vL, vH);
#pragma unroll
        for (int s = 16; s >= 1; s >>= 1) mx = fmaxf(mx, __shfl_xor(mx, s));
        float ex = act ? (__expf(vL - mx) + __expf(vH - mx)) : 0.f;
#pragma unroll
        for (int s = 16; s >= 1; s >>= 1) ex += __shfl_xor(ex, s);
        if (act) {
            float ls = __logf(ex);
            float2 o = {vL - mx - ls, vH - mx - ls};
            *(float2*)(out + (size_t)node * CLS + cl * 2) = o;
        }
    }
}

// ---------------- launch ----------------

extern "C" void kernel_launch(void* const* d_in, const int* in_sizes, int n_in,
                              void* d_out, int out_size, void* d_ws, size_t ws_size,
                              hipStream_t stream) {
    const float* x    = (const float*)d_in[0];
    const int*   ei   = (const int*)d_in[1];
    const float* W1   = (const float*)d_in[2];
    const float* as1w = (const float*)d_in[3];
    const float* ad1w = (const float*)d_in[4];
    const float* b1   = (const float*)d_in[5];
    const float* W2   = (const float*)d_in[6];
    const float* as2w = (const float*)d_in[7];
    const float* ad2w = (const float*)d_in[8];
    const float* b2   = (const float*)d_in[9];
    float* out = (float*)d_out;

    char* p = (char*)d_ws;
    auto alloc = [&](size_t bytes) {
        char* r = p;
        p += (bytes + 255) & ~(size_t)255;
        return r;
    };
    unsigned char* h1f8 = (unsigned char*)alloc((size_t)NN * C1);
    unsigned short* g1b = (unsigned short*)alloc((size_t)NN * C1 * 2);
    unsigned short* h2b = (unsigned short*)alloc((size_t)NN * CLS * 2);
    float* as1  = (float*)alloc((size_t)NN * 4 * 4);
    float* ad1  = (float*)alloc((size_t)NN * 4 * 4);
    float* as2  = (float*)alloc((size_t)NN * 4);
    float* ad2  = (float*)alloc((size_t)NN * 4);
    int* counts = (int*)alloc((size_t)NN * 4);
    int* offs   = (int*)alloc((size_t)NN * 4);
    int* cursor = (int*)alloc((size_t)NN * 4);
    int* parts  = (int*)alloc(64 * 4);
    int* ssrc   = (int*)alloc((size_t)(NE + 32) * 4);
    int* sdst   = (int*)alloc((size_t)NE * 4);
    float4* pw1 = (float4*)alloc((size_t)(NE + 16) * 16);
    float* pw2  = (float*)alloc((size_t)(NE + 16) * 4);
    unsigned short* wB1 = (unsigned short*)alloc((size_t)4096 * 8 * 2);
    unsigned short* wB2 = (unsigned short*)alloc((size_t)1536 * 8 * 2);

    const int nb_scan = (NN + 1023) / 1024;  // 49
    const int nb_e = (NE + 255) / 256;       // 3125
    const int nb_ep = nb_e + 1;              // covers NE..NE+255 pad writers

    k_zero<<<(NN + 255) / 256, 256, 0, stream>>>(counts, NN);
    k_hist<<<nb_e, 256, 0, stream>>>(ei, counts);
    k_scan1<<<nb_scan, 1024, 0, stream>>>(counts, offs, parts);
    k_scan2<<<1, 64, 0, stream>>>(parts, nb_scan);
    k_scan3<<<(NN + 255) / 256, 256, 0, stream>>>(offs, parts, cursor);
    k_scatter<<<nb_e, 256, 0, stream>>>(ei, cursor, ssrc, sdst);

    k_wconv<<<22, 256, 0, stream>>>(W1, W2, wB1, wB2);
    k_gemm1<<<(NN + 63) / 64, 256, 0, stream>>>(x, wB1, as1w, ad1w, h1f8, as1, ad1);
    k_ew1<<<nb_ep, 256, 0, stream>>>(ssrc, sdst, as1, ad1, pw1, ssrc);
    k_agg1<<<NN / 4, 256, 0, stream>>>(h1f8, (const float*)pw1, offs, ssrc, b1, g1b);

    k_gemm2<<<(NN + 63) / 64, 256, 0, stream>>>(g1b, wB2, as2w, ad2w, h2b, as2, ad2);
    k_ew2<<<nb_ep, 256, 0, stream>>>(ssrc, sdst, as2, ad2, pw2);
    k_agg2<<<NN / 4, 256, 0, stream>>>(h2b, pw2, offs, ssrc, b2, out);
}